// Round 12
// baseline (496.680 us; speedup 1.0000x reference)
//
#include <hip/hip_runtime.h>
#include <hip/hip_bf16.h>

// RWKV-7 block (TMix + CMix) for T=1024, C=2048, H=32, N=64 on gfx950.

#define T_ 1024
#define C_ 2048
#define H_ 32
#define NH 64

typedef __attribute__((ext_vector_type(8))) short short8v;
typedef __attribute__((ext_vector_type(4))) float f32x4;

__device__ __forceinline__ float bf2f(unsigned short u) {
  union { float f; unsigned int i; } c; c.i = ((unsigned int)u) << 16; return c.f;
}
__device__ __forceinline__ unsigned short f2bf(float f) {
  union { float f; unsigned int i; } c; c.f = f;
  unsigned int x = c.i;
  return (unsigned short)((x + 0x7fffu + ((x >> 16) & 1u)) >> 16); // RNE
}
__device__ __forceinline__ float sigm(float x) { return 1.f / (1.f + __expf(-x)); }

__device__ __forceinline__ void load8bf(const unsigned short* p, float* o) {
  union { int4 v; unsigned short u[8]; } c;
  c.v = *(const int4*)p;
#pragma unroll
  for (int i = 0; i < 8; ++i) o[i] = bf2f(c.u[i]);
}
__device__ __forceinline__ void store8bf(unsigned short* p, const float* o) {
  union { int4 v; unsigned short u[8]; } c;
#pragma unroll
  for (int i = 0; i < 8; ++i) c.u[i] = f2bf(o[i]);
  *(int4*)p = c.v;
}
__device__ __forceinline__ void load8f(const float* p, float* o) {
  float4 a = ((const float4*)p)[0], b = ((const float4*)p)[1];
  o[0] = a.x; o[1] = a.y; o[2] = a.z; o[3] = a.w;
  o[4] = b.x; o[5] = b.y; o[6] = b.z; o[7] = b.w;
}
__device__ __forceinline__ void load4f(const float* p, float* o) {
  float4 a = *(const float4*)p;
  o[0] = a.x; o[1] = a.y; o[2] = a.z; o[3] = a.w;
}

#define GLD16(g, l)                                                        \
  __builtin_amdgcn_global_load_lds(                                        \
      (const __attribute__((address_space(1))) void*)(g),                  \
      (__attribute__((address_space(3))) void*)(l), 16, 0, 0)

// ---------------- LayerNorm: fp32 in -> bf16 out --------------------------
__global__ __launch_bounds__(256) void ln_kernel(const float* __restrict__ x,
                                                 const float* __restrict__ w,
                                                 const float* __restrict__ b,
                                                 unsigned short* __restrict__ out) {
  int t = blockIdx.x, tid = threadIdx.x;
  const float* xr = x + (size_t)t * C_;
  float v[8];
  load8f(xr + tid * 8, v);
  float s = 0.f, q = 0.f;
#pragma unroll
  for (int i = 0; i < 8; ++i) { s += v[i]; q += v[i] * v[i]; }
  for (int m = 1; m < 64; m <<= 1) { s += __shfl_xor(s, m); q += __shfl_xor(q, m); }
  __shared__ float rs[4], rq[4];
  if ((tid & 63) == 0) { rs[tid >> 6] = s; rq[tid >> 6] = q; }
  __syncthreads();
  s = rs[0] + rs[1] + rs[2] + rs[3];
  q = rq[0] + rq[1] + rq[2] + rq[3];
  float mean = s * (1.f / C_);
  float var = q * (1.f / C_) - mean * mean;
  float rstd = rsqrtf(var + 1e-5f);
  int c = tid * 8;
  float o[8];
#pragma unroll
  for (int i = 0; i < 8; ++i) o[i] = (v[i] - mean) * rstd * w[c + i] + b[c + i];
  store8bf(out + (size_t)t * C_ + c, o);
}

// ---------------- token-shift mixes ---------------------------------------
__global__ __launch_bounds__(256) void mix6_kernel(
    const unsigned short* __restrict__ xln, const float* __restrict__ xprev,
    const float* __restrict__ mr, const float* __restrict__ mw,
    const float* __restrict__ mk, const float* __restrict__ mv,
    const float* __restrict__ ma, const float* __restrict__ mg,
    unsigned short* xr, unsigned short* xw, unsigned short* xk,
    unsigned short* xv, unsigned short* xa, unsigned short* xg) {
  int t = blockIdx.x, tid = threadIdx.x, c = tid * 8;
  float cur[8], prv[8];
  load8bf(xln + (size_t)t * C_ + c, cur);
  if (t == 0) load8f(xprev + c, prv);
  else load8bf(xln + (size_t)(t - 1) * C_ + c, prv);
  float cf[8], o[8];
  const float* coefs[6] = {mr, mw, mk, mv, ma, mg};
  unsigned short* outs6[6] = {xr, xw, xk, xv, xa, xg};
#pragma unroll
  for (int a = 0; a < 6; ++a) {
    load8f(coefs[a] + c, cf);
#pragma unroll
    for (int i = 0; i < 8; ++i) o[i] = cur[i] + (prv[i] - cur[i]) * cf[i];
    store8bf(outs6[a] + (size_t)t * C_ + c, o);
  }
}

__global__ __launch_bounds__(256) void mix1_kernel(
    const unsigned short* __restrict__ xln, const float* __restrict__ xprev,
    const float* __restrict__ coef, unsigned short* __restrict__ o) {
  int t = blockIdx.x, tid = threadIdx.x, c = tid * 8;
  float cur[8], prv[8], cf[8], o8[8];
  load8bf(xln + (size_t)t * C_ + c, cur);
  if (t == 0) load8f(xprev + c, prv);
  else load8bf(xln + (size_t)(t - 1) * C_ + c, prv);
  load8f(coef + c, cf);
#pragma unroll
  for (int i = 0; i < 8; ++i) o8[i] = cur[i] + (prv[i] - cur[i]) * cf[i];
  store8bf(o + (size_t)t * C_ + c, o8);
}

// ---------------- tiled transpose: fp32 [R][Cc] -> bf16 [Cc][R] -----------
__global__ __launch_bounds__(256) void transpose_kernel(
    const float* in0, const float* in1, const float* in2,
    unsigned short* o0, unsigned short* o1, unsigned short* o2,
    int R, int Cc) {
  const float* in = blockIdx.z == 0 ? in0 : (blockIdx.z == 1 ? in1 : in2);
  unsigned short* out = blockIdx.z == 0 ? o0 : (blockIdx.z == 1 ? o1 : o2);
  __shared__ __align__(16) unsigned short tile[64][80];
  int c0 = blockIdx.x * 64, r0 = blockIdx.y * 64;
  int rr = threadIdx.x >> 4, cq = threadIdx.x & 15;
#pragma unroll
  for (int i = 0; i < 4; ++i) {
    int r = rr + i * 16;
    float4 v = *(const float4*)(in + (size_t)(r0 + r) * Cc + c0 + cq * 4);
    tile[cq * 4 + 0][r] = f2bf(v.x);
    tile[cq * 4 + 1][r] = f2bf(v.y);
    tile[cq * 4 + 2][r] = f2bf(v.z);
    tile[cq * 4 + 3][r] = f2bf(v.w);
  }
  __syncthreads();
  int cr = threadIdx.x >> 2, rg = threadIdx.x & 3;
  int4 w0 = *(const int4*)&tile[cr][rg * 16];
  int4 w1 = *(const int4*)&tile[cr][rg * 16 + 8];
  unsigned short* op = out + (size_t)(c0 + cr) * R + r0 + rg * 16;
  *(int4*)op = w0;
  *(int4*)(op + 8) = w1;
}

// ---------------- 2-phase double-buffered bf16 GEMM: A[M,K] x Bt[N,K]^T ---
// EPI: 0=f32 store, 1=f32 addsrc+acc, 2=relu^2 -> bf16
template <int EPI>
__global__ __launch_bounds__(256) void gemm2_kernel(
    const unsigned short* A0, const unsigned short* A1, const unsigned short* A2,
    const unsigned short* B0, const unsigned short* B1, const unsigned short* B2,
    void* C0, void* C1, void* C2, const float* __restrict__ addsrc,
    int M, int K, int N) {
  int z = blockIdx.z;
  const unsigned short* A = z == 0 ? A0 : (z == 1 ? A1 : A2);
  const unsigned short* Bt = z == 0 ? B0 : (z == 1 ? B1 : B2);
  void* Cout = z == 0 ? C0 : (z == 1 ? C1 : C2);
  __shared__ __align__(16) unsigned short As[2][128 * 32];
  __shared__ __align__(16) unsigned short Bs[2][128 * 32];
  const int tid = threadIdx.x, lane = tid & 63, wid = tid >> 6;
  const int bm = blockIdx.y * 128, bn = blockIdx.x * 128;
  const int wr = wid >> 1, wc = wid & 1;
  const int mrow = lane & 15, krow = lane >> 4;
  auto stage = [&](int buf, int kt) {
#pragma unroll
    for (int q = 0; q < 2; ++q) {
      int s = q * 2048 + tid * 8;
      int m = s >> 5, k = s & 31;
      GLD16(A + (size_t)(bm + m) * K + kt + k, &As[buf][s]);
      GLD16(Bt + (size_t)(bn + m) * K + kt + k, &Bs[buf][s]);
    }
  };
  f32x4 acc[4][4] = {};
  stage(0, 0);
  __syncthreads();
  int buf = 0;
  for (int kt = 0; kt < K; kt += 32) {
    if (kt + 32 < K) stage(buf ^ 1, kt + 32);
    short8v af[4], bfrag[4];
#pragma unroll
    for (int i = 0; i < 4; ++i)
      af[i] = *(const short8v*)&As[buf][(wr * 64 + i * 16 + mrow) * 32 + krow * 8];
#pragma unroll
    for (int j = 0; j < 4; ++j)
      bfrag[j] = *(const short8v*)&Bs[buf][(wc * 64 + j * 16 + mrow) * 32 + krow * 8];
#pragma unroll
    for (int i = 0; i < 4; ++i)
#pragma unroll
      for (int j = 0; j < 4; ++j)
        acc[i][j] = __builtin_amdgcn_mfma_f32_16x16x32_bf16(af[i], bfrag[j], acc[i][j], 0, 0, 0);
    __syncthreads();
    buf ^= 1;
  }
#pragma unroll
  for (int i = 0; i < 4; ++i)
#pragma unroll
    for (int j = 0; j < 4; ++j)
#pragma unroll
      for (int e = 0; e < 4; ++e) {
        int grow = bm + wr * 64 + i * 16 + (lane >> 4) * 4 + e;
        int gcol = bn + wc * 64 + j * 16 + (lane & 15);
        size_t off = (size_t)grow * N + gcol;
        float v = acc[i][j][e];
        if constexpr (EPI == 0) ((float*)Cout)[off] = v;
        else if constexpr (EPI == 1) ((float*)Cout)[off] = addsrc[off] + v;
        else { float r = v > 0.f ? v : 0.f; ((unsigned short*)Cout)[off] = f2bf(r * r); }
      }
}

// ---------------- split-K variant: z = K-slice index, fp32 partials -------
__global__ __launch_bounds__(256) void gemm2ks_kernel(
    const unsigned short* __restrict__ A, const unsigned short* __restrict__ Bt,
    float* __restrict__ P, int M, int KH, int Ktot, int N) {
  int kz = blockIdx.z;
  const size_t kbase = (size_t)kz * KH;
  __shared__ __align__(16) unsigned short As[2][128 * 32];
  __shared__ __align__(16) unsigned short Bs[2][128 * 32];
  const int tid = threadIdx.x, lane = tid & 63, wid = tid >> 6;
  const int bm = blockIdx.y * 128, bn = blockIdx.x * 128;
  const int wr = wid >> 1, wc = wid & 1;
  const int mrow = lane & 15, krow = lane >> 4;
  auto stage = [&](int buf, int kt) {
#pragma unroll
    for (int q = 0; q < 2; ++q) {
      int s = q * 2048 + tid * 8;
      int m = s >> 5, k = s & 31;
      GLD16(A + (size_t)(bm + m) * Ktot + kbase + kt + k, &As[buf][s]);
      GLD16(Bt + (size_t)(bn + m) * Ktot + kbase + kt + k, &Bs[buf][s]);
    }
  };
  f32x4 acc[4][4] = {};
  stage(0, 0);
  __syncthreads();
  int buf = 0;
  for (int kt = 0; kt < KH; kt += 32) {
    if (kt + 32 < KH) stage(buf ^ 1, kt + 32);
    short8v af[4], bfrag[4];
#pragma unroll
    for (int i = 0; i < 4; ++i)
      af[i] = *(const short8v*)&As[buf][(wr * 64 + i * 16 + mrow) * 32 + krow * 8];
#pragma unroll
    for (int j = 0; j < 4; ++j)
      bfrag[j] = *(const short8v*)&Bs[buf][(wc * 64 + j * 16 + mrow) * 32 + krow * 8];
#pragma unroll
    for (int i = 0; i < 4; ++i)
#pragma unroll
      for (int j = 0; j < 4; ++j)
        acc[i][j] = __builtin_amdgcn_mfma_f32_16x16x32_bf16(af[i], bfrag[j], acc[i][j], 0, 0, 0);
    __syncthreads();
    buf ^= 1;
  }
  float* Pz = P + (size_t)kz * M * N;
#pragma unroll
  for (int i = 0; i < 4; ++i)
#pragma unroll
    for (int j = 0; j < 4; ++j)
#pragma unroll
      for (int e = 0; e < 4; ++e) {
        int grow = bm + wr * 64 + i * 16 + (lane >> 4) * 4 + e;
        int gcol = bn + wc * 64 + j * 16 + (lane & 15);
        Pz[(size_t)grow * N + gcol] = acc[i][j][e];
      }
}

// ---------------- split-K x 3-batch variant (rkv): z = kz*3 + batch -------
__global__ __launch_bounds__(256) void gemm2ks3_kernel(
    const unsigned short* A0, const unsigned short* A1, const unsigned short* A2,
    const unsigned short* B0, const unsigned short* B1, const unsigned short* B2,
    float* __restrict__ P, int M, int KH, int Ktot, int N) {
  int z = blockIdx.z;
  int batch = z % 3, kz = z / 3;
  const unsigned short* A = batch == 0 ? A0 : (batch == 1 ? A1 : A2);
  const unsigned short* Bt = batch == 0 ? B0 : (batch == 1 ? B1 : B2);
  const size_t kbase = (size_t)kz * KH;
  __shared__ __align__(16) unsigned short As[2][128 * 32];
  __shared__ __align__(16) unsigned short Bs[2][128 * 32];
  const int tid = threadIdx.x, lane = tid & 63, wid = tid >> 6;
  const int bm = blockIdx.y * 128, bn = blockIdx.x * 128;
  const int wr = wid >> 1, wc = wid & 1;
  const int mrow = lane & 15, krow = lane >> 4;
  auto stage = [&](int buf, int kt) {
#pragma unroll
    for (int q = 0; q < 2; ++q) {
      int s = q * 2048 + tid * 8;
      int m = s >> 5, k = s & 31;
      GLD16(A + (size_t)(bm + m) * Ktot + kbase + kt + k, &As[buf][s]);
      GLD16(Bt + (size_t)(bn + m) * Ktot + kbase + kt + k, &Bs[buf][s]);
    }
  };
  f32x4 acc[4][4] = {};
  stage(0, 0);
  __syncthreads();
  int buf = 0;
  for (int kt = 0; kt < KH; kt += 32) {
    if (kt + 32 < KH) stage(buf ^ 1, kt + 32);
    short8v af[4], bfrag[4];
#pragma unroll
    for (int i = 0; i < 4; ++i)
      af[i] = *(const short8v*)&As[buf][(wr * 64 + i * 16 + mrow) * 32 + krow * 8];
#pragma unroll
    for (int j = 0; j < 4; ++j)
      bfrag[j] = *(const short8v*)&Bs[buf][(wc * 64 + j * 16 + mrow) * 32 + krow * 8];
#pragma unroll
    for (int i = 0; i < 4; ++i)
#pragma unroll
      for (int j = 0; j < 4; ++j)
        acc[i][j] = __builtin_amdgcn_mfma_f32_16x16x32_bf16(af[i], bfrag[j], acc[i][j], 0, 0, 0);
    __syncthreads();
    buf ^= 1;
  }
  float* Pz = P + (size_t)z * M * N;
#pragma unroll
  for (int i = 0; i < 4; ++i)
#pragma unroll
    for (int j = 0; j < 4; ++j)
#pragma unroll
      for (int e = 0; e < 4; ++e) {
        int grow = bm + wr * 64 + i * 16 + (lane >> 4) * 4 + e;
        int gcol = bn + wc * 64 + j * 16 + (lane & 15);
        Pz[(size_t)grow * N + gcol] = acc[i][j][e];
      }
}

// ---------------- q[i] += q[i + 3*T*C], in-place rkv combine --------------
__global__ __launch_bounds__(256) void addsk3_kernel(float* __restrict__ q) {
  size_t i = ((size_t)blockIdx.x * 256 + threadIdx.x) * 4;
  float4 a = *(const float4*)(q + i);
  float4 b = *(const float4*)(q + i + 3ull * T_ * C_);
  float4 r;
  r.x = a.x + b.x; r.y = a.y + b.y; r.z = a.z + b.z; r.w = a.w + b.w;
  *(float4*)(q + i) = r;
}

// ---------------- o = a + p0+p1+p2+p3 (partials at stride T*C) ------------
__global__ __launch_bounds__(256) void add5_kernel(
    const float* __restrict__ a, const float* __restrict__ p,
    float* __restrict__ o) {
  size_t i = ((size_t)blockIdx.x * 256 + threadIdx.x) * 4;
  const size_t TC = (size_t)T_ * C_;
  float4 va = *(const float4*)(a + i);
  float4 v0 = *(const float4*)(p + i);
  float4 v1 = *(const float4*)(p + i + TC);
  float4 v2 = *(const float4*)(p + i + 2 * TC);
  float4 v3 = *(const float4*)(p + i + 3 * TC);
  float4 r;
  r.x = va.x + v0.x + v1.x + v2.x + v3.x;
  r.y = va.y + v0.y + v1.y + v2.y + v3.y;
  r.z = va.z + v0.z + v1.z + v2.z + v3.z;
  r.w = va.w + v0.w + v1.w + v2.w + v3.w;
  *(float4*)(o + i) = r;
}

// ---------------- K-split lora-down GEMMs (BN=64, z=mat*8+kz) -------------
__global__ __launch_bounds__(256) void gemm_ks3_kernel(
    const unsigned short* A0, const unsigned short* A1, const unsigned short* A2,
    const unsigned short* B0, const unsigned short* B1, const unsigned short* B2,
    float* P0, float* P1, float* P2, int K, int N) {
  int mz = blockIdx.z >> 3, kz = blockIdx.z & 7;
  const unsigned short* A = mz == 0 ? A0 : (mz == 1 ? A1 : A2);
  const unsigned short* Bt = mz == 0 ? B0 : (mz == 1 ? B1 : B2);
  float* partial = mz == 0 ? P0 : (mz == 1 ? P1 : P2);
  __shared__ __align__(16) unsigned short As[2][128 * 32];
  __shared__ __align__(16) unsigned short Bs[2][64 * 32];
  const int tid = threadIdx.x, lane = tid & 63, wid = tid >> 6;
  const int bn = blockIdx.x * 64, bm = blockIdx.y * 128;
  const int wr = wid >> 1, wc = wid & 1;
  const int mrow = lane & 15, krow = lane >> 4;
  auto stage = [&](int buf, int kt) {
#pragma unroll
    for (int q = 0; q < 2; ++q) {
      int s = q * 2048 + tid * 8;
      int m = s >> 5, k = s & 31;
      GLD16(A + (size_t)(bm + m) * K + kt + k, &As[buf][s]);
    }
    {
      int s = tid * 8;
      int n = s >> 5, k = s & 31;
      GLD16(Bt + (size_t)(bn + n) * K + kt + k, &Bs[buf][s]);
    }
  };
  f32x4 acc[4][2] = {};
  int k0 = kz * 256;
  stage(0, k0);
  __syncthreads();
  int buf = 0;
  for (int kt = k0; kt < k0 + 256; kt += 32) {
    if (kt + 32 < k0 + 256) stage(buf ^ 1, kt + 32);
    short8v af[4], bfrag[2];
#pragma unroll
    for (int i = 0; i < 4; ++i)
      af[i] = *(const short8v*)&As[buf][(wr * 64 + i * 16 + mrow) * 32 + krow * 8];
#pragma unroll
    for (int j = 0; j < 2; ++j)
      bfrag[j] = *(const short8v*)&Bs[buf][(wc * 32 + j * 16 + mrow) * 32 + krow * 8];
#pragma unroll
    for (int i = 0; i < 4; ++i)
#pragma unroll
      for (int j = 0; j < 2; ++j)
        acc[i][j] = __builtin_amdgcn_mfma_f32_16x16x32_bf16(af[i], bfrag[j], acc[i][j], 0, 0, 0);
    __syncthreads();
    buf ^= 1;
  }
#pragma unroll
  for (int i = 0; i < 4; ++i)
#pragma unroll
    for (int j = 0; j < 2; ++j)
#pragma unroll
      for (int e = 0; e < 4; ++e) {
        int row = bm + wr * 64 + i * 16 + (lane >> 4) * 4 + e;
        int col = bn + wc * 32 + j * 16 + (lane & 15);
        partial[((size_t)kz * 1024 + row) * N + col] = acc[i][j][e];
      }
}

__global__ __launch_bounds__(256) void gemm_ks_kernel(
    const unsigned short* __restrict__ A, const unsigned short* __restrict__ Bt,
    float* __restrict__ partial, int K, int N) {
  __shared__ __align__(16) unsigned short As[2][128 * 32];
  __shared__ __align__(16) unsigned short Bs[2][64 * 32];
  const int tid = threadIdx.x, lane = tid & 63, wid = tid >> 6;
  const int bn = blockIdx.x * 64, bm = blockIdx.y * 128, kz = blockIdx.z;
  const int wr = wid >> 1, wc = wid & 1;
  const int mrow = lane & 15, krow = lane >> 4;
  auto stage = [&](int buf, int kt) {
#pragma unroll
    for (int q = 0; q < 2; ++q) {
      int s = q * 2048 + tid * 8;
      int m = s >> 5, k = s & 31;
      GLD16(A + (size_t)(bm + m) * K + kt + k, &As[buf][s]);
    }
    {
      int s = tid * 8;
      int n = s >> 5, k = s & 31;
      GLD16(Bt + (size_t)(bn + n) * K + kt + k, &Bs[buf][s]);
    }
  };
  f32x4 acc[4][2] = {};
  int k0 = kz * 256;
  stage(0, k0);
  __syncthreads();
  int buf = 0;
  for (int kt = k0; kt < k0 + 256; kt += 32) {
    if (kt + 32 < k0 + 256) stage(buf ^ 1, kt + 32);
    short8v af[4], bfrag[2];
#pragma unroll
    for (int i = 0; i < 4; ++i)
      af[i] = *(const short8v*)&As[buf][(wr * 64 + i * 16 + mrow) * 32 + krow * 8];
#pragma unroll
    for (int j = 0; j < 2; ++j)
      bfrag[j] = *(const short8v*)&Bs[buf][(wc * 32 + j * 16 + mrow) * 32 + krow * 8];
#pragma unroll
    for (int i = 0; i < 4; ++i)
#pragma unroll
      for (int j = 0; j < 2; ++j)
        acc[i][j] = __builtin_amdgcn_mfma_f32_16x16x32_bf16(af[i], bfrag[j], acc[i][j], 0, 0, 0);
    __syncthreads();
    buf ^= 1;
  }
#pragma unroll
  for (int i = 0; i < 4; ++i)
#pragma unroll
    for (int j = 0; j < 2; ++j)
#pragma unroll
      for (int e = 0; e < 4; ++e) {
        int row = bm + wr * 64 + i * 16 + (lane >> 4) * 4 + e;
        int col = bn + wc * 32 + j * 16 + (lane & 15);
        partial[((size_t)kz * 1024 + row) * N + col] = acc[i][j][e];
      }
}

__global__ __launch_bounds__(128) void lora_combine_kernel(
    const float* __restrict__ pw, const float* __restrict__ pa,
    const float* __restrict__ pv, const float* __restrict__ pg,
    unsigned short* __restrict__ hw, unsigned short* __restrict__ ha,
    unsigned short* __restrict__ hv, unsigned short* __restrict__ hg) {
  int t = blockIdx.x, which = blockIdx.y, tid = threadIdx.x;
  int Nl = (which == 3) ? 128 : 64;
  if (tid >= Nl) return;
  const float* p = which == 0 ? pw : which == 1 ? pa : which == 2 ? pv : pg;
  float s = 0.f;
#pragma unroll
  for (int kz = 0; kz < 8; ++kz) s += p[((size_t)kz * 1024 + t) * Nl + tid];
  float r = which == 0 ? tanhf(s) : (which == 3 ? sigm(s) : s);
  unsigned short* o = which == 0 ? hw : which == 1 ? ha : which == 2 ? hv : hg;
  o[t * Nl + tid] = f2bf(r);
}

// ---------------- post: pack scan inputs (fp32) ---------------------------
// scanin[h][t][6][64] fp32: seg 0=w, 1=kkn, 2=-kkn*a, 3=k2, 4=v, 5=r
__global__ __launch_bounds__(256) void post_kernel(
    const float* __restrict__ k_, const float* __restrict__ vraw,
    const float* __restrict__ r_, const float* __restrict__ wpre,
    const float* __restrict__ apre, const float* __restrict__ vpre,
    const float* __restrict__ vfirst, const float* __restrict__ w0,
    const float* __restrict__ a0, const float* __restrict__ v0_,
    const float* __restrict__ k_k, const float* __restrict__ k_a,
    float* __restrict__ scanin) {
  int t = blockIdx.x, tid = threadIdx.x;
  int c = tid * 8, h = tid >> 3, j = c & 63;
  size_t o = (size_t)t * C_ + c;
  float kv[8], vv[8], rv[8], wv[8], av[8], vp[8], vf[8];
  load8f(k_ + o, kv); load8f(vraw + o, vv); load8f(r_ + o, rv);
  load8f(wpre + o, wv); load8f(apre + o, av); load8f(vpre + o, vp);
  load8f(vfirst + o, vf);
  float ckk[8], cka[8], cw0[8], ca0[8], cv0[8];
  load8f(k_k + c, ckk); load8f(k_a + c, cka); load8f(w0 + c, cw0);
  load8f(a0 + c, ca0); load8f(v0_ + c, cv0);
  float kk[8]; float ss = 0.f;
#pragma unroll
  for (int i = 0; i < 8; ++i) { kk[i] = kv[i] * ckk[i]; ss += kk[i] * kk[i]; }
  ss += __shfl_xor(ss, 1); ss += __shfl_xor(ss, 2); ss += __shfl_xor(ss, 4);
  float rdn = 1.f / fmaxf(sqrtf(ss), 1e-12f);
  float sw[8], skn[8], scc[8], sk2[8], sv[8];
#pragma unroll
  for (int i = 0; i < 8; ++i) {
    float kkn = kk[i] * rdn;
    float a = sigm(ca0[i] + av[i]);
    skn[i] = kkn;
    scc[i] = -kkn * a;
    sk2[i] = kv[i] * (1.f + (a - 1.f) * cka[i]);
    float sg = sigm(cv0[i] + vp[i]);
    sv[i] = vv[i] + (vf[i] - vv[i]) * sg;
    sw[i] = __expf(-0.606531f * sigm(cw0[i] + wv[i]));
  }
  float* bp = scanin + ((size_t)h * T_ + t) * 384 + j;
  ((float4*)(bp + 0))[0]   = make_float4(sw[0], sw[1], sw[2], sw[3]);
  ((float4*)(bp + 4))[0]   = make_float4(sw[4], sw[5], sw[6], sw[7]);
  ((float4*)(bp + 64))[0]  = make_float4(skn[0], skn[1], skn[2], skn[3]);
  ((float4*)(bp + 68))[0]  = make_float4(skn[4], skn[5], skn[6], skn[7]);
  ((float4*)(bp + 128))[0] = make_float4(scc[0], scc[1], scc[2], scc[3]);
  ((float4*)(bp + 132))[0] = make_float4(scc[4], scc[5], scc[6], scc[7]);
  ((float4*)(bp + 192))[0] = make_float4(sk2[0], sk2[1], sk2[2], sk2[3]);
  ((float4*)(bp + 196))[0] = make_float4(sk2[4], sk2[5], sk2[6], sk2[7]);
  ((float4*)(bp + 256))[0] = make_float4(sv[0], sv[1], sv[2], sv[3]);
  ((float4*)(bp + 260))[0] = make_float4(sv[4], sv[5], sv[6], sv[7]);
  ((float4*)(bp + 320))[0] = make_float4(rv[0], rv[1], rv[2], rv[3]);
  ((float4*)(bp + 324))[0] = make_float4(rv[4], rv[5], rv[6], rv[7]);
}

// ---------------- sequential scan v5b: 16p x 4r, 512 blocks, regs freed ---
struct SR { float wv[4], nv[4], cv[4], kv[4], rv[4], vvv; };

template <int CTRL>
__device__ __forceinline__ float dppadd(float x) {
  int y = __builtin_amdgcn_update_dpp(0, __float_as_int(x), CTRL, 0xF, 0xF, true);
  return x + __int_as_float(y);
}
// full sum across each 16-lane row, result in all 16 lanes (pure VALU)
__device__ __forceinline__ float red16(float x) {
  x = dppadd<0xB1>(x);
  x = dppadd<0x4E>(x);
  x = dppadd<0x140>(x);
  x = dppadd<0x141>(x);
  return x;
}

__device__ __forceinline__ void loadstep(const float* S, SR& R, int p4, int row) {
  load4f(S + p4, R.wv);
  load4f(S + 64 + p4, R.nv);
  load4f(S + 128 + p4, R.cv);
  load4f(S + 192 + p4, R.kv);
  load4f(S + 320 + p4, R.rv);
  R.vvv = S[256 + row];
}

__device__ __forceinline__ void stepcomp(const SR& R, float* st, int part,
                                         float* __restrict__ ob, size_t oidx) {
  float p0 = fmaf(st[0], R.nv[0], 0.f);
  float p1 = fmaf(st[1], R.nv[1], 0.f);
  p0 = fmaf(st[2], R.nv[2], p0);
  p1 = fmaf(st[3], R.nv[3], p1);
  float sa = red16(p0 + p1);
  float s0 = 0.f, s1 = 0.f;
#pragma unroll
  for (int i = 0; i < 4; ++i) {
    float t = fmaf(st[i], R.wv[i], fmaf(sa, R.cv[i], R.vvv * R.kv[i]));
    st[i] = t;
    if (i & 1) s1 = fmaf(t, R.rv[i], s1);
    else s0 = fmaf(t, R.rv[i], s0);
  }
  float so = red16(s0 + s1);
  if (part == 0) ob[oidx] = so;
}

// 512 blocks = 32 heads x 16 row-groups (head pinned to one XCD);
// 64 thr = 4 rows x 16 parts. Direct global loads, 5-deep reg pipeline.
// launch_bounds(64, 1): min 1 wave/EU -> full VGPR budget so the pipeline
// buffers stay resident (at plain (64) the compiler capped us at 60 VGPRs
// for 8-wave occupancy our 2-wave/CU grid never uses, serializing loads).
__global__ __launch_bounds__(64, 1) void scan5_kernel(
    const float* __restrict__ scanin, const float* __restrict__ vk0,
    float* __restrict__ outs) {
  int bid = blockIdx.x;
  int h = (bid & 7) + 8 * ((bid >> 3) & 3);  // h&7 fixed per XCD
  int rg = bid >> 5;                          // 0..15
  int tid = threadIdx.x;
  int part = tid & 15, row = rg * 4 + (tid >> 4);
  int p4 = part * 4;
  float st[4];
  load4f(vk0 + ((size_t)h * NH + row) * NH + p4, st);
  const float* src = scanin + (size_t)h * T_ * 384;
  float* ob = outs + h * NH + row;
  SR b0, b1, b2, b3, b4, b5;
  loadstep(src + 0 * 384, b0, p4, row);
  loadstep(src + 1 * 384, b1, p4, row);
  loadstep(src + 2 * 384, b2, p4, row);
  loadstep(src + 3 * 384, b3, p4, row);
  loadstep(src + 4 * 384, b4, p4, row);
  int s = 0;
  for (; s < T_ - 12; s += 6) {
    const float* sp = src + (size_t)s * 384;
    loadstep(sp + 5 * 384, b5, p4, row);  stepcomp(b0, st, part, ob, (size_t)(s + 0) * C_);
    loadstep(sp + 6 * 384, b0, p4, row);  stepcomp(b1, st, part, ob, (size_t)(s + 1) * C_);
    loadstep(sp + 7 * 384, b1, p4, row);  stepcomp(b2, st, part, ob, (size_t)(s + 2) * C_);
    loadstep(sp + 8 * 384, b2, p4, row);  stepcomp(b3, st, part, ob, (size_t)(s + 3) * C_);
    loadstep(sp + 9 * 384, b3, p4, row);  stepcomp(b4, st, part, ob, (size_t)(s + 4) * C_);
    loadstep(sp + 10 * 384, b4, p4, row); stepcomp(b5, st, part, ob, (size_t)(s + 5) * C_);
  }
  // s == T_-16 + 4 = 1012 -> remaining 12 steps; b0..b4 hold s..s+4
  {
    const float* sp = src + (size_t)s * 384;
    loadstep(sp + 5 * 384, b5, p4, row);  stepcomp(b0, st, part, ob, (size_t)(s + 0) * C_);
    loadstep(sp + 6 * 384, b0, p4, row);  stepcomp(b1, st, part, ob, (size_t)(s + 1) * C_);
    loadstep(sp + 7 * 384, b1, p4, row);  stepcomp(b2, st, part, ob, (size_t)(s + 2) * C_);
    loadstep(sp + 8 * 384, b2, p4, row);  stepcomp(b3, st, part, ob, (size_t)(s + 3) * C_);
    loadstep(sp + 9 * 384, b3, p4, row);  stepcomp(b4, st, part, ob, (size_t)(s + 4) * C_);
    loadstep(sp + 10 * 384, b4, p4, row); stepcomp(b5, st, part, ob, (size_t)(s + 5) * C_);
    s += 6;
  }
  // s == T_-6; b0..b4 hold steps s..s+4
  loadstep(src + (size_t)(T_ - 1) * 384, b5, p4, row);
  stepcomp(b0, st, part, ob, (size_t)(s + 0) * C_);
  stepcomp(b1, st, part, ob, (size_t)(s + 1) * C_);
  stepcomp(b2, st, part, ob, (size_t)(s + 2) * C_);
  stepcomp(b3, st, part, ob, (size_t)(s + 3) * C_);
  stepcomp(b4, st, part, ob, (size_t)(s + 4) * C_);
  stepcomp(b5, st, part, ob, (size_t)(s + 5) * C_);
}

// ---------------- groupnorm + bonus + gate --------------------------------
__global__ __launch_bounds__(256) void gnb_kernel(
    const float* __restrict__ outs, const float* __restrict__ scanin,
    const float* __restrict__ g, const float* __restrict__ rk,
    const float* __restrict__ gw, const float* __restrict__ gb,
    unsigned short* __restrict__ attin) {
  int t = blockIdx.x, tid = threadIdx.x;
  int c = tid * 8, h = tid >> 3, j = c & 63;
  float o[8], gv[8], rkv[8];
  load8f(outs + (size_t)t * C_ + c, o);
  load8f(g + (size_t)t * C_ + c, gv);
  load8f(rk + c, rkv);
  size_t sbase = ((size_t)h * T_ + t) * 384 + j;
  float rv[8], k2[8], vv[8];
  load8f(scanin + sbase + 320, rv);
  load8f(scanin + sbase + 192, k2);
  load8f(scanin + sbase + 256, vv);
  float s = 0.f, q = 0.f, bs = 0.f;
#pragma unroll
  for (int i = 0; i < 8; ++i) {
    s += o[i]; q += o[i] * o[i];
    bs += rv[i] * k2[i] * rkv[i];
  }
  s += __shfl_xor(s, 1); s += __shfl_xor(s, 2); s += __shfl_xor(s, 4);
  q += __shfl_xor(q, 1); q += __shfl_xor(q, 2); q += __shfl_xor(q, 4);
  bs += __shfl_xor(bs, 1); bs += __shfl_xor(bs, 2); bs += __shfl_xor(bs, 4);
  float mean = s * (1.f / NH);
  float var = q * (1.f / NH) - mean * mean;
  float rstd = rsqrtf(var + 0.00064f);
  float res[8];
#pragma unroll
  for (int i = 0; i < 8; ++i) {
    float gn = (o[i] - mean) * rstd * gw[c + i] + gb[c + i];
    res[i] = (gn + bs * vv[i]) * gv[i];
  }
  store8bf(attin + (size_t)t * C_ + c, res);
}

extern "C" void kernel_launch(void* const* d_in, const int* in_sizes, int n_in,
                              void* d_out, int out_size, void* d_ws, size_t ws_size,
                              hipStream_t stream) {
  const float* x       = (const float*)d_in[0];
  const float* xprev_a = (const float*)d_in[1];
  const float* vk0     = (const float*)d_in[2];
  const float* xprev_f = (const float*)d_in[3];
  const float* vfirst  = (const float*)d_in[4];
  const float* ln1w = (const float*)d_in[5];
  const float* ln1b = (const float*)d_in[6];
  const float* m_r = (const float*)d_in[7];
  const float* m_w = (const float*)d_in[8];
  const float* m_k = (const float*)d_in[9];
  const float* m_v = (const float*)d_in[10];
  const float* m_a = (const float*)d_in[11];
  const float* m_g = (const float*)d_in[12];
  const float* w0 = (const float*)d_in[13];
  const float* w1 = (const float*)d_in[14];
  const float* w2 = (const float*)d_in[15];
  const float* a0 = (const float*)d_in[16];
  const float* a1 = (const float*)d_in[17];
  const float* a2 = (const float*)d_in[18];
  const float* v0 = (const float*)d_in[19];
  const float* v1 = (const float*)d_in[20];
  const float* v2 = (const float*)d_in[21];
  const float* g1 = (const float*)d_in[22];
  const float* g2 = (const float*)d_in[23];
  const float* k_k = (const float*)d_in[24];
  const float* k_a = (const float*)d_in[25];
  const float* r_k = (const float*)d_in[26];
  const float* R_ = (const float*)d_in[27];
  const float* K_ = (const float*)d_in[28];
  const float* V_ = (const float*)d_in[29];
  const float* O_ = (const float*)d_in[30];
  const float* lnxw = (const float*)d_in[31];
  const float* lnxb = (const float*)d_in[32];
  const float* ln2w = (const float*)d_in[33];
  const float* ln2b = (const float*)d_in[34];
  const float* fxk = (const float*)d_in[35];
  const float* fK = (const float*)d_in[36];
  const float* fV = (const float*)d_in[37];
  float* out = (float*)d_out;

  char* ws = (char*)d_ws;
  const size_t MB = 1ull << 20;
  // ---- workspace layout (round-9 proven; peak 132 MB) --------------------
  unsigned short* xln   = (unsigned short*)(ws + 0 * MB);    // ph1-2 (4MB)
  unsigned short* attin = (unsigned short*)(ws + 0 * MB);    // ph7-8
  unsigned short* xr    = (unsigned short*)(ws + 4 * MB);    // ph2-3
  unsigned short* xln2  = (unsigned short*)(ws + 4 * MB);    // ph9
  unsigned short* xw    = (unsigned short*)(ws + 8 * MB);    // ph2-4
  unsigned short* xkf   = (unsigned short*)(ws + 8 * MB);    // ph9-10
  unsigned short* xk    = (unsigned short*)(ws + 12 * MB);   // ph2-3
  unsigned short* xv    = (unsigned short*)(ws + 16 * MB);   // ph2-4
  unsigned short* xa    = (unsigned short*)(ws + 20 * MB);   // ph2-4
  unsigned short* xg    = (unsigned short*)(ws + 24 * MB);   // ph2-4
  float* qRKV  = (float*)(ws + 28 * MB);                     // ph3 (6x8MB -> 76)
  float* r_buf = (float*)(ws + 28 * MB);                     // ph3-5 (= qRKV[0] after combine)
  float* k_buf = (float*)(ws + 36 * MB);                     // ph3-5 (= qRKV[1])
  float* v_buf = (float*)(ws + 44 * MB);                     // ph3-5 (= qRKV[2])
  unsigned short* fVt = (unsigned short*)(ws + 28 * MB);     // ph8-11 (32MB)
  float* wpre  = (float*)(ws + 52 * MB);                     // ph4-5 (over qRKV[3], dead after addsk3)
  float* outsb = (float*)(ws + 52 * MB);                     // ph6-7
  float* apre  = (float*)(ws + 60 * MB);                     // ph4-5
  float* x_att = (float*)(ws + 60 * MB);                     // ph8-11
  float* vpre  = (float*)(ws + 68 * MB);                     // ph4-5
  float* g_buf = (float*)(ws + 76 * MB);                     // ph4-7
  float* scanin = (float*)(ws + 84 * MB);                    // ph5-7 (48MB -> 132)
  unsigned short* Rt  = (unsigned short*)(ws + 84 * MB);     // ph3 only
  unsigned short* Kt  = (unsigned short*)(ws + 92 * MB);     // ph3
  unsigned short* Vt  = (unsigned short*)(ws + 100 * MB);    // ph3
  unsigned short* Ot  = (unsigned short*)(ws + 84 * MB);     // ph8 (after gnb)
  float* qO = (float*)(ws + 92 * MB);                        // ph8 (4x8MB -> 124, scanin dead)
  unsigned short* hffn = (unsigned short*)(ws + 84 * MB);    // ph10-11 (16MB, over Ot)
  unsigned short* fKt  = (unsigned short*)(ws + 100 * MB);   // ph10 (32MB -> 132)
  float* pF = (float*)(ws + 100 * MB);                       // ph11 (4x8MB, over dead fKt)
  // lora scratch (ph4 only)
  unsigned short* w1t = (unsigned short*)(ws + 0);
  unsigned short* a1t = (unsigned short*)(ws + 262144);
  unsigned short* v1t = (unsigned short*)(ws + 524288);
  unsigned short* g1t = (unsigned short*)(ws + 786432);
  unsigned short* hwb = (unsigned short*)(ws + 1310720);
  unsigned short* hab = (unsigned short*)(ws + 1441792);
  unsigned short* hvb = (unsigned short*)(ws + 1572864);
  unsigned short* hgb = (unsigned short*)(ws + 1703936);
  float* pw = (float*)(ws + 2 * MB);
  float* pa = (float*)(ws + 4 * MB);
  float* pv = (float*)(ws + 6 * MB);
  float* pg = (float*)(ws + 8 * MB);                         // over xw (dead)
  unsigned short* w2t = (unsigned short*)(ws + 12 * MB);     // over xk (dead)
  unsigned short* a2t = (unsigned short*)(ws + 12 * MB + 262144);
  unsigned short* v2t = (unsigned short*)(ws + 12 * MB + 524288);
  unsigned short* g2t = (unsigned short*)(ws + 12 * MB + 786432);

  ln_kernel<<<T_, 256, 0, stream>>>(x, ln1w, ln1b, xln);
  mix6_kernel<<<T_, 256, 0, stream>>>(xln, xprev_a, m_r, m_w, m_k, m_v, m_a, m_g,
                                      xr, xw, xk, xv, xa, xg);
  // big projections: split-K x2 over 3 batches -> 768 blocks, in-place combine
  transpose_kernel<<<dim3(32, 32, 3), 256, 0, stream>>>(R_, K_, V_, Rt, Kt, Vt, C_, C_);
  gemm2ks3_kernel<<<dim3(16, 8, 6), 256, 0, stream>>>(xr, xk, xv, Rt, Kt, Vt,
                                                      qRKV, T_, 1024, C_, C_);
  addsk3_kernel<<<6144, 256, 0, stream>>>(qRKV);
  // lora downs (K-split) + combine + ups (transposed bf16 weights)
  transpose_kernel<<<dim3(1, 32, 3), 256, 0, stream>>>(w1, a1, v1, w1t, a1t, v1t, C_, 64);
  transpose_kernel<<<dim3(2, 32, 1), 256, 0, stream>>>(g1, g1, g1, g1t, g1t, g1t, C_, 128);
  gemm_ks3_kernel<<<dim3(1, 8, 24), 256, 0, stream>>>(xw, xa, xv, w1t, a1t, v1t,
                                                      pw, pa, pv, C_, 64);
  gemm_ks_kernel<<<dim3(2, 8, 8), 256, 0, stream>>>(xg, g1t, pg, C_, 128);
  lora_combine_kernel<<<dim3(T_, 4), 128, 0, stream>>>(pw, pa, pv, pg, hwb, hab, hvb, hgb);
  transpose_kernel<<<dim3(32, 1, 3), 256, 0, stream>>>(w2, a2, v2, w2t, a2t, v2t, 64, C_);
  transpose_kernel<<<dim3(32, 2, 1), 256, 0, stream>>>(g2, g2, g2, g2t, g2t, g2t, 128, C_);
  gemm2_kernel<0><<<dim3(16, 8, 3), 256, 0, stream>>>(hwb, hab, hvb, w2t, a2t, v2t,
                                                      wpre, apre, vpre, nullptr, T_, 64, C_);
  gemm2_kernel<0><<<dim3(16, 8, 1), 256, 0, stream>>>(hgb, hgb, hgb, g2t, g2t, g2t,
                                                      g_buf, g_buf, g_buf, nullptr, T_, 128, C_);
  // scan
  post_kernel<<<T_, 256, 0, stream>>>(k_buf, v_buf, r_buf, wpre, apre, vpre, vfirst,
                                      w0, a0, v0, k_k, k_a, scanin);
  scan5_kernel<<<512, 64, 0, stream>>>(scanin, vk0, outsb);
  gnb_kernel<<<T_, 256, 0, stream>>>(outsb, scanin, g_buf, r_k, lnxw, lnxb, attin);
  // output proj (split-K x4) + CMix
  transpose_kernel<<<dim3(32, 32, 1), 256, 0, stream>>>(O_, O_, O_, Ot, Ot, Ot, C_, C_);
  transpose_kernel<<<dim3(32, 128, 1), 256, 0, stream>>>(fV, fV, fV, fVt, fVt, fVt, 4 * C_, C_);
  gemm2ks_kernel<<<dim3(16, 8, 4), 256, 0, stream>>>(attin, Ot, qO, T_, 512, C_, C_);
  add5_kernel<<<2048, 256, 0, stream>>>(x, qO, x_att);
  ln_kernel<<<T_, 256, 0, stream>>>(x_att, ln2w, ln2b, xln2);
  mix1_kernel<<<T_, 256, 0, stream>>>(xln2, xprev_f, fxk, xkf);
  transpose_kernel<<<dim3(128, 32, 1), 256, 0, stream>>>(fK, fK, fK, fKt, fKt, fKt, C_, 4 * C_);
  gemm2_kernel<2><<<dim3(64, 8, 1), 256, 0, stream>>>(xkf, xkf, xkf, fKt, fKt, fKt,
                                                      hffn, hffn, hffn, nullptr, T_, C_, 4 * C_);
  gemm2ks_kernel<<<dim3(16, 8, 4), 256, 0, stream>>>(hffn, fVt, pF, T_, 2048, 4 * C_, C_);
  add5_kernel<<<2048, 256, 0, stream>>>(x_att, pF, out);
}

// Round 13
// 487.529 us; speedup vs baseline: 1.0188x; 1.0188x over previous
//
#include <hip/hip_runtime.h>
#include <hip/hip_bf16.h>

// RWKV-7 block (TMix + CMix) for T=1024, C=2048, H=32, N=64 on gfx950.

#define T_ 1024
#define C_ 2048
#define H_ 32
#define NH 64

typedef __attribute__((ext_vector_type(8))) short short8v;
typedef __attribute__((ext_vector_type(4))) float f32x4;

__device__ __forceinline__ float bf2f(unsigned short u) {
  union { float f; unsigned int i; } c; c.i = ((unsigned int)u) << 16; return c.f;
}
__device__ __forceinline__ unsigned short f2bf(float f) {
  union { float f; unsigned int i; } c; c.f = f;
  unsigned int x = c.i;
  return (unsigned short)((x + 0x7fffu + ((x >> 16) & 1u)) >> 16); // RNE
}
__device__ __forceinline__ float sigm(float x) { return 1.f / (1.f + __expf(-x)); }

__device__ __forceinline__ void load8bf(const unsigned short* p, float* o) {
  union { int4 v; unsigned short u[8]; } c;
  c.v = *(const int4*)p;
#pragma unroll
  for (int i = 0; i < 8; ++i) o[i] = bf2f(c.u[i]);
}
__device__ __forceinline__ void store8bf(unsigned short* p, const float* o) {
  union { int4 v; unsigned short u[8]; } c;
#pragma unroll
  for (int i = 0; i < 8; ++i) c.u[i] = f2bf(o[i]);
  *(int4*)p = c.v;
}
__device__ __forceinline__ void load8f(const float* p, float* o) {
  float4 a = ((const float4*)p)[0], b = ((const float4*)p)[1];
  o[0] = a.x; o[1] = a.y; o[2] = a.z; o[3] = a.w;
  o[4] = b.x; o[5] = b.y; o[6] = b.z; o[7] = b.w;
}
__device__ __forceinline__ void load4f(const float* p, float* o) {
  float4 a = *(const float4*)p;
  o[0] = a.x; o[1] = a.y; o[2] = a.z; o[3] = a.w;
}

#define GLD16(g, l)                                                        \
  __builtin_amdgcn_global_load_lds(                                        \
      (const __attribute__((address_space(1))) void*)(g),                  \
      (__attribute__((address_space(3))) void*)(l), 16, 0, 0)

// ---------------- fused LN + 6-way token-shift mix ------------------------
// Each block normalizes rows t and t-1 of fp32 x (t=0 uses raw xprev).
__global__ __launch_bounds__(256) void lnmix6_kernel(
    const float* __restrict__ x, const float* __restrict__ xprev,
    const float* __restrict__ lw, const float* __restrict__ lb,
    const float* __restrict__ mr, const float* __restrict__ mw,
    const float* __restrict__ mk, const float* __restrict__ mv,
    const float* __restrict__ ma, const float* __restrict__ mg,
    unsigned short* xr, unsigned short* xw, unsigned short* xk,
    unsigned short* xv, unsigned short* xa, unsigned short* xg) {
  int t = blockIdx.x, tid = threadIdx.x, c = tid * 8;
  float cur[8], prv[8];
  load8f(x + (size_t)t * C_ + c, cur);
  if (t == 0) load8f(xprev + c, prv);
  else load8f(x + (size_t)(t - 1) * C_ + c, prv);
  float sc = 0.f, qc = 0.f, sp = 0.f, qp = 0.f;
#pragma unroll
  for (int i = 0; i < 8; ++i) {
    sc += cur[i]; qc += cur[i] * cur[i];
    sp += prv[i]; qp += prv[i] * prv[i];
  }
  for (int m = 1; m < 64; m <<= 1) {
    sc += __shfl_xor(sc, m); qc += __shfl_xor(qc, m);
    sp += __shfl_xor(sp, m); qp += __shfl_xor(qp, m);
  }
  __shared__ float r4[4][4];
  if ((tid & 63) == 0) {
    r4[tid >> 6][0] = sc; r4[tid >> 6][1] = qc;
    r4[tid >> 6][2] = sp; r4[tid >> 6][3] = qp;
  }
  __syncthreads();
  sc = r4[0][0] + r4[1][0] + r4[2][0] + r4[3][0];
  qc = r4[0][1] + r4[1][1] + r4[2][1] + r4[3][1];
  sp = r4[0][2] + r4[1][2] + r4[2][2] + r4[3][2];
  qp = r4[0][3] + r4[1][3] + r4[2][3] + r4[3][3];
  float mc = sc * (1.f / C_);
  float rc = rsqrtf(qc * (1.f / C_) - mc * mc + 1e-5f);
  float mp = sp * (1.f / C_);
  float rp = rsqrtf(qp * (1.f / C_) - mp * mp + 1e-5f);
  float cw[8], cb[8];
  load8f(lw + c, cw); load8f(lb + c, cb);
  float curn[8], prvn[8];
#pragma unroll
  for (int i = 0; i < 8; ++i) {
    curn[i] = (cur[i] - mc) * rc * cw[i] + cb[i];
    prvn[i] = (t == 0) ? prv[i] : (prv[i] - mp) * rp * cw[i] + cb[i];
  }
  float cf[8], o[8];
  const float* coefs[6] = {mr, mw, mk, mv, ma, mg};
  unsigned short* outs6[6] = {xr, xw, xk, xv, xa, xg};
#pragma unroll
  for (int a = 0; a < 6; ++a) {
    load8f(coefs[a] + c, cf);
#pragma unroll
    for (int i = 0; i < 8; ++i) o[i] = curn[i] + (prvn[i] - curn[i]) * cf[i];
    store8bf(outs6[a] + (size_t)t * C_ + c, o);
  }
}

// ---------------- fused LN + 1-way mix (CMix) -----------------------------
__global__ __launch_bounds__(256) void lnmix1_kernel(
    const float* __restrict__ x, const float* __restrict__ xprev,
    const float* __restrict__ lw, const float* __restrict__ lb,
    const float* __restrict__ coef, unsigned short* __restrict__ out) {
  int t = blockIdx.x, tid = threadIdx.x, c = tid * 8;
  float cur[8], prv[8];
  load8f(x + (size_t)t * C_ + c, cur);
  if (t == 0) load8f(xprev + c, prv);
  else load8f(x + (size_t)(t - 1) * C_ + c, prv);
  float sc = 0.f, qc = 0.f, sp = 0.f, qp = 0.f;
#pragma unroll
  for (int i = 0; i < 8; ++i) {
    sc += cur[i]; qc += cur[i] * cur[i];
    sp += prv[i]; qp += prv[i] * prv[i];
  }
  for (int m = 1; m < 64; m <<= 1) {
    sc += __shfl_xor(sc, m); qc += __shfl_xor(qc, m);
    sp += __shfl_xor(sp, m); qp += __shfl_xor(qp, m);
  }
  __shared__ float r4[4][4];
  if ((tid & 63) == 0) {
    r4[tid >> 6][0] = sc; r4[tid >> 6][1] = qc;
    r4[tid >> 6][2] = sp; r4[tid >> 6][3] = qp;
  }
  __syncthreads();
  sc = r4[0][0] + r4[1][0] + r4[2][0] + r4[3][0];
  qc = r4[0][1] + r4[1][1] + r4[2][1] + r4[3][1];
  sp = r4[0][2] + r4[1][2] + r4[2][2] + r4[3][2];
  qp = r4[0][3] + r4[1][3] + r4[2][3] + r4[3][3];
  float mc = sc * (1.f / C_);
  float rc = rsqrtf(qc * (1.f / C_) - mc * mc + 1e-5f);
  float mp = sp * (1.f / C_);
  float rp = rsqrtf(qp * (1.f / C_) - mp * mp + 1e-5f);
  float cw[8], cb[8], cf[8], o[8];
  load8f(lw + c, cw); load8f(lb + c, cb); load8f(coef + c, cf);
#pragma unroll
  for (int i = 0; i < 8; ++i) {
    float cn = (cur[i] - mc) * rc * cw[i] + cb[i];
    float pn = (t == 0) ? prv[i] : (prv[i] - mp) * rp * cw[i] + cb[i];
    o[i] = cn + (pn - cn) * cf[i];
  }
  store8bf(out + (size_t)t * C_ + c, o);
}

// ---------------- tiled transpose: fp32 [R][Cc] -> bf16 [Cc][R] -----------
__global__ __launch_bounds__(256) void transpose_kernel(
    const float* in0, const float* in1, const float* in2,
    unsigned short* o0, unsigned short* o1, unsigned short* o2,
    int R, int Cc) {
  const float* in = blockIdx.z == 0 ? in0 : (blockIdx.z == 1 ? in1 : in2);
  unsigned short* out = blockIdx.z == 0 ? o0 : (blockIdx.z == 1 ? o1 : o2);
  __shared__ __align__(16) unsigned short tile[64][80];
  int c0 = blockIdx.x * 64, r0 = blockIdx.y * 64;
  int rr = threadIdx.x >> 4, cq = threadIdx.x & 15;
#pragma unroll
  for (int i = 0; i < 4; ++i) {
    int r = rr + i * 16;
    float4 v = *(const float4*)(in + (size_t)(r0 + r) * Cc + c0 + cq * 4);
    tile[cq * 4 + 0][r] = f2bf(v.x);
    tile[cq * 4 + 1][r] = f2bf(v.y);
    tile[cq * 4 + 2][r] = f2bf(v.z);
    tile[cq * 4 + 3][r] = f2bf(v.w);
  }
  __syncthreads();
  int cr = threadIdx.x >> 2, rg = threadIdx.x & 3;
  int4 w0 = *(const int4*)&tile[cr][rg * 16];
  int4 w1 = *(const int4*)&tile[cr][rg * 16 + 8];
  unsigned short* op = out + (size_t)(c0 + cr) * R + r0 + rg * 16;
  *(int4*)op = w0;
  *(int4*)(op + 8) = w1;
}

// ---------------- 2-phase double-buffered bf16 GEMM: A[M,K] x Bt[N,K]^T ---
// EPI: 0=f32 store, 1=f32 addsrc+acc, 2=relu^2 -> bf16
template <int EPI>
__global__ __launch_bounds__(256) void gemm2_kernel(
    const unsigned short* A0, const unsigned short* A1, const unsigned short* A2,
    const unsigned short* B0, const unsigned short* B1, const unsigned short* B2,
    void* C0, void* C1, void* C2, const float* __restrict__ addsrc,
    int M, int K, int N) {
  int z = blockIdx.z;
  const unsigned short* A = z == 0 ? A0 : (z == 1 ? A1 : A2);
  const unsigned short* Bt = z == 0 ? B0 : (z == 1 ? B1 : B2);
  void* Cout = z == 0 ? C0 : (z == 1 ? C1 : C2);
  __shared__ __align__(16) unsigned short As[2][128 * 32];
  __shared__ __align__(16) unsigned short Bs[2][128 * 32];
  const int tid = threadIdx.x, lane = tid & 63, wid = tid >> 6;
  const int bm = blockIdx.y * 128, bn = blockIdx.x * 128;
  const int wr = wid >> 1, wc = wid & 1;
  const int mrow = lane & 15, krow = lane >> 4;
  auto stage = [&](int buf, int kt) {
#pragma unroll
    for (int q = 0; q < 2; ++q) {
      int s = q * 2048 + tid * 8;
      int m = s >> 5, k = s & 31;
      GLD16(A + (size_t)(bm + m) * K + kt + k, &As[buf][s]);
      GLD16(Bt + (size_t)(bn + m) * K + kt + k, &Bs[buf][s]);
    }
  };
  f32x4 acc[4][4] = {};
  stage(0, 0);
  __syncthreads();
  int buf = 0;
  for (int kt = 0; kt < K; kt += 32) {
    if (kt + 32 < K) stage(buf ^ 1, kt + 32);
    short8v af[4], bfrag[4];
#pragma unroll
    for (int i = 0; i < 4; ++i)
      af[i] = *(const short8v*)&As[buf][(wr * 64 + i * 16 + mrow) * 32 + krow * 8];
#pragma unroll
    for (int j = 0; j < 4; ++j)
      bfrag[j] = *(const short8v*)&Bs[buf][(wc * 64 + j * 16 + mrow) * 32 + krow * 8];
#pragma unroll
    for (int i = 0; i < 4; ++i)
#pragma unroll
      for (int j = 0; j < 4; ++j)
        acc[i][j] = __builtin_amdgcn_mfma_f32_16x16x32_bf16(af[i], bfrag[j], acc[i][j], 0, 0, 0);
    __syncthreads();
    buf ^= 1;
  }
#pragma unroll
  for (int i = 0; i < 4; ++i)
#pragma unroll
    for (int j = 0; j < 4; ++j)
#pragma unroll
      for (int e = 0; e < 4; ++e) {
        int grow = bm + wr * 64 + i * 16 + (lane >> 4) * 4 + e;
        int gcol = bn + wc * 64 + j * 16 + (lane & 15);
        size_t off = (size_t)grow * N + gcol;
        float v = acc[i][j][e];
        if constexpr (EPI == 0) ((float*)Cout)[off] = v;
        else if constexpr (EPI == 1) ((float*)Cout)[off] = addsrc[off] + v;
        else { float r = v > 0.f ? v : 0.f; ((unsigned short*)Cout)[off] = f2bf(r * r); }
      }
}

// ---------------- split-K variant: z = K-slice index, fp32 partials -------
__global__ __launch_bounds__(256) void gemm2ks_kernel(
    const unsigned short* __restrict__ A, const unsigned short* __restrict__ Bt,
    float* __restrict__ P, int M, int KH, int Ktot, int N) {
  int kz = blockIdx.z;
  const size_t kbase = (size_t)kz * KH;
  __shared__ __align__(16) unsigned short As[2][128 * 32];
  __shared__ __align__(16) unsigned short Bs[2][128 * 32];
  const int tid = threadIdx.x, lane = tid & 63, wid = tid >> 6;
  const int bm = blockIdx.y * 128, bn = blockIdx.x * 128;
  const int wr = wid >> 1, wc = wid & 1;
  const int mrow = lane & 15, krow = lane >> 4;
  auto stage = [&](int buf, int kt) {
#pragma unroll
    for (int q = 0; q < 2; ++q) {
      int s = q * 2048 + tid * 8;
      int m = s >> 5, k = s & 31;
      GLD16(A + (size_t)(bm + m) * Ktot + kbase + kt + k, &As[buf][s]);
      GLD16(Bt + (size_t)(bn + m) * Ktot + kbase + kt + k, &Bs[buf][s]);
    }
  };
  f32x4 acc[4][4] = {};
  stage(0, 0);
  __syncthreads();
  int buf = 0;
  for (int kt = 0; kt < KH; kt += 32) {
    if (kt + 32 < KH) stage(buf ^ 1, kt + 32);
    short8v af[4], bfrag[4];
#pragma unroll
    for (int i = 0; i < 4; ++i)
      af[i] = *(const short8v*)&As[buf][(wr * 64 + i * 16 + mrow) * 32 + krow * 8];
#pragma unroll
    for (int j = 0; j < 4; ++j)
      bfrag[j] = *(const short8v*)&Bs[buf][(wc * 64 + j * 16 + mrow) * 32 + krow * 8];
#pragma unroll
    for (int i = 0; i < 4; ++i)
#pragma unroll
      for (int j = 0; j < 4; ++j)
        acc[i][j] = __builtin_amdgcn_mfma_f32_16x16x32_bf16(af[i], bfrag[j], acc[i][j], 0, 0, 0);
    __syncthreads();
    buf ^= 1;
  }
  float* Pz = P + (size_t)kz * M * N;
#pragma unroll
  for (int i = 0; i < 4; ++i)
#pragma unroll
    for (int j = 0; j < 4; ++j)
#pragma unroll
      for (int e = 0; e < 4; ++e) {
        int grow = bm + wr * 64 + i * 16 + (lane >> 4) * 4 + e;
        int gcol = bn + wc * 64 + j * 16 + (lane & 15);
        Pz[(size_t)grow * N + gcol] = acc[i][j][e];
      }
}

// ---------------- split-K x 3-batch variant (rkv): z = kz*3 + batch -------
__global__ __launch_bounds__(256) void gemm2ks3_kernel(
    const unsigned short* A0, const unsigned short* A1, const unsigned short* A2,
    const unsigned short* B0, const unsigned short* B1, const unsigned short* B2,
    float* __restrict__ P, int M, int KH, int Ktot, int N) {
  int z = blockIdx.z;
  int batch = z % 3, kz = z / 3;
  const unsigned short* A = batch == 0 ? A0 : (batch == 1 ? A1 : A2);
  const unsigned short* Bt = batch == 0 ? B0 : (batch == 1 ? B1 : B2);
  const size_t kbase = (size_t)kz * KH;
  __shared__ __align__(16) unsigned short As[2][128 * 32];
  __shared__ __align__(16) unsigned short Bs[2][128 * 32];
  const int tid = threadIdx.x, lane = tid & 63, wid = tid >> 6;
  const int bm = blockIdx.y * 128, bn = blockIdx.x * 128;
  const int wr = wid >> 1, wc = wid & 1;
  const int mrow = lane & 15, krow = lane >> 4;
  auto stage = [&](int buf, int kt) {
#pragma unroll
    for (int q = 0; q < 2; ++q) {
      int s = q * 2048 + tid * 8;
      int m = s >> 5, k = s & 31;
      GLD16(A + (size_t)(bm + m) * Ktot + kbase + kt + k, &As[buf][s]);
      GLD16(Bt + (size_t)(bn + m) * Ktot + kbase + kt + k, &Bs[buf][s]);
    }
  };
  f32x4 acc[4][4] = {};
  stage(0, 0);
  __syncthreads();
  int buf = 0;
  for (int kt = 0; kt < KH; kt += 32) {
    if (kt + 32 < KH) stage(buf ^ 1, kt + 32);
    short8v af[4], bfrag[4];
#pragma unroll
    for (int i = 0; i < 4; ++i)
      af[i] = *(const short8v*)&As[buf][(wr * 64 + i * 16 + mrow) * 32 + krow * 8];
#pragma unroll
    for (int j = 0; j < 4; ++j)
      bfrag[j] = *(const short8v*)&Bs[buf][(wc * 64 + j * 16 + mrow) * 32 + krow * 8];
#pragma unroll
    for (int i = 0; i < 4; ++i)
#pragma unroll
      for (int j = 0; j < 4; ++j)
        acc[i][j] = __builtin_amdgcn_mfma_f32_16x16x32_bf16(af[i], bfrag[j], acc[i][j], 0, 0, 0);
    __syncthreads();
    buf ^= 1;
  }
  float* Pz = P + (size_t)z * M * N;
#pragma unroll
  for (int i = 0; i < 4; ++i)
#pragma unroll
    for (int j = 0; j < 4; ++j)
#pragma unroll
      for (int e = 0; e < 4; ++e) {
        int grow = bm + wr * 64 + i * 16 + (lane >> 4) * 4 + e;
        int gcol = bn + wc * 64 + j * 16 + (lane & 15);
        Pz[(size_t)grow * N + gcol] = acc[i][j][e];
      }
}

// ---------------- o = a + p0+p1+p2+p3 (partials at stride T*C) ------------
__global__ __launch_bounds__(256) void add5_kernel(
    const float* __restrict__ a, const float* __restrict__ p,
    float* __restrict__ o) {
  size_t i = ((size_t)blockIdx.x * 256 + threadIdx.x) * 4;
  const size_t TC = (size_t)T_ * C_;
  float4 va = *(const float4*)(a + i);
  float4 v0 = *(const float4*)(p + i);
  float4 v1 = *(const float4*)(p + i + TC);
  float4 v2 = *(const float4*)(p + i + 2 * TC);
  float4 v3 = *(const float4*)(p + i + 3 * TC);
  float4 r;
  r.x = va.x + v0.x + v1.x + v2.x + v3.x;
  r.y = va.y + v0.y + v1.y + v2.y + v3.y;
  r.z = va.z + v0.z + v1.z + v2.z + v3.z;
  r.w = va.w + v0.w + v1.w + v2.w + v3.w;
  *(float4*)(o + i) = r;
}

// ---------------- K-split lora-down GEMMs (BN=64, z=mat*8+kz) -------------
__global__ __launch_bounds__(256) void gemm_ks3_kernel(
    const unsigned short* A0, const unsigned short* A1, const unsigned short* A2,
    const unsigned short* B0, const unsigned short* B1, const unsigned short* B2,
    float* P0, float* P1, float* P2, int K, int N) {
  int mz = blockIdx.z >> 3, kz = blockIdx.z & 7;
  const unsigned short* A = mz == 0 ? A0 : (mz == 1 ? A1 : A2);
  const unsigned short* Bt = mz == 0 ? B0 : (mz == 1 ? B1 : B2);
  float* partial = mz == 0 ? P0 : (mz == 1 ? P1 : P2);
  __shared__ __align__(16) unsigned short As[2][128 * 32];
  __shared__ __align__(16) unsigned short Bs[2][64 * 32];
  const int tid = threadIdx.x, lane = tid & 63, wid = tid >> 6;
  const int bn = blockIdx.x * 64, bm = blockIdx.y * 128;
  const int wr = wid >> 1, wc = wid & 1;
  const int mrow = lane & 15, krow = lane >> 4;
  auto stage = [&](int buf, int kt) {
#pragma unroll
    for (int q = 0; q < 2; ++q) {
      int s = q * 2048 + tid * 8;
      int m = s >> 5, k = s & 31;
      GLD16(A + (size_t)(bm + m) * K + kt + k, &As[buf][s]);
    }
    {
      int s = tid * 8;
      int n = s >> 5, k = s & 31;
      GLD16(Bt + (size_t)(bn + n) * K + kt + k, &Bs[buf][s]);
    }
  };
  f32x4 acc[4][2] = {};
  int k0 = kz * 256;
  stage(0, k0);
  __syncthreads();
  int buf = 0;
  for (int kt = k0; kt < k0 + 256; kt += 32) {
    if (kt + 32 < k0 + 256) stage(buf ^ 1, kt + 32);
    short8v af[4], bfrag[2];
#pragma unroll
    for (int i = 0; i < 4; ++i)
      af[i] = *(const short8v*)&As[buf][(wr * 64 + i * 16 + mrow) * 32 + krow * 8];
#pragma unroll
    for (int j = 0; j < 2; ++j)
      bfrag[j] = *(const short8v*)&Bs[buf][(wc * 32 + j * 16 + mrow) * 32 + krow * 8];
#pragma unroll
    for (int i = 0; i < 4; ++i)
#pragma unroll
      for (int j = 0; j < 2; ++j)
        acc[i][j] = __builtin_amdgcn_mfma_f32_16x16x32_bf16(af[i], bfrag[j], acc[i][j], 0, 0, 0);
    __syncthreads();
    buf ^= 1;
  }
#pragma unroll
  for (int i = 0; i < 4; ++i)
#pragma unroll
    for (int j = 0; j < 2; ++j)
#pragma unroll
      for (int e = 0; e < 4; ++e) {
        int row = bm + wr * 64 + i * 16 + (lane >> 4) * 4 + e;
        int col = bn + wc * 32 + j * 16 + (lane & 15);
        partial[((size_t)kz * 1024 + row) * N + col] = acc[i][j][e];
      }
}

__global__ __launch_bounds__(256) void gemm_ks_kernel(
    const unsigned short* __restrict__ A, const unsigned short* __restrict__ Bt,
    float* __restrict__ partial, int K, int N) {
  __shared__ __align__(16) unsigned short As[2][128 * 32];
  __shared__ __align__(16) unsigned short Bs[2][64 * 32];
  const int tid = threadIdx.x, lane = tid & 63, wid = tid >> 6;
  const int bn = blockIdx.x * 64, bm = blockIdx.y * 128, kz = blockIdx.z;
  const int wr = wid >> 1, wc = wid & 1;
  const int mrow = lane & 15, krow = lane >> 4;
  auto stage = [&](int buf, int kt) {
#pragma unroll
    for (int q = 0; q < 2; ++q) {
      int s = q * 2048 + tid * 8;
      int m = s >> 5, k = s & 31;
      GLD16(A + (size_t)(bm + m) * K + kt + k, &As[buf][s]);
    }
    {
      int s = tid * 8;
      int n = s >> 5, k = s & 31;
      GLD16(Bt + (size_t)(bn + n) * K + kt + k, &Bs[buf][s]);
    }
  };
  f32x4 acc[4][2] = {};
  int k0 = kz * 256;
  stage(0, k0);
  __syncthreads();
  int buf = 0;
  for (int kt = k0; kt < k0 + 256; kt += 32) {
    if (kt + 32 < k0 + 256) stage(buf ^ 1, kt + 32);
    short8v af[4], bfrag[2];
#pragma unroll
    for (int i = 0; i < 4; ++i)
      af[i] = *(const short8v*)&As[buf][(wr * 64 + i * 16 + mrow) * 32 + krow * 8];
#pragma unroll
    for (int j = 0; j < 2; ++j)
      bfrag[j] = *(const short8v*)&Bs[buf][(wc * 32 + j * 16 + mrow) * 32 + krow * 8];
#pragma unroll
    for (int i = 0; i < 4; ++i)
#pragma unroll
      for (int j = 0; j < 2; ++j)
        acc[i][j] = __builtin_amdgcn_mfma_f32_16x16x32_bf16(af[i], bfrag[j], acc[i][j], 0, 0, 0);
    __syncthreads();
    buf ^= 1;
  }
#pragma unroll
  for (int i = 0; i < 4; ++i)
#pragma unroll
    for (int j = 0; j < 2; ++j)
#pragma unroll
      for (int e = 0; e < 4; ++e) {
        int row = bm + wr * 64 + i * 16 + (lane >> 4) * 4 + e;
        int col = bn + wc * 32 + j * 16 + (lane & 15);
        partial[((size_t)kz * 1024 + row) * N + col] = acc[i][j][e];
      }
}

__global__ __launch_bounds__(128) void lora_combine_kernel(
    const float* __restrict__ pw, const float* __restrict__ pa,
    const float* __restrict__ pv, const float* __restrict__ pg,
    unsigned short* __restrict__ hw, unsigned short* __restrict__ ha,
    unsigned short* __restrict__ hv, unsigned short* __restrict__ hg) {
  int t = blockIdx.x, which = blockIdx.y, tid = threadIdx.x;
  int Nl = (which == 3) ? 128 : 64;
  if (tid >= Nl) return;
  const float* p = which == 0 ? pw : which == 1 ? pa : which == 2 ? pv : pg;
  float s = 0.f;
#pragma unroll
  for (int kz = 0; kz < 8; ++kz) s += p[((size_t)kz * 1024 + t) * Nl + tid];
  float r = which == 0 ? tanhf(s) : (which == 3 ? sigm(s) : s);
  unsigned short* o = which == 0 ? hw : which == 1 ? ha : which == 2 ? hv : hg;
  o[t * Nl + tid] = f2bf(r);
}

// ---------------- post: rkv split-K combine + pack scan inputs (fp32) -----
// scanin[h][t][6][64] fp32: seg 0=w, 1=kkn, 2=-kkn*a, 3=k2, 4=v, 5=r
__global__ __launch_bounds__(256) void post_kernel(
    const float* __restrict__ qRKV, const float* __restrict__ wpre,
    const float* __restrict__ apre, const float* __restrict__ vpre,
    const float* __restrict__ vfirst, const float* __restrict__ w0,
    const float* __restrict__ a0, const float* __restrict__ v0_,
    const float* __restrict__ k_k, const float* __restrict__ k_a,
    float* __restrict__ scanin) {
  int t = blockIdx.x, tid = threadIdx.x;
  int c = tid * 8, h = tid >> 3, j = c & 63;
  size_t o = (size_t)t * C_ + c;
  const size_t TC = (size_t)T_ * C_;
  float rv[8], kv[8], vv[8], t0[8], wv[8], av[8], vp[8], vf[8];
  load8f(qRKV + o, rv);          load8f(qRKV + 3 * TC + o, t0);
#pragma unroll
  for (int i = 0; i < 8; ++i) rv[i] += t0[i];
  load8f(qRKV + TC + o, kv);     load8f(qRKV + 4 * TC + o, t0);
#pragma unroll
  for (int i = 0; i < 8; ++i) kv[i] += t0[i];
  load8f(qRKV + 2 * TC + o, vv); load8f(qRKV + 5 * TC + o, t0);
#pragma unroll
  for (int i = 0; i < 8; ++i) vv[i] += t0[i];
  load8f(wpre + o, wv); load8f(apre + o, av); load8f(vpre + o, vp);
  load8f(vfirst + o, vf);
  float ckk[8], cka[8], cw0[8], ca0[8], cv0[8];
  load8f(k_k + c, ckk); load8f(k_a + c, cka); load8f(w0 + c, cw0);
  load8f(a0 + c, ca0); load8f(v0_ + c, cv0);
  float kk[8]; float ss = 0.f;
#pragma unroll
  for (int i = 0; i < 8; ++i) { kk[i] = kv[i] * ckk[i]; ss += kk[i] * kk[i]; }
  ss += __shfl_xor(ss, 1); ss += __shfl_xor(ss, 2); ss += __shfl_xor(ss, 4);
  float rdn = 1.f / fmaxf(sqrtf(ss), 1e-12f);
  float sw[8], skn[8], scc[8], sk2[8], sv[8];
#pragma unroll
  for (int i = 0; i < 8; ++i) {
    float kkn = kk[i] * rdn;
    float a = sigm(ca0[i] + av[i]);
    skn[i] = kkn;
    scc[i] = -kkn * a;
    sk2[i] = kv[i] * (1.f + (a - 1.f) * cka[i]);
    float sg = sigm(cv0[i] + vp[i]);
    sv[i] = vv[i] + (vf[i] - vv[i]) * sg;
    sw[i] = __expf(-0.606531f * sigm(cw0[i] + wv[i]));
  }
  float* bp = scanin + ((size_t)h * T_ + t) * 384 + j;
  ((float4*)(bp + 0))[0]   = make_float4(sw[0], sw[1], sw[2], sw[3]);
  ((float4*)(bp + 4))[0]   = make_float4(sw[4], sw[5], sw[6], sw[7]);
  ((float4*)(bp + 64))[0]  = make_float4(skn[0], skn[1], skn[2], skn[3]);
  ((float4*)(bp + 68))[0]  = make_float4(skn[4], skn[5], skn[6], skn[7]);
  ((float4*)(bp + 128))[0] = make_float4(scc[0], scc[1], scc[2], scc[3]);
  ((float4*)(bp + 132))[0] = make_float4(scc[4], scc[5], scc[6], scc[7]);
  ((float4*)(bp + 192))[0] = make_float4(sk2[0], sk2[1], sk2[2], sk2[3]);
  ((float4*)(bp + 196))[0] = make_float4(sk2[4], sk2[5], sk2[6], sk2[7]);
  ((float4*)(bp + 256))[0] = make_float4(sv[0], sv[1], sv[2], sv[3]);
  ((float4*)(bp + 260))[0] = make_float4(sv[4], sv[5], sv[6], sv[7]);
  ((float4*)(bp + 320))[0] = make_float4(rv[0], rv[1], rv[2], rv[3]);
  ((float4*)(bp + 324))[0] = make_float4(rv[4], rv[5], rv[6], rv[7]);
}

// ---------------- sequential scan v5: 16 parts x 4 rows, 512 blocks -------
struct SR { float wv[4], nv[4], cv[4], kv[4], rv[4], vvv; };

template <int CTRL>
__device__ __forceinline__ float dppadd(float x) {
  int y = __builtin_amdgcn_update_dpp(0, __float_as_int(x), CTRL, 0xF, 0xF, true);
  return x + __int_as_float(y);
}
// full sum across each 16-lane row, result in all 16 lanes (pure VALU)
__device__ __forceinline__ float red16(float x) {
  x = dppadd<0xB1>(x);
  x = dppadd<0x4E>(x);
  x = dppadd<0x140>(x);
  x = dppadd<0x141>(x);
  return x;
}

__device__ __forceinline__ void loadstep(const float* S, SR& R, int p4, int row) {
  load4f(S + p4, R.wv);
  load4f(S + 64 + p4, R.nv);
  load4f(S + 128 + p4, R.cv);
  load4f(S + 192 + p4, R.kv);
  load4f(S + 320 + p4, R.rv);
  R.vvv = S[256 + row];
}

__device__ __forceinline__ void stepcomp(const SR& R, float* st, int part,
                                         float* __restrict__ ob, size_t oidx) {
  float p0 = fmaf(st[0], R.nv[0], 0.f);
  float p1 = fmaf(st[1], R.nv[1], 0.f);
  p0 = fmaf(st[2], R.nv[2], p0);
  p1 = fmaf(st[3], R.nv[3], p1);
  float sa = red16(p0 + p1);
  float s0 = 0.f, s1 = 0.f;
#pragma unroll
  for (int i = 0; i < 4; ++i) {
    float t = fmaf(st[i], R.wv[i], fmaf(sa, R.cv[i], R.vvv * R.kv[i]));
    st[i] = t;
    if (i & 1) s1 = fmaf(t, R.rv[i], s1);
    else s0 = fmaf(t, R.rv[i], s0);
  }
  float so = red16(s0 + s1);
  if (part == 0) ob[oidx] = so;
}

// 512 blocks = 32 heads x 16 row-groups (head pinned to one XCD);
// 64 thr = 4 rows x 16 parts. Direct global loads, 3-step-deep pipeline.
__global__ __launch_bounds__(64) void scan5_kernel(
    const float* __restrict__ scanin, const float* __restrict__ vk0,
    float* __restrict__ outs) {
  int bid = blockIdx.x;
  int h = (bid & 7) + 8 * ((bid >> 3) & 3);  // h&7 fixed per XCD
  int rg = bid >> 5;                          // 0..15
  int tid = threadIdx.x;
  int part = tid & 15, row = rg * 4 + (tid >> 4);
  int p4 = part * 4;
  float st[4];
  load4f(vk0 + ((size_t)h * NH + row) * NH + p4, st);
  const float* src = scanin + (size_t)h * T_ * 384;
  float* ob = outs + h * NH + row;
  SR A, B, C, D;
  loadstep(src + 0 * 384, A, p4, row);
  loadstep(src + 1 * 384, B, p4, row);
  loadstep(src + 2 * 384, C, p4, row);
  int s = 0;
  for (; s < T_ - 4; s += 4) {
    const float* sp = src + (size_t)s * 384;
    loadstep(sp + 3 * 384, D, p4, row);
    stepcomp(A, st, part, ob, (size_t)(s + 0) * C_);
    loadstep(sp + 4 * 384, A, p4, row);
    stepcomp(B, st, part, ob, (size_t)(s + 1) * C_);
    loadstep(sp + 5 * 384, B, p4, row);
    stepcomp(C, st, part, ob, (size_t)(s + 2) * C_);
    loadstep(sp + 6 * 384, C, p4, row);
    stepcomp(D, st, part, ob, (size_t)(s + 3) * C_);
  }
  // tail: s == T_-4; A,B,C hold s..s+2
  loadstep(src + (size_t)(T_ - 1) * 384, D, p4, row);
  stepcomp(A, st, part, ob, (size_t)(s + 0) * C_);
  stepcomp(B, st, part, ob, (size_t)(s + 1) * C_);
  stepcomp(C, st, part, ob, (size_t)(s + 2) * C_);
  stepcomp(D, st, part, ob, (size_t)(s + 3) * C_);
}

// ---------------- groupnorm + bonus + gate --------------------------------
__global__ __launch_bounds__(256) void gnb_kernel(
    const float* __restrict__ outs, const float* __restrict__ scanin,
    const float* __restrict__ g, const float* __restrict__ rk,
    const float* __restrict__ gw, const float* __restrict__ gb,
    unsigned short* __restrict__ attin) {
  int t = blockIdx.x, tid = threadIdx.x;
  int c = tid * 8, h = tid >> 3, j = c & 63;
  float o[8], gv[8], rkv[8];
  load8f(outs + (size_t)t * C_ + c, o);
  load8f(g + (size_t)t * C_ + c, gv);
  load8f(rk + c, rkv);
  size_t sbase = ((size_t)h * T_ + t) * 384 + j;
  float rv[8], k2[8], vv[8];
  load8f(scanin + sbase + 320, rv);
  load8f(scanin + sbase + 192, k2);
  load8f(scanin + sbase + 256, vv);
  float s = 0.f, q = 0.f, bs = 0.f;
#pragma unroll
  for (int i = 0; i < 8; ++i) {
    s += o[i]; q += o[i] * o[i];
    bs += rv[i] * k2[i] * rkv[i];
  }
  s += __shfl_xor(s, 1); s += __shfl_xor(s, 2); s += __shfl_xor(s, 4);
  q += __shfl_xor(q, 1); q += __shfl_xor(q, 2); q += __shfl_xor(q, 4);
  bs += __shfl_xor(bs, 1); bs += __shfl_xor(bs, 2); bs += __shfl_xor(bs, 4);
  float mean = s * (1.f / NH);
  float var = q * (1.f / NH) - mean * mean;
  float rstd = rsqrtf(var + 0.00064f);
  float res[8];
#pragma unroll
  for (int i = 0; i < 8; ++i) {
    float gn = (o[i] - mean) * rstd * gw[c + i] + gb[c + i];
    res[i] = (gn + bs * vv[i]) * gv[i];
  }
  store8bf(attin + (size_t)t * C_ + c, res);
}

extern "C" void kernel_launch(void* const* d_in, const int* in_sizes, int n_in,
                              void* d_out, int out_size, void* d_ws, size_t ws_size,
                              hipStream_t stream) {
  const float* x       = (const float*)d_in[0];
  const float* xprev_a = (const float*)d_in[1];
  const float* vk0     = (const float*)d_in[2];
  const float* xprev_f = (const float*)d_in[3];
  const float* vfirst  = (const float*)d_in[4];
  const float* ln1w = (const float*)d_in[5];
  const float* ln1b = (const float*)d_in[6];
  const float* m_r = (const float*)d_in[7];
  const float* m_w = (const float*)d_in[8];
  const float* m_k = (const float*)d_in[9];
  const float* m_v = (const float*)d_in[10];
  const float* m_a = (const float*)d_in[11];
  const float* m_g = (const float*)d_in[12];
  const float* w0 = (const float*)d_in[13];
  const float* w1 = (const float*)d_in[14];
  const float* w2 = (const float*)d_in[15];
  const float* a0 = (const float*)d_in[16];
  const float* a1 = (const float*)d_in[17];
  const float* a2 = (const float*)d_in[18];
  const float* v0 = (const float*)d_in[19];
  const float* v1 = (const float*)d_in[20];
  const float* v2 = (const float*)d_in[21];
  const float* g1 = (const float*)d_in[22];
  const float* g2 = (const float*)d_in[23];
  const float* k_k = (const float*)d_in[24];
  const float* k_a = (const float*)d_in[25];
  const float* r_k = (const float*)d_in[26];
  const float* R_ = (const float*)d_in[27];
  const float* K_ = (const float*)d_in[28];
  const float* V_ = (const float*)d_in[29];
  const float* O_ = (const float*)d_in[30];
  const float* lnxw = (const float*)d_in[31];
  const float* lnxb = (const float*)d_in[32];
  const float* ln2w = (const float*)d_in[33];
  const float* ln2b = (const float*)d_in[34];
  const float* fxk = (const float*)d_in[35];
  const float* fK = (const float*)d_in[36];
  const float* fV = (const float*)d_in[37];
  float* out = (float*)d_out;

  char* ws = (char*)d_ws;
  const size_t MB = 1ull << 20;
  // ---- workspace layout (fused-post revision; peak 132 MB) ---------------
  // 0-1.25: w1t..g1t (ph4) then w2t..g2t (ph4b)       [attin 0-4 at ph7+]
  // 1.31-2: hwb..hgb (ph4)
  // 2-4: pw; 4-6: pa; 6-8: pv; 8-12: pg (ph4, over xr/xw dead zones)
  // 4-12: wpre (ph5, over pa/pv/pg dead); 12-20: apre; 20-28: vpre
  // 4-8: xr (ph2-3); 8-12: xw; 12-16: xk; 16-20: xv; 20-24: xa; 24-28: xg
  // 8-12: xkf (ph9-10)
  // 28-76: qRKV (ph3-5, 6x8MB; combined inside post)
  // 28-60: fVt (ph8-11); 52-60: outsb (ph6-7); 60-68: x_att (ph8-11)
  // 76-84: g_buf (ph4-7)
  // 84-132: scanin fp32 (ph5-7); 84-108: Rt/Kt/Vt (ph3); 84-92: Ot (ph8)
  // 92-124: qO (ph8); 84-100: hffn (ph10-11); 100-132: fKt (ph10) / pF (ph11)
  unsigned short* attin = (unsigned short*)(ws + 0 * MB);
  unsigned short* xr    = (unsigned short*)(ws + 4 * MB);
  unsigned short* xw    = (unsigned short*)(ws + 8 * MB);
  unsigned short* xkf   = (unsigned short*)(ws + 8 * MB);
  unsigned short* xk    = (unsigned short*)(ws + 12 * MB);
  unsigned short* xv    = (unsigned short*)(ws + 16 * MB);
  unsigned short* xa    = (unsigned short*)(ws + 20 * MB);
  unsigned short* xg    = (unsigned short*)(ws + 24 * MB);
  float* wpre  = (float*)(ws + 4 * MB);
  float* apre  = (float*)(ws + 12 * MB);
  float* vpre  = (float*)(ws + 20 * MB);
  float* qRKV  = (float*)(ws + 28 * MB);
  unsigned short* fVt = (unsigned short*)(ws + 28 * MB);
  float* outsb = (float*)(ws + 52 * MB);
  float* x_att = (float*)(ws + 60 * MB);
  float* g_buf = (float*)(ws + 76 * MB);
  float* scanin = (float*)(ws + 84 * MB);
  unsigned short* Rt  = (unsigned short*)(ws + 84 * MB);
  unsigned short* Kt  = (unsigned short*)(ws + 92 * MB);
  unsigned short* Vt  = (unsigned short*)(ws + 100 * MB);
  unsigned short* Ot  = (unsigned short*)(ws + 84 * MB);
  float* qO = (float*)(ws + 92 * MB);
  unsigned short* hffn = (unsigned short*)(ws + 84 * MB);
  unsigned short* fKt  = (unsigned short*)(ws + 100 * MB);
  float* pF = (float*)(ws + 100 * MB);
  unsigned short* w1t = (unsigned short*)(ws + 0);
  unsigned short* a1t = (unsigned short*)(ws + 262144);
  unsigned short* v1t = (unsigned short*)(ws + 524288);
  unsigned short* g1t = (unsigned short*)(ws + 786432);
  unsigned short* w2t = (unsigned short*)(ws + 0);
  unsigned short* a2t = (unsigned short*)(ws + 262144);
  unsigned short* v2t = (unsigned short*)(ws + 524288);
  unsigned short* g2t = (unsigned short*)(ws + 786432);
  unsigned short* hwb = (unsigned short*)(ws + 1376256);
  unsigned short* hab = (unsigned short*)(ws + 1507328);
  unsigned short* hvb = (unsigned short*)(ws + 1638400);
  unsigned short* hgb = (unsigned short*)(ws + 1769472);
  float* pw = (float*)(ws + 2 * MB);
  float* pa = (float*)(ws + 4 * MB);
  float* pv = (float*)(ws + 6 * MB);
  float* pg = (float*)(ws + 8 * MB);

  // TMix front: fused LN+mix, projections
  lnmix6_kernel<<<T_, 256, 0, stream>>>(x, xprev_a, ln1w, ln1b,
                                        m_r, m_w, m_k, m_v, m_a, m_g,
                                        xr, xw, xk, xv, xa, xg);
  transpose_kernel<<<dim3(32, 32, 3), 256, 0, stream>>>(R_, K_, V_, Rt, Kt, Vt, C_, C_);
  gemm2ks3_kernel<<<dim3(16, 8, 6), 256, 0, stream>>>(xr, xk, xv, Rt, Kt, Vt,
                                                      qRKV, T_, 1024, C_, C_);
  // loras
  transpose_kernel<<<dim3(1, 32, 3), 256, 0, stream>>>(w1, a1, v1, w1t, a1t, v1t, C_, 64);
  transpose_kernel<<<dim3(2, 32, 1), 256, 0, stream>>>(g1, g1, g1, g1t, g1t, g1t, C_, 128);
  gemm_ks3_kernel<<<dim3(1, 8, 24), 256, 0, stream>>>(xw, xa, xv, w1t, a1t, v1t,
                                                      pw, pa, pv, C_, 64);
  gemm_ks_kernel<<<dim3(2, 8, 8), 256, 0, stream>>>(xg, g1t, pg, C_, 128);
  lora_combine_kernel<<<dim3(T_, 4), 128, 0, stream>>>(pw, pa, pv, pg, hwb, hab, hvb, hgb);
  transpose_kernel<<<dim3(32, 1, 3), 256, 0, stream>>>(w2, a2, v2, w2t, a2t, v2t, 64, C_);
  transpose_kernel<<<dim3(32, 2, 1), 256, 0, stream>>>(g2, g2, g2, g2t, g2t, g2t, 128, C_);
  gemm2_kernel<0><<<dim3(16, 8, 3), 256, 0, stream>>>(hwb, hab, hvb, w2t, a2t, v2t,
                                                      wpre, apre, vpre, nullptr, T_, 64, C_);
  gemm2_kernel<0><<<dim3(16, 8, 1), 256, 0, stream>>>(hgb, hgb, hgb, g2t, g2t, g2t,
                                                      g_buf, g_buf, g_buf, nullptr, T_, 128, C_);
  // scan (post fuses the rkv split-K combine)
  post_kernel<<<T_, 256, 0, stream>>>(qRKV, wpre, apre, vpre, vfirst,
                                      w0, a0, v0, k_k, k_a, scanin);
  scan5_kernel<<<512, 64, 0, stream>>>(scanin, vk0, outsb);
  gnb_kernel<<<T_, 256, 0, stream>>>(outsb, scanin, g_buf, r_k, lnxw, lnxb, attin);
  // output proj (split-K x4) + CMix
  transpose_kernel<<<dim3(32, 32, 1), 256, 0, stream>>>(O_, O_, O_, Ot, Ot, Ot, C_, C_);
  transpose_kernel<<<dim3(32, 128, 1), 256, 0, stream>>>(fV, fV, fV, fVt, fVt, fVt, 4 * C_, C_);
  gemm2ks_kernel<<<dim3(16, 8, 4), 256, 0, stream>>>(attin, Ot, qO, T_, 512, C_, C_);
  add5_kernel<<<2048, 256, 0, stream>>>(x, qO, x_att);
  lnmix1_kernel<<<T_, 256, 0, stream>>>(x_att, xprev_f, ln2w, ln2b, fxk, xkf);
  transpose_kernel<<<dim3(128, 32, 1), 256, 0, stream>>>(fK, fK, fK, fKt, fKt, fKt, C_, 4 * C_);
  gemm2_kernel<2><<<dim3(64, 8, 1), 256, 0, stream>>>(xkf, xkf, xkf, fKt, fKt, fKt,
                                                      hffn, hffn, hffn, nullptr, T_, C_, 4 * C_);
  gemm2ks_kernel<<<dim3(16, 8, 4), 256, 0, stream>>>(hffn, fVt, pF, T_, 2048, 4 * C_, C_);
  add5_kernel<<<2048, 256, 0, stream>>>(x_att, pF, out);
}

// Round 14
// 470.823 us; speedup vs baseline: 1.0549x; 1.0355x over previous
//
#include <hip/hip_runtime.h>
#include <hip/hip_bf16.h>

// RWKV-7 block (TMix + CMix) for T=1024, C=2048, H=32, N=64 on gfx950.

#define T_ 1024
#define C_ 2048
#define H_ 32
#define NH 64

typedef __attribute__((ext_vector_type(8))) short short8v;
typedef __attribute__((ext_vector_type(4))) float f32x4;

__device__ __forceinline__ float bf2f(unsigned short u) {
  union { float f; unsigned int i; } c; c.i = ((unsigned int)u) << 16; return c.f;
}
__device__ __forceinline__ unsigned short f2bf(float f) {
  union { float f; unsigned int i; } c; c.f = f;
  unsigned int x = c.i;
  return (unsigned short)((x + 0x7fffu + ((x >> 16) & 1u)) >> 16); // RNE
}
__device__ __forceinline__ float sigm(float x) { return 1.f / (1.f + __expf(-x)); }

__device__ __forceinline__ void load8bf(const unsigned short* p, float* o) {
  union { int4 v; unsigned short u[8]; } c;
  c.v = *(const int4*)p;
#pragma unroll
  for (int i = 0; i < 8; ++i) o[i] = bf2f(c.u[i]);
}
__device__ __forceinline__ void store8bf(unsigned short* p, const float* o) {
  union { int4 v; unsigned short u[8]; } c;
#pragma unroll
  for (int i = 0; i < 8; ++i) c.u[i] = f2bf(o[i]);
  *(int4*)p = c.v;
}
__device__ __forceinline__ void load8f(const float* p, float* o) {
  float4 a = ((const float4*)p)[0], b = ((const float4*)p)[1];
  o[0] = a.x; o[1] = a.y; o[2] = a.z; o[3] = a.w;
  o[4] = b.x; o[5] = b.y; o[6] = b.z; o[7] = b.w;
}
__device__ __forceinline__ void load4f(const float* p, float* o) {
  float4 a = *(const float4*)p;
  o[0] = a.x; o[1] = a.y; o[2] = a.z; o[3] = a.w;
}

#define GLD16(g, l)                                                        \
  __builtin_amdgcn_global_load_lds(                                        \
      (const __attribute__((address_space(1))) void*)(g),                  \
      (__attribute__((address_space(3))) void*)(l), 16, 0, 0)

// ---------------- fused LN + 6-way token-shift mix ------------------------
__global__ __launch_bounds__(256) void lnmix6_kernel(
    const float* __restrict__ x, const float* __restrict__ xprev,
    const float* __restrict__ lw, const float* __restrict__ lb,
    const float* __restrict__ mr, const float* __restrict__ mw,
    const float* __restrict__ mk, const float* __restrict__ mv,
    const float* __restrict__ ma, const float* __restrict__ mg,
    unsigned short* xr, unsigned short* xw, unsigned short* xk,
    unsigned short* xv, unsigned short* xa, unsigned short* xg) {
  int t = blockIdx.x, tid = threadIdx.x, c = tid * 8;
  float cur[8], prv[8];
  load8f(x + (size_t)t * C_ + c, cur);
  if (t == 0) load8f(xprev + c, prv);
  else load8f(x + (size_t)(t - 1) * C_ + c, prv);
  float sc = 0.f, qc = 0.f, sp = 0.f, qp = 0.f;
#pragma unroll
  for (int i = 0; i < 8; ++i) {
    sc += cur[i]; qc += cur[i] * cur[i];
    sp += prv[i]; qp += prv[i] * prv[i];
  }
  for (int m = 1; m < 64; m <<= 1) {
    sc += __shfl_xor(sc, m); qc += __shfl_xor(qc, m);
    sp += __shfl_xor(sp, m); qp += __shfl_xor(qp, m);
  }
  __shared__ float r4[4][4];
  if ((tid & 63) == 0) {
    r4[tid >> 6][0] = sc; r4[tid >> 6][1] = qc;
    r4[tid >> 6][2] = sp; r4[tid >> 6][3] = qp;
  }
  __syncthreads();
  sc = r4[0][0] + r4[1][0] + r4[2][0] + r4[3][0];
  qc = r4[0][1] + r4[1][1] + r4[2][1] + r4[3][1];
  sp = r4[0][2] + r4[1][2] + r4[2][2] + r4[3][2];
  qp = r4[0][3] + r4[1][3] + r4[2][3] + r4[3][3];
  float mc = sc * (1.f / C_);
  float rc = rsqrtf(qc * (1.f / C_) - mc * mc + 1e-5f);
  float mp = sp * (1.f / C_);
  float rp = rsqrtf(qp * (1.f / C_) - mp * mp + 1e-5f);
  float cw[8], cb[8];
  load8f(lw + c, cw); load8f(lb + c, cb);
  float curn[8], prvn[8];
#pragma unroll
  for (int i = 0; i < 8; ++i) {
    curn[i] = (cur[i] - mc) * rc * cw[i] + cb[i];
    prvn[i] = (t == 0) ? prv[i] : (prv[i] - mp) * rp * cw[i] + cb[i];
  }
  float cf[8], o[8];
  const float* coefs[6] = {mr, mw, mk, mv, ma, mg};
  unsigned short* outs6[6] = {xr, xw, xk, xv, xa, xg};
#pragma unroll
  for (int a = 0; a < 6; ++a) {
    load8f(coefs[a] + c, cf);
#pragma unroll
    for (int i = 0; i < 8; ++i) o[i] = curn[i] + (prvn[i] - curn[i]) * cf[i];
    store8bf(outs6[a] + (size_t)t * C_ + c, o);
  }
}

// ---------------- fused LN + 1-way mix (CMix) -----------------------------
__global__ __launch_bounds__(256) void lnmix1_kernel(
    const float* __restrict__ x, const float* __restrict__ xprev,
    const float* __restrict__ lw, const float* __restrict__ lb,
    const float* __restrict__ coef, unsigned short* __restrict__ out) {
  int t = blockIdx.x, tid = threadIdx.x, c = tid * 8;
  float cur[8], prv[8];
  load8f(x + (size_t)t * C_ + c, cur);
  if (t == 0) load8f(xprev + c, prv);
  else load8f(x + (size_t)(t - 1) * C_ + c, prv);
  float sc = 0.f, qc = 0.f, sp = 0.f, qp = 0.f;
#pragma unroll
  for (int i = 0; i < 8; ++i) {
    sc += cur[i]; qc += cur[i] * cur[i];
    sp += prv[i]; qp += prv[i] * prv[i];
  }
  for (int m = 1; m < 64; m <<= 1) {
    sc += __shfl_xor(sc, m); qc += __shfl_xor(qc, m);
    sp += __shfl_xor(sp, m); qp += __shfl_xor(qp, m);
  }
  __shared__ float r4[4][4];
  if ((tid & 63) == 0) {
    r4[tid >> 6][0] = sc; r4[tid >> 6][1] = qc;
    r4[tid >> 6][2] = sp; r4[tid >> 6][3] = qp;
  }
  __syncthreads();
  sc = r4[0][0] + r4[1][0] + r4[2][0] + r4[3][0];
  qc = r4[0][1] + r4[1][1] + r4[2][1] + r4[3][1];
  sp = r4[0][2] + r4[1][2] + r4[2][2] + r4[3][2];
  qp = r4[0][3] + r4[1][3] + r4[2][3] + r4[3][3];
  float mc = sc * (1.f / C_);
  float rc = rsqrtf(qc * (1.f / C_) - mc * mc + 1e-5f);
  float mp = sp * (1.f / C_);
  float rp = rsqrtf(qp * (1.f / C_) - mp * mp + 1e-5f);
  float cw[8], cb[8], cf[8], o[8];
  load8f(lw + c, cw); load8f(lb + c, cb); load8f(coef + c, cf);
#pragma unroll
  for (int i = 0; i < 8; ++i) {
    float cn = (cur[i] - mc) * rc * cw[i] + cb[i];
    float pn = (t == 0) ? prv[i] : (prv[i] - mp) * rp * cw[i] + cb[i];
    o[i] = cn + (pn - cn) * cf[i];
  }
  store8bf(out + (size_t)t * C_ + c, o);
}

// ---------------- tiled transpose: fp32 [R][Cc] -> bf16 [Cc][R] -----------
__global__ __launch_bounds__(256) void transpose_kernel(
    const float* in0, const float* in1, const float* in2,
    unsigned short* o0, unsigned short* o1, unsigned short* o2,
    int R, int Cc) {
  const float* in = blockIdx.z == 0 ? in0 : (blockIdx.z == 1 ? in1 : in2);
  unsigned short* out = blockIdx.z == 0 ? o0 : (blockIdx.z == 1 ? o1 : o2);
  __shared__ __align__(16) unsigned short tile[64][80];
  int c0 = blockIdx.x * 64, r0 = blockIdx.y * 64;
  int rr = threadIdx.x >> 4, cq = threadIdx.x & 15;
#pragma unroll
  for (int i = 0; i < 4; ++i) {
    int r = rr + i * 16;
    float4 v = *(const float4*)(in + (size_t)(r0 + r) * Cc + c0 + cq * 4);
    tile[cq * 4 + 0][r] = f2bf(v.x);
    tile[cq * 4 + 1][r] = f2bf(v.y);
    tile[cq * 4 + 2][r] = f2bf(v.z);
    tile[cq * 4 + 3][r] = f2bf(v.w);
  }
  __syncthreads();
  int cr = threadIdx.x >> 2, rg = threadIdx.x & 3;
  int4 w0 = *(const int4*)&tile[cr][rg * 16];
  int4 w1 = *(const int4*)&tile[cr][rg * 16 + 8];
  unsigned short* op = out + (size_t)(c0 + cr) * R + r0 + rg * 16;
  *(int4*)op = w0;
  *(int4*)(op + 8) = w1;
}

// ---------------- 2-phase double-buffered bf16 GEMM: A[M,K] x Bt[N,K]^T ---
// EPI: 0=f32 store, 1=f32 addsrc+acc, 2=relu^2 -> bf16
template <int EPI>
__global__ __launch_bounds__(256) void gemm2_kernel(
    const unsigned short* A0, const unsigned short* A1, const unsigned short* A2,
    const unsigned short* B0, const unsigned short* B1, const unsigned short* B2,
    void* C0, void* C1, void* C2, const float* __restrict__ addsrc,
    int M, int K, int N) {
  int z = blockIdx.z;
  const unsigned short* A = z == 0 ? A0 : (z == 1 ? A1 : A2);
  const unsigned short* Bt = z == 0 ? B0 : (z == 1 ? B1 : B2);
  void* Cout = z == 0 ? C0 : (z == 1 ? C1 : C2);
  __shared__ __align__(16) unsigned short As[2][128 * 32];
  __shared__ __align__(16) unsigned short Bs[2][128 * 32];
  const int tid = threadIdx.x, lane = tid & 63, wid = tid >> 6;
  const int bm = blockIdx.y * 128, bn = blockIdx.x * 128;
  const int wr = wid >> 1, wc = wid & 1;
  const int mrow = lane & 15, krow = lane >> 4;
  auto stage = [&](int buf, int kt) {
#pragma unroll
    for (int q = 0; q < 2; ++q) {
      int s = q * 2048 + tid * 8;
      int m = s >> 5, k = s & 31;
      GLD16(A + (size_t)(bm + m) * K + kt + k, &As[buf][s]);
      GLD16(Bt + (size_t)(bn + m) * K + kt + k, &Bs[buf][s]);
    }
  };
  f32x4 acc[4][4] = {};
  stage(0, 0);
  __syncthreads();
  int buf = 0;
  for (int kt = 0; kt < K; kt += 32) {
    if (kt + 32 < K) stage(buf ^ 1, kt + 32);
    short8v af[4], bfrag[4];
#pragma unroll
    for (int i = 0; i < 4; ++i)
      af[i] = *(const short8v*)&As[buf][(wr * 64 + i * 16 + mrow) * 32 + krow * 8];
#pragma unroll
    for (int j = 0; j < 4; ++j)
      bfrag[j] = *(const short8v*)&Bs[buf][(wc * 64 + j * 16 + mrow) * 32 + krow * 8];
#pragma unroll
    for (int i = 0; i < 4; ++i)
#pragma unroll
      for (int j = 0; j < 4; ++j)
        acc[i][j] = __builtin_amdgcn_mfma_f32_16x16x32_bf16(af[i], bfrag[j], acc[i][j], 0, 0, 0);
    __syncthreads();
    buf ^= 1;
  }
#pragma unroll
  for (int i = 0; i < 4; ++i)
#pragma unroll
    for (int j = 0; j < 4; ++j)
#pragma unroll
      for (int e = 0; e < 4; ++e) {
        int grow = bm + wr * 64 + i * 16 + (lane >> 4) * 4 + e;
        int gcol = bn + wc * 64 + j * 16 + (lane & 15);
        size_t off = (size_t)grow * N + gcol;
        float v = acc[i][j][e];
        if constexpr (EPI == 0) ((float*)Cout)[off] = v;
        else if constexpr (EPI == 1) ((float*)Cout)[off] = addsrc[off] + v;
        else { float r = v > 0.f ? v : 0.f; ((unsigned short*)Cout)[off] = f2bf(r * r); }
      }
}

// ---------------- split-K variant: z = K-slice, bf16 partials -------------
__global__ __launch_bounds__(256) void gemm2ks_kernel(
    const unsigned short* __restrict__ A, const unsigned short* __restrict__ Bt,
    unsigned short* __restrict__ P, int M, int KH, int Ktot, int N) {
  int kz = blockIdx.z;
  const size_t kbase = (size_t)kz * KH;
  __shared__ __align__(16) unsigned short As[2][128 * 32];
  __shared__ __align__(16) unsigned short Bs[2][128 * 32];
  const int tid = threadIdx.x, lane = tid & 63, wid = tid >> 6;
  const int bm = blockIdx.y * 128, bn = blockIdx.x * 128;
  const int wr = wid >> 1, wc = wid & 1;
  const int mrow = lane & 15, krow = lane >> 4;
  auto stage = [&](int buf, int kt) {
#pragma unroll
    for (int q = 0; q < 2; ++q) {
      int s = q * 2048 + tid * 8;
      int m = s >> 5, k = s & 31;
      GLD16(A + (size_t)(bm + m) * Ktot + kbase + kt + k, &As[buf][s]);
      GLD16(Bt + (size_t)(bn + m) * Ktot + kbase + kt + k, &Bs[buf][s]);
    }
  };
  f32x4 acc[4][4] = {};
  stage(0, 0);
  __syncthreads();
  int buf = 0;
  for (int kt = 0; kt < KH; kt += 32) {
    if (kt + 32 < KH) stage(buf ^ 1, kt + 32);
    short8v af[4], bfrag[4];
#pragma unroll
    for (int i = 0; i < 4; ++i)
      af[i] = *(const short8v*)&As[buf][(wr * 64 + i * 16 + mrow) * 32 + krow * 8];
#pragma unroll
    for (int j = 0; j < 4; ++j)
      bfrag[j] = *(const short8v*)&Bs[buf][(wc * 64 + j * 16 + mrow) * 32 + krow * 8];
#pragma unroll
    for (int i = 0; i < 4; ++i)
#pragma unroll
      for (int j = 0; j < 4; ++j)
        acc[i][j] = __builtin_amdgcn_mfma_f32_16x16x32_bf16(af[i], bfrag[j], acc[i][j], 0, 0, 0);
    __syncthreads();
    buf ^= 1;
  }
  unsigned short* Pz = P + (size_t)kz * M * N;
#pragma unroll
  for (int i = 0; i < 4; ++i)
#pragma unroll
    for (int j = 0; j < 4; ++j)
#pragma unroll
      for (int e = 0; e < 4; ++e) {
        int grow = bm + wr * 64 + i * 16 + (lane >> 4) * 4 + e;
        int gcol = bn + wc * 64 + j * 16 + (lane & 15);
        Pz[(size_t)grow * N + gcol] = f2bf(acc[i][j][e]);
      }
}

// ---------------- split-K x 3-batch variant (rkv), bf16 partials ----------
__global__ __launch_bounds__(256) void gemm2ks3_kernel(
    const unsigned short* A0, const unsigned short* A1, const unsigned short* A2,
    const unsigned short* B0, const unsigned short* B1, const unsigned short* B2,
    unsigned short* __restrict__ P, int M, int KH, int Ktot, int N) {
  int z = blockIdx.z;
  int batch = z % 3, kz = z / 3;
  const unsigned short* A = batch == 0 ? A0 : (batch == 1 ? A1 : A2);
  const unsigned short* Bt = batch == 0 ? B0 : (batch == 1 ? B1 : B2);
  const size_t kbase = (size_t)kz * KH;
  __shared__ __align__(16) unsigned short As[2][128 * 32];
  __shared__ __align__(16) unsigned short Bs[2][128 * 32];
  const int tid = threadIdx.x, lane = tid & 63, wid = tid >> 6;
  const int bm = blockIdx.y * 128, bn = blockIdx.x * 128;
  const int wr = wid >> 1, wc = wid & 1;
  const int mrow = lane & 15, krow = lane >> 4;
  auto stage = [&](int buf, int kt) {
#pragma unroll
    for (int q = 0; q < 2; ++q) {
      int s = q * 2048 + tid * 8;
      int m = s >> 5, k = s & 31;
      GLD16(A + (size_t)(bm + m) * Ktot + kbase + kt + k, &As[buf][s]);
      GLD16(Bt + (size_t)(bn + m) * Ktot + kbase + kt + k, &Bs[buf][s]);
    }
  };
  f32x4 acc[4][4] = {};
  stage(0, 0);
  __syncthreads();
  int buf = 0;
  for (int kt = 0; kt < KH; kt += 32) {
    if (kt + 32 < KH) stage(buf ^ 1, kt + 32);
    short8v af[4], bfrag[4];
#pragma unroll
    for (int i = 0; i < 4; ++i)
      af[i] = *(const short8v*)&As[buf][(wr * 64 + i * 16 + mrow) * 32 + krow * 8];
#pragma unroll
    for (int j = 0; j < 4; ++j)
      bfrag[j] = *(const short8v*)&Bs[buf][(wc * 64 + j * 16 + mrow) * 32 + krow * 8];
#pragma unroll
    for (int i = 0; i < 4; ++i)
#pragma unroll
      for (int j = 0; j < 4; ++j)
        acc[i][j] = __builtin_amdgcn_mfma_f32_16x16x32_bf16(af[i], bfrag[j], acc[i][j], 0, 0, 0);
    __syncthreads();
    buf ^= 1;
  }
  unsigned short* Pz = P + (size_t)z * M * N;
#pragma unroll
  for (int i = 0; i < 4; ++i)
#pragma unroll
    for (int j = 0; j < 4; ++j)
#pragma unroll
      for (int e = 0; e < 4; ++e) {
        int grow = bm + wr * 64 + i * 16 + (lane >> 4) * 4 + e;
        int gcol = bn + wc * 64 + j * 16 + (lane & 15);
        Pz[(size_t)grow * N + gcol] = f2bf(acc[i][j][e]);
      }
}

// ---------------- o = a + p0+p1+p2+p3 (bf16 partials at stride T*C) -------
__global__ __launch_bounds__(256) void add5_kernel(
    const float* __restrict__ a, const unsigned short* __restrict__ p,
    float* __restrict__ o) {
  size_t i = ((size_t)blockIdx.x * 256 + threadIdx.x) * 8;
  const size_t TC = (size_t)T_ * C_;
  float va[8], v0[8], v1[8], v2[8], v3[8], r[8];
  load8f(a + i, va);
  load8bf(p + i, v0);
  load8bf(p + i + TC, v1);
  load8bf(p + i + 2 * TC, v2);
  load8bf(p + i + 3 * TC, v3);
#pragma unroll
  for (int k = 0; k < 8; ++k) r[k] = va[k] + v0[k] + v1[k] + v2[k] + v3[k];
  *(float4*)(o + i) = make_float4(r[0], r[1], r[2], r[3]);
  *(float4*)(o + i + 4) = make_float4(r[4], r[5], r[6], r[7]);
}

// ---------------- K-split lora-down GEMMs (BN=64, z=mat*8+kz) -------------
__global__ __launch_bounds__(256) void gemm_ks3_kernel(
    const unsigned short* A0, const unsigned short* A1, const unsigned short* A2,
    const unsigned short* B0, const unsigned short* B1, const unsigned short* B2,
    float* P0, float* P1, float* P2, int K, int N) {
  int mz = blockIdx.z >> 3, kz = blockIdx.z & 7;
  const unsigned short* A = mz == 0 ? A0 : (mz == 1 ? A1 : A2);
  const unsigned short* Bt = mz == 0 ? B0 : (mz == 1 ? B1 : B2);
  float* partial = mz == 0 ? P0 : (mz == 1 ? P1 : P2);
  __shared__ __align__(16) unsigned short As[2][128 * 32];
  __shared__ __align__(16) unsigned short Bs[2][64 * 32];
  const int tid = threadIdx.x, lane = tid & 63, wid = tid >> 6;
  const int bn = blockIdx.x * 64, bm = blockIdx.y * 128;
  const int wr = wid >> 1, wc = wid & 1;
  const int mrow = lane & 15, krow = lane >> 4;
  auto stage = [&](int buf, int kt) {
#pragma unroll
    for (int q = 0; q < 2; ++q) {
      int s = q * 2048 + tid * 8;
      int m = s >> 5, k = s & 31;
      GLD16(A + (size_t)(bm + m) * K + kt + k, &As[buf][s]);
    }
    {
      int s = tid * 8;
      int n = s >> 5, k = s & 31;
      GLD16(Bt + (size_t)(bn + n) * K + kt + k, &Bs[buf][s]);
    }
  };
  f32x4 acc[4][2] = {};
  int k0 = kz * 256;
  stage(0, k0);
  __syncthreads();
  int buf = 0;
  for (int kt = k0; kt < k0 + 256; kt += 32) {
    if (kt + 32 < k0 + 256) stage(buf ^ 1, kt + 32);
    short8v af[4], bfrag[2];
#pragma unroll
    for (int i = 0; i < 4; ++i)
      af[i] = *(const short8v*)&As[buf][(wr * 64 + i * 16 + mrow) * 32 + krow * 8];
#pragma unroll
    for (int j = 0; j < 2; ++j)
      bfrag[j] = *(const short8v*)&Bs[buf][(wc * 32 + j * 16 + mrow) * 32 + krow * 8];
#pragma unroll
    for (int i = 0; i < 4; ++i)
#pragma unroll
      for (int j = 0; j < 2; ++j)
        acc[i][j] = __builtin_amdgcn_mfma_f32_16x16x32_bf16(af[i], bfrag[j], acc[i][j], 0, 0, 0);
    __syncthreads();
    buf ^= 1;
  }
#pragma unroll
  for (int i = 0; i < 4; ++i)
#pragma unroll
    for (int j = 0; j < 2; ++j)
#pragma unroll
      for (int e = 0; e < 4; ++e) {
        int row = bm + wr * 64 + i * 16 + (lane >> 4) * 4 + e;
        int col = bn + wc * 32 + j * 16 + (lane & 15);
        partial[((size_t)kz * 1024 + row) * N + col] = acc[i][j][e];
      }
}

__global__ __launch_bounds__(256) void gemm_ks_kernel(
    const unsigned short* __restrict__ A, const unsigned short* __restrict__ Bt,
    float* __restrict__ partial, int K, int N) {
  __shared__ __align__(16) unsigned short As[2][128 * 32];
  __shared__ __align__(16) unsigned short Bs[2][64 * 32];
  const int tid = threadIdx.x, lane = tid & 63, wid = tid >> 6;
  const int bn = blockIdx.x * 64, bm = blockIdx.y * 128, kz = blockIdx.z;
  const int wr = wid >> 1, wc = wid & 1;
  const int mrow = lane & 15, krow = lane >> 4;
  auto stage = [&](int buf, int kt) {
#pragma unroll
    for (int q = 0; q < 2; ++q) {
      int s = q * 2048 + tid * 8;
      int m = s >> 5, k = s & 31;
      GLD16(A + (size_t)(bm + m) * K + kt + k, &As[buf][s]);
    }
    {
      int s = tid * 8;
      int n = s >> 5, k = s & 31;
      GLD16(Bt + (size_t)(bn + n) * K + kt + k, &Bs[buf][s]);
    }
  };
  f32x4 acc[4][2] = {};
  int k0 = kz * 256;
  stage(0, k0);
  __syncthreads();
  int buf = 0;
  for (int kt = k0; kt < k0 + 256; kt += 32) {
    if (kt + 32 < k0 + 256) stage(buf ^ 1, kt + 32);
    short8v af[4], bfrag[2];
#pragma unroll
    for (int i = 0; i < 4; ++i)
      af[i] = *(const short8v*)&As[buf][(wr * 64 + i * 16 + mrow) * 32 + krow * 8];
#pragma unroll
    for (int j = 0; j < 2; ++j)
      bfrag[j] = *(const short8v*)&Bs[buf][(wc * 32 + j * 16 + mrow) * 32 + krow * 8];
#pragma unroll
    for (int i = 0; i < 4; ++i)
#pragma unroll
      for (int j = 0; j < 2; ++j)
        acc[i][j] = __builtin_amdgcn_mfma_f32_16x16x32_bf16(af[i], bfrag[j], acc[i][j], 0, 0, 0);
    __syncthreads();
    buf ^= 1;
  }
#pragma unroll
  for (int i = 0; i < 4; ++i)
#pragma unroll
    for (int j = 0; j < 2; ++j)
#pragma unroll
      for (int e = 0; e < 4; ++e) {
        int row = bm + wr * 64 + i * 16 + (lane >> 4) * 4 + e;
        int col = bn + wc * 32 + j * 16 + (lane & 15);
        partial[((size_t)kz * 1024 + row) * N + col] = acc[i][j][e];
      }
}

__global__ __launch_bounds__(128) void lora_combine_kernel(
    const float* __restrict__ pw, const float* __restrict__ pa,
    const float* __restrict__ pv, const float* __restrict__ pg,
    unsigned short* __restrict__ hw, unsigned short* __restrict__ ha,
    unsigned short* __restrict__ hv, unsigned short* __restrict__ hg) {
  int t = blockIdx.x, which = blockIdx.y, tid = threadIdx.x;
  int Nl = (which == 3) ? 128 : 64;
  if (tid >= Nl) return;
  const float* p = which == 0 ? pw : which == 1 ? pa : which == 2 ? pv : pg;
  float s = 0.f;
#pragma unroll
  for (int kz = 0; kz < 8; ++kz) s += p[((size_t)kz * 1024 + t) * Nl + tid];
  float r = which == 0 ? tanhf(s) : (which == 3 ? sigm(s) : s);
  unsigned short* o = which == 0 ? hw : which == 1 ? ha : which == 2 ? hv : hg;
  o[t * Nl + tid] = f2bf(r);
}

// ---------------- post: rkv bf16-partial combine + pack scan inputs -------
// scanin[h][t][6][64] fp32: seg 0=w, 1=kkn, 2=-kkn*a, 3=k2, 4=v, 5=r
__global__ __launch_bounds__(256) void post_kernel(
    const unsigned short* __restrict__ qRKV, const float* __restrict__ wpre,
    const float* __restrict__ apre, const float* __restrict__ vpre,
    const float* __restrict__ vfirst, const float* __restrict__ w0,
    const float* __restrict__ a0, const float* __restrict__ v0_,
    const float* __restrict__ k_k, const float* __restrict__ k_a,
    float* __restrict__ scanin) {
  int t = blockIdx.x, tid = threadIdx.x;
  int c = tid * 8, h = tid >> 3, j = c & 63;
  size_t o = (size_t)t * C_ + c;
  const size_t TC = (size_t)T_ * C_;
  float rv[8], kv[8], vv[8], t0[8], wv[8], av[8], vp[8], vf[8];
  load8bf(qRKV + o, rv);          load8bf(qRKV + 3 * TC + o, t0);
#pragma unroll
  for (int i = 0; i < 8; ++i) rv[i] += t0[i];
  load8bf(qRKV + TC + o, kv);     load8bf(qRKV + 4 * TC + o, t0);
#pragma unroll
  for (int i = 0; i < 8; ++i) kv[i] += t0[i];
  load8bf(qRKV + 2 * TC + o, vv); load8bf(qRKV + 5 * TC + o, t0);
#pragma unroll
  for (int i = 0; i < 8; ++i) vv[i] += t0[i];
  load8f(wpre + o, wv); load8f(apre + o, av); load8f(vpre + o, vp);
  load8f(vfirst + o, vf);
  float ckk[8], cka[8], cw0[8], ca0[8], cv0[8];
  load8f(k_k + c, ckk); load8f(k_a + c, cka); load8f(w0 + c, cw0);
  load8f(a0 + c, ca0); load8f(v0_ + c, cv0);
  float kk[8]; float ss = 0.f;
#pragma unroll
  for (int i = 0; i < 8; ++i) { kk[i] = kv[i] * ckk[i]; ss += kk[i] * kk[i]; }
  ss += __shfl_xor(ss, 1); ss += __shfl_xor(ss, 2); ss += __shfl_xor(ss, 4);
  float rdn = 1.f / fmaxf(sqrtf(ss), 1e-12f);
  float sw[8], skn[8], scc[8], sk2[8], sv[8];
#pragma unroll
  for (int i = 0; i < 8; ++i) {
    float kkn = kk[i] * rdn;
    float a = sigm(ca0[i] + av[i]);
    skn[i] = kkn;
    scc[i] = -kkn * a;
    sk2[i] = kv[i] * (1.f + (a - 1.f) * cka[i]);
    float sg = sigm(cv0[i] + vp[i]);
    sv[i] = vv[i] + (vf[i] - vv[i]) * sg;
    sw[i] = __expf(-0.606531f * sigm(cw0[i] + wv[i]));
  }
  float* bp = scanin + ((size_t)h * T_ + t) * 384 + j;
  ((float4*)(bp + 0))[0]   = make_float4(sw[0], sw[1], sw[2], sw[3]);
  ((float4*)(bp + 4))[0]   = make_float4(sw[4], sw[5], sw[6], sw[7]);
  ((float4*)(bp + 64))[0]  = make_float4(skn[0], skn[1], skn[2], skn[3]);
  ((float4*)(bp + 68))[0]  = make_float4(skn[4], skn[5], skn[6], skn[7]);
  ((float4*)(bp + 128))[0] = make_float4(scc[0], scc[1], scc[2], scc[3]);
  ((float4*)(bp + 132))[0] = make_float4(scc[4], scc[5], scc[6], scc[7]);
  ((float4*)(bp + 192))[0] = make_float4(sk2[0], sk2[1], sk2[2], sk2[3]);
  ((float4*)(bp + 196))[0] = make_float4(sk2[4], sk2[5], sk2[6], sk2[7]);
  ((float4*)(bp + 256))[0] = make_float4(sv[0], sv[1], sv[2], sv[3]);
  ((float4*)(bp + 260))[0] = make_float4(sv[4], sv[5], sv[6], sv[7]);
  ((float4*)(bp + 320))[0] = make_float4(rv[0], rv[1], rv[2], rv[3]);
  ((float4*)(bp + 324))[0] = make_float4(rv[4], rv[5], rv[6], rv[7]);
}

// ---------------- sequential scan v5: 16 parts x 4 rows, 512 blocks -------
struct SR { float wv[4], nv[4], cv[4], kv[4], rv[4], vvv; };

template <int CTRL>
__device__ __forceinline__ float dppadd(float x) {
  int y = __builtin_amdgcn_update_dpp(0, __float_as_int(x), CTRL, 0xF, 0xF, true);
  return x + __int_as_float(y);
}
// full sum across each 16-lane row, result in all 16 lanes (pure VALU)
__device__ __forceinline__ float red16(float x) {
  x = dppadd<0xB1>(x);
  x = dppadd<0x4E>(x);
  x = dppadd<0x140>(x);
  x = dppadd<0x141>(x);
  return x;
}

__device__ __forceinline__ void loadstep(const float* S, SR& R, int p4, int row) {
  load4f(S + p4, R.wv);
  load4f(S + 64 + p4, R.nv);
  load4f(S + 128 + p4, R.cv);
  load4f(S + 192 + p4, R.kv);
  load4f(S + 320 + p4, R.rv);
  R.vvv = S[256 + row];
}

__device__ __forceinline__ void stepcomp(const SR& R, float* st, int part,
                                         float* __restrict__ ob, size_t oidx) {
  float p0 = fmaf(st[0], R.nv[0], 0.f);
  float p1 = fmaf(st[1], R.nv[1], 0.f);
  p0 = fmaf(st[2], R.nv[2], p0);
  p1 = fmaf(st[3], R.nv[3], p1);
  float sa = red16(p0 + p1);
  float s0 = 0.f, s1 = 0.f;
#pragma unroll
  for (int i = 0; i < 4; ++i) {
    float t = fmaf(st[i], R.wv[i], fmaf(sa, R.cv[i], R.vvv * R.kv[i]));
    st[i] = t;
    if (i & 1) s1 = fmaf(t, R.rv[i], s1);
    else s0 = fmaf(t, R.rv[i], s0);
  }
  float so = red16(s0 + s1);
  if (part == 0) ob[oidx] = so;
}

// 512 blocks = 32 heads x 16 row-groups (head pinned to one XCD);
// 64 thr = 4 rows x 16 parts. Direct global loads, 3-step-deep pipeline.
__global__ __launch_bounds__(64) void scan5_kernel(
    const float* __restrict__ scanin, const float* __restrict__ vk0,
    float* __restrict__ outs) {
  int bid = blockIdx.x;
  int h = (bid & 7) + 8 * ((bid >> 3) & 3);  // h&7 fixed per XCD
  int rg = bid >> 5;                          // 0..15
  int tid = threadIdx.x;
  int part = tid & 15, row = rg * 4 + (tid >> 4);
  int p4 = part * 4;
  float st[4];
  load4f(vk0 + ((size_t)h * NH + row) * NH + p4, st);
  const float* src = scanin + (size_t)h * T_ * 384;
  float* ob = outs + h * NH + row;
  SR A, B, C, D;
  loadstep(src + 0 * 384, A, p4, row);
  loadstep(src + 1 * 384, B, p4, row);
  loadstep(src + 2 * 384, C, p4, row);
  int s = 0;
  for (; s < T_ - 4; s += 4) {
    const float* sp = src + (size_t)s * 384;
    loadstep(sp + 3 * 384, D, p4, row);
    stepcomp(A, st, part, ob, (size_t)(s + 0) * C_);
    loadstep(sp + 4 * 384, A, p4, row);
    stepcomp(B, st, part, ob, (size_t)(s + 1) * C_);
    loadstep(sp + 5 * 384, B, p4, row);
    stepcomp(C, st, part, ob, (size_t)(s + 2) * C_);
    loadstep(sp + 6 * 384, C, p4, row);
    stepcomp(D, st, part, ob, (size_t)(s + 3) * C_);
  }
  // tail: s == T_-4; A,B,C hold s..s+2
  loadstep(src + (size_t)(T_ - 1) * 384, D, p4, row);
  stepcomp(A, st, part, ob, (size_t)(s + 0) * C_);
  stepcomp(B, st, part, ob, (size_t)(s + 1) * C_);
  stepcomp(C, st, part, ob, (size_t)(s + 2) * C_);
  stepcomp(D, st, part, ob, (size_t)(s + 3) * C_);
}

// ---------------- groupnorm + bonus + gate --------------------------------
__global__ __launch_bounds__(256) void gnb_kernel(
    const float* __restrict__ outs, const float* __restrict__ scanin,
    const float* __restrict__ g, const float* __restrict__ rk,
    const float* __restrict__ gw, const float* __restrict__ gb,
    unsigned short* __restrict__ attin) {
  int t = blockIdx.x, tid = threadIdx.x;
  int c = tid * 8, h = tid >> 3, j = c & 63;
  float o[8], gv[8], rkv[8];
  load8f(outs + (size_t)t * C_ + c, o);
  load8f(g + (size_t)t * C_ + c, gv);
  load8f(rk + c, rkv);
  size_t sbase = ((size_t)h * T_ + t) * 384 + j;
  float rv[8], k2[8], vv[8];
  load8f(scanin + sbase + 320, rv);
  load8f(scanin + sbase + 192, k2);
  load8f(scanin + sbase + 256, vv);
  float s = 0.f, q = 0.f, bs = 0.f;
#pragma unroll
  for (int i = 0; i < 8; ++i) {
    s += o[i]; q += o[i] * o[i];
    bs += rv[i] * k2[i] * rkv[i];
  }
  s += __shfl_xor(s, 1); s += __shfl_xor(s, 2); s += __shfl_xor(s, 4);
  q += __shfl_xor(q, 1); q += __shfl_xor(q, 2); q += __shfl_xor(q, 4);
  bs += __shfl_xor(bs, 1); bs += __shfl_xor(bs, 2); bs += __shfl_xor(bs, 4);
  float mean = s * (1.f / NH);
  float var = q * (1.f / NH) - mean * mean;
  float rstd = rsqrtf(var + 0.00064f);
  float res[8];
#pragma unroll
  for (int i = 0; i < 8; ++i) {
    float gn = (o[i] - mean) * rstd * gw[c + i] + gb[c + i];
    res[i] = (gn + bs * vv[i]) * gv[i];
  }
  store8bf(attin + (size_t)t * C_ + c, res);
}

extern "C" void kernel_launch(void* const* d_in, const int* in_sizes, int n_in,
                              void* d_out, int out_size, void* d_ws, size_t ws_size,
                              hipStream_t stream) {
  const float* x       = (const float*)d_in[0];
  const float* xprev_a = (const float*)d_in[1];
  const float* vk0     = (const float*)d_in[2];
  const float* xprev_f = (const float*)d_in[3];
  const float* vfirst  = (const float*)d_in[4];
  const float* ln1w = (const float*)d_in[5];
  const float* ln1b = (const float*)d_in[6];
  const float* m_r = (const float*)d_in[7];
  const float* m_w = (const float*)d_in[8];
  const float* m_k = (const float*)d_in[9];
  const float* m_v = (const float*)d_in[10];
  const float* m_a = (const float*)d_in[11];
  const float* m_g = (const float*)d_in[12];
  const float* w0 = (const float*)d_in[13];
  const float* w1 = (const float*)d_in[14];
  const float* w2 = (const float*)d_in[15];
  const float* a0 = (const float*)d_in[16];
  const float* a1 = (const float*)d_in[17];
  const float* a2 = (const float*)d_in[18];
  const float* v0 = (const float*)d_in[19];
  const float* v1 = (const float*)d_in[20];
  const float* v2 = (const float*)d_in[21];
  const float* g1 = (const float*)d_in[22];
  const float* g2 = (const float*)d_in[23];
  const float* k_k = (const float*)d_in[24];
  const float* k_a = (const float*)d_in[25];
  const float* r_k = (const float*)d_in[26];
  const float* R_ = (const float*)d_in[27];
  const float* K_ = (const float*)d_in[28];
  const float* V_ = (const float*)d_in[29];
  const float* O_ = (const float*)d_in[30];
  const float* lnxw = (const float*)d_in[31];
  const float* lnxb = (const float*)d_in[32];
  const float* ln2w = (const float*)d_in[33];
  const float* ln2b = (const float*)d_in[34];
  const float* fxk = (const float*)d_in[35];
  const float* fK = (const float*)d_in[36];
  const float* fV = (const float*)d_in[37];
  float* out = (float*)d_out;

  char* ws = (char*)d_ws;
  const size_t MB = 1ull << 20;
  // ---- workspace layout (bf16-partials revision; peak 132 MB) ------------
  // 0-4: attin (ph7-8); 0-1.25: w1t..g1t/w2t..g2t (ph4); 1.31-2: hwb..hgb
  // 2-4: pw; 4-6: pa; 6-8: pv; 8-12: pg (ph4)
  // 4-8: xr; 8-12: xw; 12-16: xk; 16-20: xv; 20-24: xa; 24-28: xg (ph2-3)
  // 4-12: wpre; 12-20: apre; 20-28: vpre (ph4b-5)
  // 8-12: xkf (ph9-10); 4-20: pF bf16 (ph11)
  // 28-52: qRKV bf16 (ph3-5); 28-60: fVt (ph8-11)
  // 52-60: outsb (ph6-7); 60-68: x_att (ph8-12); 76-84: g_buf (ph4-7)
  // 84-132: scanin fp32 (ph5-7); 84-108: Rt/Kt/Vt (ph3); 84-92: Ot (ph8)
  // 92-108: qO bf16 (ph8); 84-100: hffn (ph10-11); 100-132: fKt (ph10-11)
  unsigned short* attin = (unsigned short*)(ws + 0 * MB);
  unsigned short* xr    = (unsigned short*)(ws + 4 * MB);
  unsigned short* xw    = (unsigned short*)(ws + 8 * MB);
  unsigned short* xkf   = (unsigned short*)(ws + 8 * MB);
  unsigned short* xk    = (unsigned short*)(ws + 12 * MB);
  unsigned short* xv    = (unsigned short*)(ws + 16 * MB);
  unsigned short* xa    = (unsigned short*)(ws + 20 * MB);
  unsigned short* xg    = (unsigned short*)(ws + 24 * MB);
  float* wpre  = (float*)(ws + 4 * MB);
  float* apre  = (float*)(ws + 12 * MB);
  float* vpre  = (float*)(ws + 20 * MB);
  unsigned short* qRKV = (unsigned short*)(ws + 28 * MB);
  unsigned short* fVt = (unsigned short*)(ws + 28 * MB);
  float* outsb = (float*)(ws + 52 * MB);
  float* x_att = (float*)(ws + 60 * MB);
  float* g_buf = (float*)(ws + 76 * MB);
  float* scanin = (float*)(ws + 84 * MB);
  unsigned short* Rt  = (unsigned short*)(ws + 84 * MB);
  unsigned short* Kt  = (unsigned short*)(ws + 92 * MB);
  unsigned short* Vt  = (unsigned short*)(ws + 100 * MB);
  unsigned short* Ot  = (unsigned short*)(ws + 84 * MB);
  unsigned short* qO  = (unsigned short*)(ws + 92 * MB);
  unsigned short* hffn = (unsigned short*)(ws + 84 * MB);
  unsigned short* fKt  = (unsigned short*)(ws + 100 * MB);
  unsigned short* pF   = (unsigned short*)(ws + 4 * MB);
  unsigned short* w1t = (unsigned short*)(ws + 0);
  unsigned short* a1t = (unsigned short*)(ws + 262144);
  unsigned short* v1t = (unsigned short*)(ws + 524288);
  unsigned short* g1t = (unsigned short*)(ws + 786432);
  unsigned short* w2t = (unsigned short*)(ws + 0);
  unsigned short* a2t = (unsigned short*)(ws + 262144);
  unsigned short* v2t = (unsigned short*)(ws + 524288);
  unsigned short* g2t = (unsigned short*)(ws + 786432);
  unsigned short* hwb = (unsigned short*)(ws + 1376256);
  unsigned short* hab = (unsigned short*)(ws + 1507328);
  unsigned short* hvb = (unsigned short*)(ws + 1638400);
  unsigned short* hgb = (unsigned short*)(ws + 1769472);
  float* pw = (float*)(ws + 2 * MB);
  float* pa = (float*)(ws + 4 * MB);
  float* pv = (float*)(ws + 6 * MB);
  float* pg = (float*)(ws + 8 * MB);

  // TMix front: fused LN+mix, projections
  lnmix6_kernel<<<T_, 256, 0, stream>>>(x, xprev_a, ln1w, ln1b,
                                        m_r, m_w, m_k, m_v, m_a, m_g,
                                        xr, xw, xk, xv, xa, xg);
  transpose_kernel<<<dim3(32, 32, 3), 256, 0, stream>>>(R_, K_, V_, Rt, Kt, Vt, C_, C_);
  gemm2ks3_kernel<<<dim3(16, 8, 6), 256, 0, stream>>>(xr, xk, xv, Rt, Kt, Vt,
                                                      qRKV, T_, 1024, C_, C_);
  // loras
  transpose_kernel<<<dim3(1, 32, 3), 256, 0, stream>>>(w1, a1, v1, w1t, a1t, v1t, C_, 64);
  transpose_kernel<<<dim3(2, 32, 1), 256, 0, stream>>>(g1, g1, g1, g1t, g1t, g1t, C_, 128);
  gemm_ks3_kernel<<<dim3(1, 8, 24), 256, 0, stream>>>(xw, xa, xv, w1t, a1t, v1t,
                                                      pw, pa, pv, C_, 64);
  gemm_ks_kernel<<<dim3(2, 8, 8), 256, 0, stream>>>(xg, g1t, pg, C_, 128);
  lora_combine_kernel<<<dim3(T_, 4), 128, 0, stream>>>(pw, pa, pv, pg, hwb, hab, hvb, hgb);
  transpose_kernel<<<dim3(32, 1, 3), 256, 0, stream>>>(w2, a2, v2, w2t, a2t, v2t, 64, C_);
  transpose_kernel<<<dim3(32, 2, 1), 256, 0, stream>>>(g2, g2, g2, g2t, g2t, g2t, 128, C_);
  gemm2_kernel<0><<<dim3(16, 8, 3), 256, 0, stream>>>(hwb, hab, hvb, w2t, a2t, v2t,
                                                      wpre, apre, vpre, nullptr, T_, 64, C_);
  gemm2_kernel<0><<<dim3(16, 8, 1), 256, 0, stream>>>(hgb, hgb, hgb, g2t, g2t, g2t,
                                                      g_buf, g_buf, g_buf, nullptr, T_, 128, C_);
  // scan (post fuses the rkv split-K combine, bf16 partials)
  post_kernel<<<T_, 256, 0, stream>>>(qRKV, wpre, apre, vpre, vfirst,
                                      w0, a0, v0, k_k, k_a, scanin);
  scan5_kernel<<<512, 64, 0, stream>>>(scanin, vk0, outsb);
  gnb_kernel<<<T_, 256, 0, stream>>>(outsb, scanin, g_buf, r_k, lnxw, lnxb, attin);
  // output proj (split-K x4, bf16 partials) + CMix
  transpose_kernel<<<dim3(32, 32, 1), 256, 0, stream>>>(O_, O_, O_, Ot, Ot, Ot, C_, C_);
  transpose_kernel<<<dim3(32, 128, 1), 256, 0, stream>>>(fV, fV, fV, fVt, fVt, fVt, 4 * C_, C_);
  gemm2ks_kernel<<<dim3(16, 8, 4), 256, 0, stream>>>(attin, Ot, qO, T_, 512, C_, C_);
  add5_kernel<<<1024, 256, 0, stream>>>(x, qO, x_att);
  lnmix1_kernel<<<T_, 256, 0, stream>>>(x_att, xprev_f, ln2w, ln2b, fxk, xkf);
  transpose_kernel<<<dim3(128, 32, 1), 256, 0, stream>>>(fK, fK, fK, fKt, fKt, fKt, C_, 4 * C_);
  gemm2_kernel<2><<<dim3(64, 8, 1), 256, 0, stream>>>(xkf, xkf, xkf, fKt, fKt, fKt,
                                                      hffn, hffn, hffn, nullptr, T_, C_, 4 * C_);
  gemm2ks_kernel<<<dim3(16, 8, 4), 256, 0, stream>>>(hffn, fVt, pF, T_, 2048, 4 * C_, C_);
  add5_kernel<<<1024, 256, 0, stream>>>(x_att, pF, out);
}

// Round 15
// 451.194 us; speedup vs baseline: 1.1008x; 1.0435x over previous
//
#include <hip/hip_runtime.h>
#include <hip/hip_bf16.h>

// RWKV-7 block (TMix + CMix) for T=1024, C=2048, H=32, N=64 on gfx950.

#define T_ 1024
#define C_ 2048
#define H_ 32
#define NH 64

typedef __attribute__((ext_vector_type(8))) short short8v;
typedef __attribute__((ext_vector_type(4))) float f32x4;

__device__ __forceinline__ float bf2f(unsigned short u) {
  union { float f; unsigned int i; } c; c.i = ((unsigned int)u) << 16; return c.f;
}
__device__ __forceinline__ unsigned short f2bf(float f) {
  union { float f; unsigned int i; } c; c.f = f;
  unsigned int x = c.i;
  return (unsigned short)((x + 0x7fffu + ((x >> 16) & 1u)) >> 16); // RNE
}
__device__ __forceinline__ float sigm(float x) { return 1.f / (1.f + __expf(-x)); }

__device__ __forceinline__ void load8bf(const unsigned short* p, float* o) {
  union { int4 v; unsigned short u[8]; } c;
  c.v = *(const int4*)p;
#pragma unroll
  for (int i = 0; i < 8; ++i) o[i] = bf2f(c.u[i]);
}
__device__ __forceinline__ void store8bf(unsigned short* p, const float* o) {
  union { int4 v; unsigned short u[8]; } c;
#pragma unroll
  for (int i = 0; i < 8; ++i) c.u[i] = f2bf(o[i]);
  *(int4*)p = c.v;
}
__device__ __forceinline__ void load8f(const float* p, float* o) {
  float4 a = ((const float4*)p)[0], b = ((const float4*)p)[1];
  o[0] = a.x; o[1] = a.y; o[2] = a.z; o[3] = a.w;
  o[4] = b.x; o[5] = b.y; o[6] = b.z; o[7] = b.w;
}
__device__ __forceinline__ void load4f(const float* p, float* o) {
  float4 a = *(const float4*)p;
  o[0] = a.x; o[1] = a.y; o[2] = a.z; o[3] = a.w;
}

#define GLD16(g, l)                                                        \
  __builtin_amdgcn_global_load_lds(                                        \
      (const __attribute__((address_space(1))) void*)(g),                  \
      (__attribute__((address_space(3))) void*)(l), 16, 0, 0)

// ---------------- fused LN + 6-way token-shift mix ------------------------
__global__ __launch_bounds__(256) void lnmix6_kernel(
    const float* __restrict__ x, const float* __restrict__ xprev,
    const float* __restrict__ lw, const float* __restrict__ lb,
    const float* __restrict__ mr, const float* __restrict__ mw,
    const float* __restrict__ mk, const float* __restrict__ mv,
    const float* __restrict__ ma, const float* __restrict__ mg,
    unsigned short* xr, unsigned short* xw, unsigned short* xk,
    unsigned short* xv, unsigned short* xa, unsigned short* xg) {
  int t = blockIdx.x, tid = threadIdx.x, c = tid * 8;
  float cur[8], prv[8];
  load8f(x + (size_t)t * C_ + c, cur);
  if (t == 0) load8f(xprev + c, prv);
  else load8f(x + (size_t)(t - 1) * C_ + c, prv);
  float sc = 0.f, qc = 0.f, sp = 0.f, qp = 0.f;
#pragma unroll
  for (int i = 0; i < 8; ++i) {
    sc += cur[i]; qc += cur[i] * cur[i];
    sp += prv[i]; qp += prv[i] * prv[i];
  }
  for (int m = 1; m < 64; m <<= 1) {
    sc += __shfl_xor(sc, m); qc += __shfl_xor(qc, m);
    sp += __shfl_xor(sp, m); qp += __shfl_xor(qp, m);
  }
  __shared__ float r4[4][4];
  if ((tid & 63) == 0) {
    r4[tid >> 6][0] = sc; r4[tid >> 6][1] = qc;
    r4[tid >> 6][2] = sp; r4[tid >> 6][3] = qp;
  }
  __syncthreads();
  sc = r4[0][0] + r4[1][0] + r4[2][0] + r4[3][0];
  qc = r4[0][1] + r4[1][1] + r4[2][1] + r4[3][1];
  sp = r4[0][2] + r4[1][2] + r4[2][2] + r4[3][2];
  qp = r4[0][3] + r4[1][3] + r4[2][3] + r4[3][3];
  float mc = sc * (1.f / C_);
  float rc = rsqrtf(qc * (1.f / C_) - mc * mc + 1e-5f);
  float mp = sp * (1.f / C_);
  float rp = rsqrtf(qp * (1.f / C_) - mp * mp + 1e-5f);
  float cw[8], cb[8];
  load8f(lw + c, cw); load8f(lb + c, cb);
  float curn[8], prvn[8];
#pragma unroll
  for (int i = 0; i < 8; ++i) {
    curn[i] = (cur[i] - mc) * rc * cw[i] + cb[i];
    prvn[i] = (t == 0) ? prv[i] : (prv[i] - mp) * rp * cw[i] + cb[i];
  }
  float cf[8], o[8];
  const float* coefs[6] = {mr, mw, mk, mv, ma, mg};
  unsigned short* outs6[6] = {xr, xw, xk, xv, xa, xg};
#pragma unroll
  for (int a = 0; a < 6; ++a) {
    load8f(coefs[a] + c, cf);
#pragma unroll
    for (int i = 0; i < 8; ++i) o[i] = curn[i] + (prvn[i] - curn[i]) * cf[i];
    store8bf(outs6[a] + (size_t)t * C_ + c, o);
  }
}

// ---------------- fused LN + 1-way mix (CMix) -----------------------------
__global__ __launch_bounds__(256) void lnmix1_kernel(
    const float* __restrict__ x, const float* __restrict__ xprev,
    const float* __restrict__ lw, const float* __restrict__ lb,
    const float* __restrict__ coef, unsigned short* __restrict__ out) {
  int t = blockIdx.x, tid = threadIdx.x, c = tid * 8;
  float cur[8], prv[8];
  load8f(x + (size_t)t * C_ + c, cur);
  if (t == 0) load8f(xprev + c, prv);
  else load8f(x + (size_t)(t - 1) * C_ + c, prv);
  float sc = 0.f, qc = 0.f, sp = 0.f, qp = 0.f;
#pragma unroll
  for (int i = 0; i < 8; ++i) {
    sc += cur[i]; qc += cur[i] * cur[i];
    sp += prv[i]; qp += prv[i] * prv[i];
  }
  for (int m = 1; m < 64; m <<= 1) {
    sc += __shfl_xor(sc, m); qc += __shfl_xor(qc, m);
    sp += __shfl_xor(sp, m); qp += __shfl_xor(qp, m);
  }
  __shared__ float r4[4][4];
  if ((tid & 63) == 0) {
    r4[tid >> 6][0] = sc; r4[tid >> 6][1] = qc;
    r4[tid >> 6][2] = sp; r4[tid >> 6][3] = qp;
  }
  __syncthreads();
  sc = r4[0][0] + r4[1][0] + r4[2][0] + r4[3][0];
  qc = r4[0][1] + r4[1][1] + r4[2][1] + r4[3][1];
  sp = r4[0][2] + r4[1][2] + r4[2][2] + r4[3][2];
  qp = r4[0][3] + r4[1][3] + r4[2][3] + r4[3][3];
  float mc = sc * (1.f / C_);
  float rc = rsqrtf(qc * (1.f / C_) - mc * mc + 1e-5f);
  float mp = sp * (1.f / C_);
  float rp = rsqrtf(qp * (1.f / C_) - mp * mp + 1e-5f);
  float cw[8], cb[8], cf[8], o[8];
  load8f(lw + c, cw); load8f(lb + c, cb); load8f(coef + c, cf);
#pragma unroll
  for (int i = 0; i < 8; ++i) {
    float cn = (cur[i] - mc) * rc * cw[i] + cb[i];
    float pn = (t == 0) ? prv[i] : (prv[i] - mp) * rp * cw[i] + cb[i];
    o[i] = cn + (pn - cn) * cf[i];
  }
  store8bf(out + (size_t)t * C_ + c, o);
}

// ---------------- tiled transpose body (device) ---------------------------
__device__ __forceinline__ void transpose_tile(
    const float* __restrict__ in, unsigned short* __restrict__ out,
    int R, int Cc, int bx, int by, unsigned short (*tile)[80]) {
  int c0 = bx * 64, r0 = by * 64;
  int rr = threadIdx.x >> 4, cq = threadIdx.x & 15;
#pragma unroll
  for (int i = 0; i < 4; ++i) {
    int r = rr + i * 16;
    float4 v = *(const float4*)(in + (size_t)(r0 + r) * Cc + c0 + cq * 4);
    tile[cq * 4 + 0][r] = f2bf(v.x);
    tile[cq * 4 + 1][r] = f2bf(v.y);
    tile[cq * 4 + 2][r] = f2bf(v.z);
    tile[cq * 4 + 3][r] = f2bf(v.w);
  }
  __syncthreads();
  int cr = threadIdx.x >> 2, rg = threadIdx.x & 3;
  int4 w0 = *(const int4*)&tile[cr][rg * 16];
  int4 w1 = *(const int4*)&tile[cr][rg * 16 + 8];
  unsigned short* op = out + (size_t)(c0 + cr) * R + r0 + rg * 16;
  *(int4*)op = w0;
  *(int4*)(op + 8) = w1;
}

// ---------------- standalone transpose kernel -----------------------------
__global__ __launch_bounds__(256) void transpose_kernel(
    const float* in0, const float* in1, const float* in2,
    unsigned short* o0, unsigned short* o1, unsigned short* o2,
    int R, int Cc) {
  const float* in = blockIdx.z == 0 ? in0 : (blockIdx.z == 1 ? in1 : in2);
  unsigned short* out = blockIdx.z == 0 ? o0 : (blockIdx.z == 1 ? o1 : o2);
  __shared__ __align__(16) unsigned short tile[64][80];
  transpose_tile(in, out, R, Cc, blockIdx.x, blockIdx.y, tile);
}

// ---------------- 2-phase double-buffered bf16 GEMM: A[M,K] x Bt[N,K]^T ---
// EPI: 0=f32 store, 1=f32 addsrc+acc, 2=relu^2 -> bf16
template <int EPI>
__global__ __launch_bounds__(256) void gemm2_kernel(
    const unsigned short* A0, const unsigned short* A1, const unsigned short* A2,
    const unsigned short* B0, const unsigned short* B1, const unsigned short* B2,
    void* C0, void* C1, void* C2, const float* __restrict__ addsrc,
    int M, int K, int N) {
  int z = blockIdx.z;
  const unsigned short* A = z == 0 ? A0 : (z == 1 ? A1 : A2);
  const unsigned short* Bt = z == 0 ? B0 : (z == 1 ? B1 : B2);
  void* Cout = z == 0 ? C0 : (z == 1 ? C1 : C2);
  __shared__ __align__(16) unsigned short As[2][128 * 32];
  __shared__ __align__(16) unsigned short Bs[2][128 * 32];
  const int tid = threadIdx.x, lane = tid & 63, wid = tid >> 6;
  const int bm = blockIdx.y * 128, bn = blockIdx.x * 128;
  const int wr = wid >> 1, wc = wid & 1;
  const int mrow = lane & 15, krow = lane >> 4;
  auto stage = [&](int buf, int kt) {
#pragma unroll
    for (int q = 0; q < 2; ++q) {
      int s = q * 2048 + tid * 8;
      int m = s >> 5, k = s & 31;
      GLD16(A + (size_t)(bm + m) * K + kt + k, &As[buf][s]);
      GLD16(Bt + (size_t)(bn + m) * K + kt + k, &Bs[buf][s]);
    }
  };
  f32x4 acc[4][4] = {};
  stage(0, 0);
  __syncthreads();
  int buf = 0;
  for (int kt = 0; kt < K; kt += 32) {
    if (kt + 32 < K) stage(buf ^ 1, kt + 32);
    short8v af[4], bfrag[4];
#pragma unroll
    for (int i = 0; i < 4; ++i)
      af[i] = *(const short8v*)&As[buf][(wr * 64 + i * 16 + mrow) * 32 + krow * 8];
#pragma unroll
    for (int j = 0; j < 4; ++j)
      bfrag[j] = *(const short8v*)&Bs[buf][(wc * 64 + j * 16 + mrow) * 32 + krow * 8];
#pragma unroll
    for (int i = 0; i < 4; ++i)
#pragma unroll
      for (int j = 0; j < 4; ++j)
        acc[i][j] = __builtin_amdgcn_mfma_f32_16x16x32_bf16(af[i], bfrag[j], acc[i][j], 0, 0, 0);
    __syncthreads();
    buf ^= 1;
  }
#pragma unroll
  for (int i = 0; i < 4; ++i)
#pragma unroll
    for (int j = 0; j < 4; ++j)
#pragma unroll
      for (int e = 0; e < 4; ++e) {
        int grow = bm + wr * 64 + i * 16 + (lane >> 4) * 4 + e;
        int gcol = bn + wc * 64 + j * 16 + (lane & 15);
        size_t off = (size_t)grow * N + gcol;
        float v = acc[i][j][e];
        if constexpr (EPI == 0) ((float*)Cout)[off] = v;
        else if constexpr (EPI == 1) ((float*)Cout)[off] = addsrc[off] + v;
        else { float r = v > 0.f ? v : 0.f; ((unsigned short*)Cout)[off] = f2bf(r * r); }
      }
}

// ---------------- split-K variant: z = K-slice, bf16 partials -------------
__global__ __launch_bounds__(256) void gemm2ks_kernel(
    const unsigned short* __restrict__ A, const unsigned short* __restrict__ Bt,
    unsigned short* __restrict__ P, int M, int KH, int Ktot, int N) {
  int kz = blockIdx.z;
  const size_t kbase = (size_t)kz * KH;
  __shared__ __align__(16) unsigned short As[2][128 * 32];
  __shared__ __align__(16) unsigned short Bs[2][128 * 32];
  const int tid = threadIdx.x, lane = tid & 63, wid = tid >> 6;
  const int bm = blockIdx.y * 128, bn = blockIdx.x * 128;
  const int wr = wid >> 1, wc = wid & 1;
  const int mrow = lane & 15, krow = lane >> 4;
  auto stage = [&](int buf, int kt) {
#pragma unroll
    for (int q = 0; q < 2; ++q) {
      int s = q * 2048 + tid * 8;
      int m = s >> 5, k = s & 31;
      GLD16(A + (size_t)(bm + m) * Ktot + kbase + kt + k, &As[buf][s]);
      GLD16(Bt + (size_t)(bn + m) * Ktot + kbase + kt + k, &Bs[buf][s]);
    }
  };
  f32x4 acc[4][4] = {};
  stage(0, 0);
  __syncthreads();
  int buf = 0;
  for (int kt = 0; kt < KH; kt += 32) {
    if (kt + 32 < KH) stage(buf ^ 1, kt + 32);
    short8v af[4], bfrag[4];
#pragma unroll
    for (int i = 0; i < 4; ++i)
      af[i] = *(const short8v*)&As[buf][(wr * 64 + i * 16 + mrow) * 32 + krow * 8];
#pragma unroll
    for (int j = 0; j < 4; ++j)
      bfrag[j] = *(const short8v*)&Bs[buf][(wc * 64 + j * 16 + mrow) * 32 + krow * 8];
#pragma unroll
    for (int i = 0; i < 4; ++i)
#pragma unroll
      for (int j = 0; j < 4; ++j)
        acc[i][j] = __builtin_amdgcn_mfma_f32_16x16x32_bf16(af[i], bfrag[j], acc[i][j], 0, 0, 0);
    __syncthreads();
    buf ^= 1;
  }
  unsigned short* Pz = P + (size_t)kz * M * N;
#pragma unroll
  for (int i = 0; i < 4; ++i)
#pragma unroll
    for (int j = 0; j < 4; ++j)
#pragma unroll
      for (int e = 0; e < 4; ++e) {
        int grow = bm + wr * 64 + i * 16 + (lane >> 4) * 4 + e;
        int gcol = bn + wc * 64 + j * 16 + (lane & 15);
        Pz[(size_t)grow * N + gcol] = f2bf(acc[i][j][e]);
      }
}

// ---------------- split-K x 3-batch variant (rkv), bf16 partials ----------
__global__ __launch_bounds__(256) void gemm2ks3_kernel(
    const unsigned short* A0, const unsigned short* A1, const unsigned short* A2,
    const unsigned short* B0, const unsigned short* B1, const unsigned short* B2,
    unsigned short* __restrict__ P, int M, int KH, int Ktot, int N) {
  int z = blockIdx.z;
  int batch = z % 3, kz = z / 3;
  const unsigned short* A = batch == 0 ? A0 : (batch == 1 ? A1 : A2);
  const unsigned short* Bt = batch == 0 ? B0 : (batch == 1 ? B1 : B2);
  const size_t kbase = (size_t)kz * KH;
  __shared__ __align__(16) unsigned short As[2][128 * 32];
  __shared__ __align__(16) unsigned short Bs[2][128 * 32];
  const int tid = threadIdx.x, lane = tid & 63, wid = tid >> 6;
  const int bm = blockIdx.y * 128, bn = blockIdx.x * 128;
  const int wr = wid >> 1, wc = wid & 1;
  const int mrow = lane & 15, krow = lane >> 4;
  auto stage = [&](int buf, int kt) {
#pragma unroll
    for (int q = 0; q < 2; ++q) {
      int s = q * 2048 + tid * 8;
      int m = s >> 5, k = s & 31;
      GLD16(A + (size_t)(bm + m) * Ktot + kbase + kt + k, &As[buf][s]);
      GLD16(Bt + (size_t)(bn + m) * Ktot + kbase + kt + k, &Bs[buf][s]);
    }
  };
  f32x4 acc[4][4] = {};
  stage(0, 0);
  __syncthreads();
  int buf = 0;
  for (int kt = 0; kt < KH; kt += 32) {
    if (kt + 32 < KH) stage(buf ^ 1, kt + 32);
    short8v af[4], bfrag[4];
#pragma unroll
    for (int i = 0; i < 4; ++i)
      af[i] = *(const short8v*)&As[buf][(wr * 64 + i * 16 + mrow) * 32 + krow * 8];
#pragma unroll
    for (int j = 0; j < 4; ++j)
      bfrag[j] = *(const short8v*)&Bs[buf][(wc * 64 + j * 16 + mrow) * 32 + krow * 8];
#pragma unroll
    for (int i = 0; i < 4; ++i)
#pragma unroll
      for (int j = 0; j < 4; ++j)
        acc[i][j] = __builtin_amdgcn_mfma_f32_16x16x32_bf16(af[i], bfrag[j], acc[i][j], 0, 0, 0);
    __syncthreads();
    buf ^= 1;
  }
  unsigned short* Pz = P + (size_t)z * M * N;
#pragma unroll
  for (int i = 0; i < 4; ++i)
#pragma unroll
    for (int j = 0; j < 4; ++j)
#pragma unroll
      for (int e = 0; e < 4; ++e) {
        int grow = bm + wr * 64 + i * 16 + (lane >> 4) * 4 + e;
        int gcol = bn + wc * 64 + j * 16 + (lane & 15);
        Pz[(size_t)grow * N + gcol] = f2bf(acc[i][j][e]);
      }
}

// ---------------- o = a + p0+p1+p2+p3 (bf16 partials at stride T*C) -------
__global__ __launch_bounds__(256) void add5_kernel(
    const float* __restrict__ a, const unsigned short* __restrict__ p,
    float* __restrict__ o) {
  size_t i = ((size_t)blockIdx.x * 256 + threadIdx.x) * 8;
  const size_t TC = (size_t)T_ * C_;
  float va[8], v0[8], v1[8], v2[8], v3[8], r[8];
  load8f(a + i, va);
  load8bf(p + i, v0);
  load8bf(p + i + TC, v1);
  load8bf(p + i + 2 * TC, v2);
  load8bf(p + i + 3 * TC, v3);
#pragma unroll
  for (int k = 0; k < 8; ++k) r[k] = va[k] + v0[k] + v1[k] + v2[k] + v3[k];
  *(float4*)(o + i) = make_float4(r[0], r[1], r[2], r[3]);
  *(float4*)(o + i + 4) = make_float4(r[4], r[5], r[6], r[7]);
}

// ---------------- add5 + fK transpose fused (blocks >= 1024) --------------
__global__ __launch_bounds__(256) void add5tr_kernel(
    const float* __restrict__ a, const unsigned short* __restrict__ p,
    float* __restrict__ o, const float* __restrict__ fK,
    unsigned short* __restrict__ fKt) {
  int bid = blockIdx.x;
  if (bid < 1024) {
    size_t i = ((size_t)bid * 256 + threadIdx.x) * 8;
    const size_t TC = (size_t)T_ * C_;
    float va[8], v0[8], v1[8], v2[8], v3[8], r[8];
    load8f(a + i, va);
    load8bf(p + i, v0);
    load8bf(p + i + TC, v1);
    load8bf(p + i + 2 * TC, v2);
    load8bf(p + i + 3 * TC, v3);
#pragma unroll
    for (int k = 0; k < 8; ++k) r[k] = va[k] + v0[k] + v1[k] + v2[k] + v3[k];
    *(float4*)(o + i) = make_float4(r[0], r[1], r[2], r[3]);
    *(float4*)(o + i + 4) = make_float4(r[4], r[5], r[6], r[7]);
    return;
  }
  // fK transpose: fp32 [C_][4C] -> bf16 [4C][C_]; 128x32 tiles
  __shared__ __align__(16) unsigned short tile[64][80];
  int idx = bid - 1024;                 // 0..4095
  transpose_tile(fK, fKt, C_, 4 * C_, idx & 127, idx >> 7, tile);
}

// ---------------- K-split lora-down GEMMs (BN=64, z=mat*8+kz) -------------
__global__ __launch_bounds__(256) void gemm_ks3_kernel(
    const unsigned short* A0, const unsigned short* A1, const unsigned short* A2,
    const unsigned short* B0, const unsigned short* B1, const unsigned short* B2,
    float* P0, float* P1, float* P2, int K, int N) {
  int mz = blockIdx.z >> 3, kz = blockIdx.z & 7;
  const unsigned short* A = mz == 0 ? A0 : (mz == 1 ? A1 : A2);
  const unsigned short* Bt = mz == 0 ? B0 : (mz == 1 ? B1 : B2);
  float* partial = mz == 0 ? P0 : (mz == 1 ? P1 : P2);
  __shared__ __align__(16) unsigned short As[2][128 * 32];
  __shared__ __align__(16) unsigned short Bs[2][64 * 32];
  const int tid = threadIdx.x, lane = tid & 63, wid = tid >> 6;
  const int bn = blockIdx.x * 64, bm = blockIdx.y * 128;
  const int wr = wid >> 1, wc = wid & 1;
  const int mrow = lane & 15, krow = lane >> 4;
  auto stage = [&](int buf, int kt) {
#pragma unroll
    for (int q = 0; q < 2; ++q) {
      int s = q * 2048 + tid * 8;
      int m = s >> 5, k = s & 31;
      GLD16(A + (size_t)(bm + m) * K + kt + k, &As[buf][s]);
    }
    {
      int s = tid * 8;
      int n = s >> 5, k = s & 31;
      GLD16(Bt + (size_t)(bn + n) * K + kt + k, &Bs[buf][s]);
    }
  };
  f32x4 acc[4][2] = {};
  int k0 = kz * 256;
  stage(0, k0);
  __syncthreads();
  int buf = 0;
  for (int kt = k0; kt < k0 + 256; kt += 32) {
    if (kt + 32 < k0 + 256) stage(buf ^ 1, kt + 32);
    short8v af[4], bfrag[2];
#pragma unroll
    for (int i = 0; i < 4; ++i)
      af[i] = *(const short8v*)&As[buf][(wr * 64 + i * 16 + mrow) * 32 + krow * 8];
#pragma unroll
    for (int j = 0; j < 2; ++j)
      bfrag[j] = *(const short8v*)&Bs[buf][(wc * 32 + j * 16 + mrow) * 32 + krow * 8];
#pragma unroll
    for (int i = 0; i < 4; ++i)
#pragma unroll
      for (int j = 0; j < 2; ++j)
        acc[i][j] = __builtin_amdgcn_mfma_f32_16x16x32_bf16(af[i], bfrag[j], acc[i][j], 0, 0, 0);
    __syncthreads();
    buf ^= 1;
  }
#pragma unroll
  for (int i = 0; i < 4; ++i)
#pragma unroll
    for (int j = 0; j < 2; ++j)
#pragma unroll
      for (int e = 0; e < 4; ++e) {
        int row = bm + wr * 64 + i * 16 + (lane >> 4) * 4 + e;
        int col = bn + wc * 32 + j * 16 + (lane & 15);
        partial[((size_t)kz * 1024 + row) * N + col] = acc[i][j][e];
      }
}

__global__ __launch_bounds__(256) void gemm_ks_kernel(
    const unsigned short* __restrict__ A, const unsigned short* __restrict__ Bt,
    float* __restrict__ partial, int K, int N) {
  __shared__ __align__(16) unsigned short As[2][128 * 32];
  __shared__ __align__(16) unsigned short Bs[2][64 * 32];
  const int tid = threadIdx.x, lane = tid & 63, wid = tid >> 6;
  const int bn = blockIdx.x * 64, bm = blockIdx.y * 128, kz = blockIdx.z;
  const int wr = wid >> 1, wc = wid & 1;
  const int mrow = lane & 15, krow = lane >> 4;
  auto stage = [&](int buf, int kt) {
#pragma unroll
    for (int q = 0; q < 2; ++q) {
      int s = q * 2048 + tid * 8;
      int m = s >> 5, k = s & 31;
      GLD16(A + (size_t)(bm + m) * K + kt + k, &As[buf][s]);
    }
    {
      int s = tid * 8;
      int n = s >> 5, k = s & 31;
      GLD16(Bt + (size_t)(bn + n) * K + kt + k, &Bs[buf][s]);
    }
  };
  f32x4 acc[4][2] = {};
  int k0 = kz * 256;
  stage(0, k0);
  __syncthreads();
  int buf = 0;
  for (int kt = k0; kt < k0 + 256; kt += 32) {
    if (kt + 32 < k0 + 256) stage(buf ^ 1, kt + 32);
    short8v af[4], bfrag[2];
#pragma unroll
    for (int i = 0; i < 4; ++i)
      af[i] = *(const short8v*)&As[buf][(wr * 64 + i * 16 + mrow) * 32 + krow * 8];
#pragma unroll
    for (int j = 0; j < 2; ++j)
      bfrag[j] = *(const short8v*)&Bs[buf][(wc * 32 + j * 16 + mrow) * 32 + krow * 8];
#pragma unroll
    for (int i = 0; i < 4; ++i)
#pragma unroll
      for (int j = 0; j < 2; ++j)
        acc[i][j] = __builtin_amdgcn_mfma_f32_16x16x32_bf16(af[i], bfrag[j], acc[i][j], 0, 0, 0);
    __syncthreads();
    buf ^= 1;
  }
#pragma unroll
  for (int i = 0; i < 4; ++i)
#pragma unroll
    for (int j = 0; j < 2; ++j)
#pragma unroll
      for (int e = 0; e < 4; ++e) {
        int row = bm + wr * 64 + i * 16 + (lane >> 4) * 4 + e;
        int col = bn + wc * 32 + j * 16 + (lane & 15);
        partial[((size_t)kz * 1024 + row) * N + col] = acc[i][j][e];
      }
}

__global__ __launch_bounds__(128) void lora_combine_kernel(
    const float* __restrict__ pw, const float* __restrict__ pa,
    const float* __restrict__ pv, const float* __restrict__ pg,
    unsigned short* __restrict__ hw, unsigned short* __restrict__ ha,
    unsigned short* __restrict__ hv, unsigned short* __restrict__ hg) {
  int t = blockIdx.x, which = blockIdx.y, tid = threadIdx.x;
  int Nl = (which == 3) ? 128 : 64;
  if (tid >= Nl) return;
  const float* p = which == 0 ? pw : which == 1 ? pa : which == 2 ? pv : pg;
  float s = 0.f;
#pragma unroll
  for (int kz = 0; kz < 8; ++kz) s += p[((size_t)kz * 1024 + t) * Nl + tid];
  float r = which == 0 ? tanhf(s) : (which == 3 ? sigm(s) : s);
  unsigned short* o = which == 0 ? hw : which == 1 ? ha : which == 2 ? hv : hg;
  o[t * Nl + tid] = f2bf(r);
}

// ---------------- post: rkv bf16-partial combine + pack scan inputs -------
// scanin[h][t][6][64] fp32: seg 0=w, 1=kkn, 2=-kkn*a, 3=k2, 4=v, 5=r
__global__ __launch_bounds__(256) void post_kernel(
    const unsigned short* __restrict__ qRKV, const float* __restrict__ wpre,
    const float* __restrict__ apre, const float* __restrict__ vpre,
    const float* __restrict__ vfirst, const float* __restrict__ w0,
    const float* __restrict__ a0, const float* __restrict__ v0_,
    const float* __restrict__ k_k, const float* __restrict__ k_a,
    float* __restrict__ scanin) {
  int t = blockIdx.x, tid = threadIdx.x;
  int c = tid * 8, h = tid >> 3, j = c & 63;
  size_t o = (size_t)t * C_ + c;
  const size_t TC = (size_t)T_ * C_;
  float rv[8], kv[8], vv[8], t0[8], wv[8], av[8], vp[8], vf[8];
  load8bf(qRKV + o, rv);          load8bf(qRKV + 3 * TC + o, t0);
#pragma unroll
  for (int i = 0; i < 8; ++i) rv[i] += t0[i];
  load8bf(qRKV + TC + o, kv);     load8bf(qRKV + 4 * TC + o, t0);
#pragma unroll
  for (int i = 0; i < 8; ++i) kv[i] += t0[i];
  load8bf(qRKV + 2 * TC + o, vv); load8bf(qRKV + 5 * TC + o, t0);
#pragma unroll
  for (int i = 0; i < 8; ++i) vv[i] += t0[i];
  load8f(wpre + o, wv); load8f(apre + o, av); load8f(vpre + o, vp);
  load8f(vfirst + o, vf);
  float ckk[8], cka[8], cw0[8], ca0[8], cv0[8];
  load8f(k_k + c, ckk); load8f(k_a + c, cka); load8f(w0 + c, cw0);
  load8f(a0 + c, ca0); load8f(v0_ + c, cv0);
  float kk[8]; float ss = 0.f;
#pragma unroll
  for (int i = 0; i < 8; ++i) { kk[i] = kv[i] * ckk[i]; ss += kk[i] * kk[i]; }
  ss += __shfl_xor(ss, 1); ss += __shfl_xor(ss, 2); ss += __shfl_xor(ss, 4);
  float rdn = 1.f / fmaxf(sqrtf(ss), 1e-12f);
  float sw[8], skn[8], scc[8], sk2[8], sv[8];
#pragma unroll
  for (int i = 0; i < 8; ++i) {
    float kkn = kk[i] * rdn;
    float a = sigm(ca0[i] + av[i]);
    skn[i] = kkn;
    scc[i] = -kkn * a;
    sk2[i] = kv[i] * (1.f + (a - 1.f) * cka[i]);
    float sg = sigm(cv0[i] + vp[i]);
    sv[i] = vv[i] + (vf[i] - vv[i]) * sg;
    sw[i] = __expf(-0.606531f * sigm(cw0[i] + wv[i]));
  }
  float* bp = scanin + ((size_t)h * T_ + t) * 384 + j;
  ((float4*)(bp + 0))[0]   = make_float4(sw[0], sw[1], sw[2], sw[3]);
  ((float4*)(bp + 4))[0]   = make_float4(sw[4], sw[5], sw[6], sw[7]);
  ((float4*)(bp + 64))[0]  = make_float4(skn[0], skn[1], skn[2], skn[3]);
  ((float4*)(bp + 68))[0]  = make_float4(skn[4], skn[5], skn[6], skn[7]);
  ((float4*)(bp + 128))[0] = make_float4(scc[0], scc[1], scc[2], scc[3]);
  ((float4*)(bp + 132))[0] = make_float4(scc[4], scc[5], scc[6], scc[7]);
  ((float4*)(bp + 192))[0] = make_float4(sk2[0], sk2[1], sk2[2], sk2[3]);
  ((float4*)(bp + 196))[0] = make_float4(sk2[4], sk2[5], sk2[6], sk2[7]);
  ((float4*)(bp + 256))[0] = make_float4(sv[0], sv[1], sv[2], sv[3]);
  ((float4*)(bp + 260))[0] = make_float4(sv[4], sv[5], sv[6], sv[7]);
  ((float4*)(bp + 320))[0] = make_float4(rv[0], rv[1], rv[2], rv[3]);
  ((float4*)(bp + 324))[0] = make_float4(rv[4], rv[5], rv[6], rv[7]);
}

// ---------------- scan + O/fV transposes fused ----------------------------
struct SR { float wv[4], nv[4], cv[4], kv[4], rv[4], vvv; };

template <int CTRL>
__device__ __forceinline__ float dppadd(float x) {
  int y = __builtin_amdgcn_update_dpp(0, __float_as_int(x), CTRL, 0xF, 0xF, true);
  return x + __int_as_float(y);
}
// full sum across each 16-lane row, result in all 16 lanes (pure VALU)
__device__ __forceinline__ float red16(float x) {
  x = dppadd<0xB1>(x);
  x = dppadd<0x4E>(x);
  x = dppadd<0x140>(x);
  x = dppadd<0x141>(x);
  return x;
}

__device__ __forceinline__ void loadstep(const float* S, SR& R, int p4, int row) {
  load4f(S + p4, R.wv);
  load4f(S + 64 + p4, R.nv);
  load4f(S + 128 + p4, R.cv);
  load4f(S + 192 + p4, R.kv);
  load4f(S + 320 + p4, R.rv);
  R.vvv = S[256 + row];
}

__device__ __forceinline__ void stepcomp(const SR& R, float* st, int part,
                                         float* __restrict__ ob, size_t oidx) {
  float p0 = fmaf(st[0], R.nv[0], 0.f);
  float p1 = fmaf(st[1], R.nv[1], 0.f);
  p0 = fmaf(st[2], R.nv[2], p0);
  p1 = fmaf(st[3], R.nv[3], p1);
  float sa = red16(p0 + p1);
  float s0 = 0.f, s1 = 0.f;
#pragma unroll
  for (int i = 0; i < 4; ++i) {
    float t = fmaf(st[i], R.wv[i], fmaf(sa, R.cv[i], R.vvv * R.kv[i]));
    st[i] = t;
    if (i & 1) s1 = fmaf(t, R.rv[i], s1);
    else s0 = fmaf(t, R.rv[i], s0);
  }
  float so = red16(s0 + s1);
  if (part == 0) ob[oidx] = so;
}

// blocks 0..511: scan (tid<64 active; 16p x 4r per block, head->XCD pinned).
// blocks 512..1535: O transpose tiles. blocks 1536..5631: fV transpose tiles.
__global__ __launch_bounds__(256) void scanfuse_kernel(
    const float* __restrict__ scanin, const float* __restrict__ vk0,
    float* __restrict__ outs,
    const float* __restrict__ Osrc, unsigned short* __restrict__ Ot,
    const float* __restrict__ fVsrc, unsigned short* __restrict__ fVt) {
  int bid = blockIdx.x;
  if (bid >= 512) {
    __shared__ __align__(16) unsigned short tile[64][80];
    int idx = bid - 512;
    if (idx < 1024) transpose_tile(Osrc, Ot, C_, C_, idx & 31, idx >> 5, tile);
    else { idx -= 1024; transpose_tile(fVsrc, fVt, 4 * C_, C_, idx & 31, idx >> 5, tile); }
    return;
  }
  if (threadIdx.x >= 64) return;
  int h = (bid & 7) + 8 * ((bid >> 3) & 3);  // h&7 fixed per XCD
  int rg = bid >> 5;                          // 0..15
  int tid = threadIdx.x;
  int part = tid & 15, row = rg * 4 + (tid >> 4);
  int p4 = part * 4;
  float st[4];
  load4f(vk0 + ((size_t)h * NH + row) * NH + p4, st);
  const float* src = scanin + (size_t)h * T_ * 384;
  float* ob = outs + h * NH + row;
  SR A, B, C, D;
  loadstep(src + 0 * 384, A, p4, row);
  loadstep(src + 1 * 384, B, p4, row);
  loadstep(src + 2 * 384, C, p4, row);
  int s = 0;
  for (; s < T_ - 4; s += 4) {
    const float* sp = src + (size_t)s * 384;
    loadstep(sp + 3 * 384, D, p4, row);
    stepcomp(A, st, part, ob, (size_t)(s + 0) * C_);
    loadstep(sp + 4 * 384, A, p4, row);
    stepcomp(B, st, part, ob, (size_t)(s + 1) * C_);
    loadstep(sp + 5 * 384, B, p4, row);
    stepcomp(C, st, part, ob, (size_t)(s + 2) * C_);
    loadstep(sp + 6 * 384, C, p4, row);
    stepcomp(D, st, part, ob, (size_t)(s + 3) * C_);
  }
  // tail: s == T_-4; A,B,C hold s..s+2
  loadstep(src + (size_t)(T_ - 1) * 384, D, p4, row);
  stepcomp(A, st, part, ob, (size_t)(s + 0) * C_);
  stepcomp(B, st, part, ob, (size_t)(s + 1) * C_);
  stepcomp(C, st, part, ob, (size_t)(s + 2) * C_);
  stepcomp(D, st, part, ob, (size_t)(s + 3) * C_);
}

// ---------------- groupnorm + bonus + gate --------------------------------
__global__ __launch_bounds__(256) void gnb_kernel(
    const float* __restrict__ outs, const float* __restrict__ scanin,
    const float* __restrict__ g, const float* __restrict__ rk,
    const float* __restrict__ gw, const float* __restrict__ gb,
    unsigned short* __restrict__ attin) {
  int t = blockIdx.x, tid = threadIdx.x;
  int c = tid * 8, h = tid >> 3, j = c & 63;
  float o[8], gv[8], rkv[8];
  load8f(outs + (size_t)t * C_ + c, o);
  load8f(g + (size_t)t * C_ + c, gv);
  load8f(rk + c, rkv);
  size_t sbase = ((size_t)h * T_ + t) * 384 + j;
  float rv[8], k2[8], vv[8];
  load8f(scanin + sbase + 320, rv);
  load8f(scanin + sbase + 192, k2);
  load8f(scanin + sbase + 256, vv);
  float s = 0.f, q = 0.f, bs = 0.f;
#pragma unroll
  for (int i = 0; i < 8; ++i) {
    s += o[i]; q += o[i] * o[i];
    bs += rv[i] * k2[i] * rkv[i];
  }
  s += __shfl_xor(s, 1); s += __shfl_xor(s, 2); s += __shfl_xor(s, 4);
  q += __shfl_xor(q, 1); q += __shfl_xor(q, 2); q += __shfl_xor(q, 4);
  bs += __shfl_xor(bs, 1); bs += __shfl_xor(bs, 2); bs += __shfl_xor(bs, 4);
  float mean = s * (1.f / NH);
  float var = q * (1.f / NH) - mean * mean;
  float rstd = rsqrtf(var + 0.00064f);
  float res[8];
#pragma unroll
  for (int i = 0; i < 8; ++i) {
    float gn = (o[i] - mean) * rstd * gw[c + i] + gb[c + i];
    res[i] = (gn + bs * vv[i]) * gv[i];
  }
  store8bf(attin + (size_t)t * C_ + c, res);
}

extern "C" void kernel_launch(void* const* d_in, const int* in_sizes, int n_in,
                              void* d_out, int out_size, void* d_ws, size_t ws_size,
                              hipStream_t stream) {
  const float* x       = (const float*)d_in[0];
  const float* xprev_a = (const float*)d_in[1];
  const float* vk0     = (const float*)d_in[2];
  const float* xprev_f = (const float*)d_in[3];
  const float* vfirst  = (const float*)d_in[4];
  const float* ln1w = (const float*)d_in[5];
  const float* ln1b = (const float*)d_in[6];
  const float* m_r = (const float*)d_in[7];
  const float* m_w = (const float*)d_in[8];
  const float* m_k = (const float*)d_in[9];
  const float* m_v = (const float*)d_in[10];
  const float* m_a = (const float*)d_in[11];
  const float* m_g = (const float*)d_in[12];
  const float* w0 = (const float*)d_in[13];
  const float* w1 = (const float*)d_in[14];
  const float* w2 = (const float*)d_in[15];
  const float* a0 = (const float*)d_in[16];
  const float* a1 = (const float*)d_in[17];
  const float* a2 = (const float*)d_in[18];
  const float* v0 = (const float*)d_in[19];
  const float* v1 = (const float*)d_in[20];
  const float* v2 = (const float*)d_in[21];
  const float* g1 = (const float*)d_in[22];
  const float* g2 = (const float*)d_in[23];
  const float* k_k = (const float*)d_in[24];
  const float* k_a = (const float*)d_in[25];
  const float* r_k = (const float*)d_in[26];
  const float* R_ = (const float*)d_in[27];
  const float* K_ = (const float*)d_in[28];
  const float* V_ = (const float*)d_in[29];
  const float* O_ = (const float*)d_in[30];
  const float* lnxw = (const float*)d_in[31];
  const float* lnxb = (const float*)d_in[32];
  const float* ln2w = (const float*)d_in[33];
  const float* ln2b = (const float*)d_in[34];
  const float* fxk = (const float*)d_in[35];
  const float* fK = (const float*)d_in[36];
  const float* fV = (const float*)d_in[37];
  float* out = (float*)d_out;

  char* ws = (char*)d_ws;
  const size_t MB = 1ull << 20;
  // ---- workspace layout (scan-fused transposes; peak 132 MB) -------------
  // 0-4: attin (ph7+); 0-1.25: w1t..g1t / w2t..g2t (ph4); 1.31-2: hwb..hgb
  // 2-4: pw; 4-6: pa; 6-8: pv; 8-12: pg (ph4)
  // 4-8: xr; 8-12: xw; 12-16: xk; 16-20: xv; 20-24: xa; 24-28: xg (ph2-3)
  // 4-12: wpre; 12-20: apre; 20-28: vpre (ph4b-5, dead after post)
  // 28-52: qRKV bf16 (ph3-5, dead after post)
  // 4-36: fVt bf16 (written during scanfuse, read ph11)
  // 36-40: xkf (ph9b-10)
  // 52-60: outsb (ph6-7); 60-68: Ot (scanfuse..ph8) then x_att (ph9+)
  // 76-84: g_buf (ph4-7); 84-132: scanin fp32 (ph5-7, dead after gnb)
  // 84-108: Rt/Kt/Vt (ph3); 84-100: qO bf16 (ph8-9) then hffn (ph10-11)
  // 100-132: fKt (add5tr..ph10); 100-116: pF bf16 (ph11, over dead fKt)
  unsigned short* attin = (unsigned short*)(ws + 0 * MB);
  unsigned short* xr    = (unsigned short*)(ws + 4 * MB);
  unsigned short* xw    = (unsigned short*)(ws + 8 * MB);
  unsigned short* xk    = (unsigned short*)(ws + 12 * MB);
  unsigned short* xv    = (unsigned short*)(ws + 16 * MB);
  unsigned short* xa    = (unsigned short*)(ws + 20 * MB);
  unsigned short* xg    = (unsigned short*)(ws + 24 * MB);
  float* wpre  = (float*)(ws + 4 * MB);
  float* apre  = (float*)(ws + 12 * MB);
  float* vpre  = (float*)(ws + 20 * MB);
  unsigned short* fVt = (unsigned short*)(ws + 4 * MB);
  unsigned short* xkf = (unsigned short*)(ws + 36 * MB);
  unsigned short* qRKV = (unsigned short*)(ws + 28 * MB);
  float* outsb = (float*)(ws + 52 * MB);
  unsigned short* Ot = (unsigned short*)(ws + 60 * MB);
  float* x_att = (float*)(ws + 60 * MB);
  float* g_buf = (float*)(ws + 76 * MB);
  float* scanin = (float*)(ws + 84 * MB);
  unsigned short* Rt  = (unsigned short*)(ws + 84 * MB);
  unsigned short* Kt  = (unsigned short*)(ws + 92 * MB);
  unsigned short* Vt  = (unsigned short*)(ws + 100 * MB);
  unsigned short* qO  = (unsigned short*)(ws + 84 * MB);
  unsigned short* hffn = (unsigned short*)(ws + 84 * MB);
  unsigned short* fKt  = (unsigned short*)(ws + 100 * MB);
  unsigned short* pF   = (unsigned short*)(ws + 100 * MB);
  unsigned short* w1t = (unsigned short*)(ws + 0);
  unsigned short* a1t = (unsigned short*)(ws + 262144);
  unsigned short* v1t = (unsigned short*)(ws + 524288);
  unsigned short* g1t = (unsigned short*)(ws + 786432);
  unsigned short* w2t = (unsigned short*)(ws + 0);
  unsigned short* a2t = (unsigned short*)(ws + 262144);
  unsigned short* v2t = (unsigned short*)(ws + 524288);
  unsigned short* g2t = (unsigned short*)(ws + 786432);
  unsigned short* hwb = (unsigned short*)(ws + 1376256);
  unsigned short* hab = (unsigned short*)(ws + 1507328);
  unsigned short* hvb = (unsigned short*)(ws + 1638400);
  unsigned short* hgb = (unsigned short*)(ws + 1769472);
  float* pw = (float*)(ws + 2 * MB);
  float* pa = (float*)(ws + 4 * MB);
  float* pv = (float*)(ws + 6 * MB);
  float* pg = (float*)(ws + 8 * MB);

  // TMix front: fused LN+mix, projections
  lnmix6_kernel<<<T_, 256, 0, stream>>>(x, xprev_a, ln1w, ln1b,
                                        m_r, m_w, m_k, m_v, m_a, m_g,
                                        xr, xw, xk, xv, xa, xg);
  transpose_kernel<<<dim3(32, 32, 3), 256, 0, stream>>>(R_, K_, V_, Rt, Kt, Vt, C_, C_);
  gemm2ks3_kernel<<<dim3(16, 8, 6), 256, 0, stream>>>(xr, xk, xv, Rt, Kt, Vt,
                                                      qRKV, T_, 1024, C_, C_);
  // loras
  transpose_kernel<<<dim3(1, 32, 3), 256, 0, stream>>>(w1, a1, v1, w1t, a1t, v1t, C_, 64);
  transpose_kernel<<<dim3(2, 32, 1), 256, 0, stream>>>(g1, g1, g1, g1t, g1t, g1t, C_, 128);
  gemm_ks3_kernel<<<dim3(1, 8, 24), 256, 0, stream>>>(xw, xa, xv, w1t, a1t, v1t,
                                                      pw, pa, pv, C_, 64);
  gemm_ks_kernel<<<dim3(2, 8, 8), 256, 0, stream>>>(xg, g1t, pg, C_, 128);
  lora_combine_kernel<<<dim3(T_, 4), 128, 0, stream>>>(pw, pa, pv, pg, hwb, hab, hvb, hgb);
  transpose_kernel<<<dim3(32, 1, 3), 256, 0, stream>>>(w2, a2, v2, w2t, a2t, v2t, 64, C_);
  transpose_kernel<<<dim3(32, 2, 1), 256, 0, stream>>>(g2, g2, g2, g2t, g2t, g2t, 128, C_);
  gemm2_kernel<0><<<dim3(16, 8, 3), 256, 0, stream>>>(hwb, hab, hvb, w2t, a2t, v2t,
                                                      wpre, apre, vpre, nullptr, T_, 64, C_);
  gemm2_kernel<0><<<dim3(16, 8, 1), 256, 0, stream>>>(hgb, hgb, hgb, g2t, g2t, g2t,
                                                      g_buf, g_buf, g_buf, nullptr, T_, 128, C_);
  // scan (post fuses rkv combine; scanfuse hides O/fV transposes under scan)
  post_kernel<<<T_, 256, 0, stream>>>(qRKV, wpre, apre, vpre, vfirst,
                                      w0, a0, v0, k_k, k_a, scanin);
  scanfuse_kernel<<<5632, 256, 0, stream>>>(scanin, vk0, outsb, O_, Ot, fV, fVt);
  gnb_kernel<<<T_, 256, 0, stream>>>(outsb, scanin, g_buf, r_k, lnxw, lnxb, attin);
  // output proj (split-K x4, bf16 partials) + CMix (fK transpose rides add5)
  gemm2ks_kernel<<<dim3(16, 8, 4), 256, 0, stream>>>(attin, Ot, qO, T_, 512, C_, C_);
  add5tr_kernel<<<5120, 256, 0, stream>>>(x, qO, x_att, fK, fKt);
  lnmix1_kernel<<<T_, 256, 0, stream>>>(x_att, xprev_f, ln2w, ln2b, fxk, xkf);
  gemm2_kernel<2><<<dim3(64, 8, 1), 256, 0, stream>>>(xkf, xkf, xkf, fKt, fKt, fKt,
                                                      hffn, hffn, hffn, nullptr, T_, C_, 4 * C_);
  gemm2ks_kernel<<<dim3(16, 8, 4), 256, 0, stream>>>(hffn, fVt, pF, T_, 2048, 4 * C_, C_);
  add5_kernel<<<1024, 256, 0, stream>>>(x_att, pF, out);
}

// Round 17
// 429.022 us; speedup vs baseline: 1.1577x; 1.0517x over previous
//
#include <hip/hip_runtime.h>
#include <hip/hip_bf16.h>

// RWKV-7 block (TMix + CMix) for T=1024, C=2048, H=32, N=64 on gfx950.

#define T_ 1024
#define C_ 2048
#define H_ 32
#define NH 64

typedef __attribute__((ext_vector_type(8))) short short8v;
typedef __attribute__((ext_vector_type(4))) float f32x4;

__device__ __forceinline__ float bf2f(unsigned short u) {
  union { float f; unsigned int i; } c; c.i = ((unsigned int)u) << 16; return c.f;
}
__device__ __forceinline__ unsigned short f2bf(float f) {
  union { float f; unsigned int i; } c; c.f = f;
  unsigned int x = c.i;
  return (unsigned short)((x + 0x7fffu + ((x >> 16) & 1u)) >> 16); // RNE
}
__device__ __forceinline__ float sigm(float x) { return 1.f / (1.f + __expf(-x)); }

__device__ __forceinline__ void load8bf(const unsigned short* p, float* o) {
  union { int4 v; unsigned short u[8]; } c;
  c.v = *(const int4*)p;
#pragma unroll
  for (int i = 0; i < 8; ++i) o[i] = bf2f(c.u[i]);
}
__device__ __forceinline__ void store8bf(unsigned short* p, const float* o) {
  union { int4 v; unsigned short u[8]; } c;
#pragma unroll
  for (int i = 0; i < 8; ++i) c.u[i] = f2bf(o[i]);
  *(int4*)p = c.v;
}
__device__ __forceinline__ void load8f(const float* p, float* o) {
  float4 a = ((const float4*)p)[0], b = ((const float4*)p)[1];
  o[0] = a.x; o[1] = a.y; o[2] = a.z; o[3] = a.w;
  o[4] = b.x; o[5] = b.y; o[6] = b.z; o[7] = b.w;
}
__device__ __forceinline__ void load4f(const float* p, float* o) {
  float4 a = *(const float4*)p;
  o[0] = a.x; o[1] = a.y; o[2] = a.z; o[3] = a.w;
}

#define GLD16(g, l)                                                        \
  __builtin_amdgcn_global_load_lds(                                        \
      (const __attribute__((address_space(1))) void*)(g),                  \
      (__attribute__((address_space(3))) void*)(l), 16, 0, 0)

// ---------------- tiled transpose body (device) ---------------------------
__device__ __forceinline__ void transpose_tile(
    const float* __restrict__ in, unsigned short* __restrict__ out,
    int R, int Cc, int bx, int by, unsigned short (*tile)[80]) {
  int c0 = bx * 64, r0 = by * 64;
  int rr = threadIdx.x >> 4, cq = threadIdx.x & 15;
#pragma unroll
  for (int i = 0; i < 4; ++i) {
    int r = rr + i * 16;
    float4 v = *(const float4*)(in + (size_t)(r0 + r) * Cc + c0 + cq * 4);
    tile[cq * 4 + 0][r] = f2bf(v.x);
    tile[cq * 4 + 1][r] = f2bf(v.y);
    tile[cq * 4 + 2][r] = f2bf(v.z);
    tile[cq * 4 + 3][r] = f2bf(v.w);
  }
  __syncthreads();
  int cr = threadIdx.x >> 2, rg = threadIdx.x & 3;
  int4 w0 = *(const int4*)&tile[cr][rg * 16];
  int4 w1 = *(const int4*)&tile[cr][rg * 16 + 8];
  unsigned short* op = out + (size_t)(c0 + cr) * R + r0 + rg * 16;
  *(int4*)op = w0;
  *(int4*)(op + 8) = w1;
}

// ---------------- fused LN+mix6 + ALL weight transposes -------------------
// blocks 0..1023: lnmix6; 1024..4095: R/K/V; 4096..4191: w1/a1/v1;
// 4192..4255: g1; 4256..4351: w2/a2/v2; 4352..4415: g2.
__global__ __launch_bounds__(256) void lnmix6tr_kernel(
    const float* __restrict__ x, const float* __restrict__ xprev,
    const float* __restrict__ lw, const float* __restrict__ lb,
    const float* __restrict__ mr, const float* __restrict__ mw,
    const float* __restrict__ mk, const float* __restrict__ mv,
    const float* __restrict__ ma, const float* __restrict__ mg,
    unsigned short* xr, unsigned short* xw, unsigned short* xk,
    unsigned short* xv, unsigned short* xa, unsigned short* xg,
    const float* R_, const float* K_, const float* V_,
    unsigned short* Rt, unsigned short* Kt, unsigned short* Vt,
    const float* w1, const float* a1, const float* v1,
    unsigned short* w1t, unsigned short* a1t, unsigned short* v1t,
    const float* g1, unsigned short* g1t,
    const float* w2, const float* a2, const float* v2,
    unsigned short* w2t, unsigned short* a2t, unsigned short* v2t,
    const float* g2, unsigned short* g2t) {
  __shared__ __align__(16) unsigned short tile[64][80];
  __shared__ float r4[4][4];
  int bid = blockIdx.x;
  if (bid >= 1024) {
    int idx = bid - 1024;
    if (idx < 3072) {
      const float* in = idx < 1024 ? R_ : (idx < 2048 ? K_ : V_);
      unsigned short* out = idx < 1024 ? Rt : (idx < 2048 ? Kt : Vt);
      int r = idx & 1023;
      transpose_tile(in, out, C_, C_, r & 31, r >> 5, tile);
      return;
    }
    idx -= 3072;
    if (idx < 96) {
      const float* in = idx < 32 ? w1 : (idx < 64 ? a1 : v1);
      unsigned short* out = idx < 32 ? w1t : (idx < 64 ? a1t : v1t);
      transpose_tile(in, out, C_, 64, 0, idx & 31, tile);
      return;
    }
    idx -= 96;
    if (idx < 64) { transpose_tile(g1, g1t, C_, 128, idx & 1, idx >> 1, tile); return; }
    idx -= 64;
    if (idx < 96) {
      const float* in = idx < 32 ? w2 : (idx < 64 ? a2 : v2);
      unsigned short* out = idx < 32 ? w2t : (idx < 64 ? a2t : v2t);
      transpose_tile(in, out, 64, C_, idx & 31, 0, tile);
      return;
    }
    idx -= 96;
    transpose_tile(g2, g2t, 128, C_, idx & 31, idx >> 5, tile);
    return;
  }
  int t = bid, tid = threadIdx.x, c = tid * 8;
  float cur[8], prv[8];
  load8f(x + (size_t)t * C_ + c, cur);
  if (t == 0) load8f(xprev + c, prv);
  else load8f(x + (size_t)(t - 1) * C_ + c, prv);
  float sc = 0.f, qc = 0.f, sp = 0.f, qp = 0.f;
#pragma unroll
  for (int i = 0; i < 8; ++i) {
    sc += cur[i]; qc += cur[i] * cur[i];
    sp += prv[i]; qp += prv[i] * prv[i];
  }
  for (int m = 1; m < 64; m <<= 1) {
    sc += __shfl_xor(sc, m); qc += __shfl_xor(qc, m);
    sp += __shfl_xor(sp, m); qp += __shfl_xor(qp, m);
  }
  if ((tid & 63) == 0) {
    r4[tid >> 6][0] = sc; r4[tid >> 6][1] = qc;
    r4[tid >> 6][2] = sp; r4[tid >> 6][3] = qp;
  }
  __syncthreads();
  sc = r4[0][0] + r4[1][0] + r4[2][0] + r4[3][0];
  qc = r4[0][1] + r4[1][1] + r4[2][1] + r4[3][1];
  sp = r4[0][2] + r4[1][2] + r4[2][2] + r4[3][2];
  qp = r4[0][3] + r4[1][3] + r4[2][3] + r4[3][3];
  float mc = sc * (1.f / C_);
  float rc = rsqrtf(qc * (1.f / C_) - mc * mc + 1e-5f);
  float mp = sp * (1.f / C_);
  float rp = rsqrtf(qp * (1.f / C_) - mp * mp + 1e-5f);
  float cw[8], cb[8];
  load8f(lw + c, cw); load8f(lb + c, cb);
  float curn[8], prvn[8];
#pragma unroll
  for (int i = 0; i < 8; ++i) {
    curn[i] = (cur[i] - mc) * rc * cw[i] + cb[i];
    prvn[i] = (t == 0) ? prv[i] : (prv[i] - mp) * rp * cw[i] + cb[i];
  }
  float cf[8], o[8];
  const float* coefs[6] = {mr, mw, mk, mv, ma, mg};
  unsigned short* outs6[6] = {xr, xw, xk, xv, xa, xg};
#pragma unroll
  for (int a = 0; a < 6; ++a) {
    load8f(coefs[a] + c, cf);
#pragma unroll
    for (int i = 0; i < 8; ++i) o[i] = curn[i] + (prvn[i] - curn[i]) * cf[i];
    store8bf(outs6[a] + (size_t)t * C_ + c, o);
  }
}

// ---------------- fused LN + 1-way mix (CMix) -----------------------------
__global__ __launch_bounds__(256) void lnmix1_kernel(
    const float* __restrict__ x, const float* __restrict__ xprev,
    const float* __restrict__ lw, const float* __restrict__ lb,
    const float* __restrict__ coef, unsigned short* __restrict__ out) {
  int t = blockIdx.x, tid = threadIdx.x, c = tid * 8;
  float cur[8], prv[8];
  load8f(x + (size_t)t * C_ + c, cur);
  if (t == 0) load8f(xprev + c, prv);
  else load8f(x + (size_t)(t - 1) * C_ + c, prv);
  float sc = 0.f, qc = 0.f, sp = 0.f, qp = 0.f;
#pragma unroll
  for (int i = 0; i < 8; ++i) {
    sc += cur[i]; qc += cur[i] * cur[i];
    sp += prv[i]; qp += prv[i] * prv[i];
  }
  for (int m = 1; m < 64; m <<= 1) {
    sc += __shfl_xor(sc, m); qc += __shfl_xor(qc, m);
    sp += __shfl_xor(sp, m); qp += __shfl_xor(qp, m);
  }
  __shared__ float r4[4][4];
  if ((tid & 63) == 0) {
    r4[tid >> 6][0] = sc; r4[tid >> 6][1] = qc;
    r4[tid >> 6][2] = sp; r4[tid >> 6][3] = qp;
  }
  __syncthreads();
  sc = r4[0][0] + r4[1][0] + r4[2][0] + r4[3][0];
  qc = r4[0][1] + r4[1][1] + r4[2][1] + r4[3][1];
  sp = r4[0][2] + r4[1][2] + r4[2][2] + r4[3][2];
  qp = r4[0][3] + r4[1][3] + r4[2][3] + r4[3][3];
  float mc = sc * (1.f / C_);
  float rc = rsqrtf(qc * (1.f / C_) - mc * mc + 1e-5f);
  float mp = sp * (1.f / C_);
  float rp = rsqrtf(qp * (1.f / C_) - mp * mp + 1e-5f);
  float cw[8], cb[8], cf[8], o[8];
  load8f(lw + c, cw); load8f(lb + c, cb); load8f(coef + c, cf);
#pragma unroll
  for (int i = 0; i < 8; ++i) {
    float cn = (cur[i] - mc) * rc * cw[i] + cb[i];
    float pn = (t == 0) ? prv[i] : (prv[i] - mp) * rp * cw[i] + cb[i];
    o[i] = cn + (pn - cn) * cf[i];
  }
  store8bf(out + (size_t)t * C_ + c, o);
}

// ---------------- 2-phase double-buffered bf16 GEMM (ffn_K, relu^2) -------
template <int EPI>
__global__ __launch_bounds__(256) void gemm2_kernel(
    const unsigned short* A0, const unsigned short* A1, const unsigned short* A2,
    const unsigned short* B0, const unsigned short* B1, const unsigned short* B2,
    void* C0, void* C1, void* C2, const float* __restrict__ addsrc,
    int M, int K, int N) {
  int z = blockIdx.z;
  const unsigned short* A = z == 0 ? A0 : (z == 1 ? A1 : A2);
  const unsigned short* Bt = z == 0 ? B0 : (z == 1 ? B1 : B2);
  void* Cout = z == 0 ? C0 : (z == 1 ? C1 : C2);
  __shared__ __align__(16) unsigned short As[2][128 * 32];
  __shared__ __align__(16) unsigned short Bs[2][128 * 32];
  const int tid = threadIdx.x, lane = tid & 63, wid = tid >> 6;
  const int bm = blockIdx.y * 128, bn = blockIdx.x * 128;
  const int wr = wid >> 1, wc = wid & 1;
  const int mrow = lane & 15, krow = lane >> 4;
  auto stage = [&](int buf, int kt) {
#pragma unroll
    for (int q = 0; q < 2; ++q) {
      int s = q * 2048 + tid * 8;
      int m = s >> 5, k = s & 31;
      GLD16(A + (size_t)(bm + m) * K + kt + k, &As[buf][s]);
      GLD16(Bt + (size_t)(bn + m) * K + kt + k, &Bs[buf][s]);
    }
  };
  f32x4 acc[4][4] = {};
  stage(0, 0);
  __syncthreads();
  int buf = 0;
  for (int kt = 0; kt < K; kt += 32) {
    if (kt + 32 < K) stage(buf ^ 1, kt + 32);
    short8v af[4], bfrag[4];
#pragma unroll
    for (int i = 0; i < 4; ++i)
      af[i] = *(const short8v*)&As[buf][(wr * 64 + i * 16 + mrow) * 32 + krow * 8];
#pragma unroll
    for (int j = 0; j < 4; ++j)
      bfrag[j] = *(const short8v*)&Bs[buf][(wc * 64 + j * 16 + mrow) * 32 + krow * 8];
#pragma unroll
    for (int i = 0; i < 4; ++i)
#pragma unroll
      for (int j = 0; j < 4; ++j)
        acc[i][j] = __builtin_amdgcn_mfma_f32_16x16x32_bf16(af[i], bfrag[j], acc[i][j], 0, 0, 0);
    __syncthreads();
    buf ^= 1;
  }
#pragma unroll
  for (int i = 0; i < 4; ++i)
#pragma unroll
    for (int j = 0; j < 4; ++j)
#pragma unroll
      for (int e = 0; e < 4; ++e) {
        int grow = bm + wr * 64 + i * 16 + (lane >> 4) * 4 + e;
        int gcol = bn + wc * 64 + j * 16 + (lane & 15);
        size_t off = (size_t)grow * N + gcol;
        float v = acc[i][j][e];
        if constexpr (EPI == 0) ((float*)Cout)[off] = v;
        else if constexpr (EPI == 1) ((float*)Cout)[off] = addsrc[off] + v;
        else { float r = v > 0.f ? v : 0.f; ((unsigned short*)Cout)[off] = f2bf(r * r); }
      }
}

// ---------------- merged up-projections: z<3 K=64 (w/a/v), z=3 K=128 (g) --
__global__ __launch_bounds__(256) void gemm2up_kernel(
    const unsigned short* hwb, const unsigned short* hab,
    const unsigned short* hvb, const unsigned short* hgb,
    const unsigned short* w2t, const unsigned short* a2t,
    const unsigned short* v2t, const unsigned short* g2t,
    float* wpre, float* apre, float* vpre, float* g_buf) {
  int z = blockIdx.z;
  const unsigned short* A = z == 0 ? hwb : (z == 1 ? hab : (z == 2 ? hvb : hgb));
  const unsigned short* Bt = z == 0 ? w2t : (z == 1 ? a2t : (z == 2 ? v2t : g2t));
  float* Cout = z == 0 ? wpre : (z == 1 ? apre : (z == 2 ? vpre : g_buf));
  const int K = (z == 3) ? 128 : 64;
  const int N = C_;
  __shared__ __align__(16) unsigned short As[2][128 * 32];
  __shared__ __align__(16) unsigned short Bs[2][128 * 32];
  const int tid = threadIdx.x, lane = tid & 63, wid = tid >> 6;
  const int bm = blockIdx.y * 128, bn = blockIdx.x * 128;
  const int wr = wid >> 1, wc = wid & 1;
  const int mrow = lane & 15, krow = lane >> 4;
  auto stage = [&](int buf, int kt) {
#pragma unroll
    for (int q = 0; q < 2; ++q) {
      int s = q * 2048 + tid * 8;
      int m = s >> 5, k = s & 31;
      GLD16(A + (size_t)(bm + m) * K + kt + k, &As[buf][s]);
      GLD16(Bt + (size_t)(bn + m) * K + kt + k, &Bs[buf][s]);
    }
  };
  f32x4 acc[4][4] = {};
  stage(0, 0);
  __syncthreads();
  int buf = 0;
  for (int kt = 0; kt < K; kt += 32) {
    if (kt + 32 < K) stage(buf ^ 1, kt + 32);
    short8v af[4], bfrag[4];
#pragma unroll
    for (int i = 0; i < 4; ++i)
      af[i] = *(const short8v*)&As[buf][(wr * 64 + i * 16 + mrow) * 32 + krow * 8];
#pragma unroll
    for (int j = 0; j < 4; ++j)
      bfrag[j] = *(const short8v*)&Bs[buf][(wc * 64 + j * 16 + mrow) * 32 + krow * 8];
#pragma unroll
    for (int i = 0; i < 4; ++i)
#pragma unroll
      for (int j = 0; j < 4; ++j)
        acc[i][j] = __builtin_amdgcn_mfma_f32_16x16x32_bf16(af[i], bfrag[j], acc[i][j], 0, 0, 0);
    __syncthreads();
    buf ^= 1;
  }
#pragma unroll
  for (int i = 0; i < 4; ++i)
#pragma unroll
    for (int j = 0; j < 4; ++j)
#pragma unroll
      for (int e = 0; e < 4; ++e) {
        int grow = bm + wr * 64 + i * 16 + (lane >> 4) * 4 + e;
        int gcol = bn + wc * 64 + j * 16 + (lane & 15);
        Cout[(size_t)grow * N + gcol] = acc[i][j][e];
      }
}

// ---------------- split-K variant: z = K-slice, bf16 partials -------------
__global__ __launch_bounds__(256) void gemm2ks_kernel(
    const unsigned short* __restrict__ A, const unsigned short* __restrict__ Bt,
    unsigned short* __restrict__ P, int M, int KH, int Ktot, int N) {
  int kz = blockIdx.z;
  const size_t kbase = (size_t)kz * KH;
  __shared__ __align__(16) unsigned short As[2][128 * 32];
  __shared__ __align__(16) unsigned short Bs[2][128 * 32];
  const int tid = threadIdx.x, lane = tid & 63, wid = tid >> 6;
  const int bm = blockIdx.y * 128, bn = blockIdx.x * 128;
  const int wr = wid >> 1, wc = wid & 1;
  const int mrow = lane & 15, krow = lane >> 4;
  auto stage = [&](int buf, int kt) {
#pragma unroll
    for (int q = 0; q < 2; ++q) {
      int s = q * 2048 + tid * 8;
      int m = s >> 5, k = s & 31;
      GLD16(A + (size_t)(bm + m) * Ktot + kbase + kt + k, &As[buf][s]);
      GLD16(Bt + (size_t)(bn + m) * Ktot + kbase + kt + k, &Bs[buf][s]);
    }
  };
  f32x4 acc[4][4] = {};
  stage(0, 0);
  __syncthreads();
  int buf = 0;
  for (int kt = 0; kt < KH; kt += 32) {
    if (kt + 32 < KH) stage(buf ^ 1, kt + 32);
    short8v af[4], bfrag[4];
#pragma unroll
    for (int i = 0; i < 4; ++i)
      af[i] = *(const short8v*)&As[buf][(wr * 64 + i * 16 + mrow) * 32 + krow * 8];
#pragma unroll
    for (int j = 0; j < 4; ++j)
      bfrag[j] = *(const short8v*)&Bs[buf][(wc * 64 + j * 16 + mrow) * 32 + krow * 8];
#pragma unroll
    for (int i = 0; i < 4; ++i)
#pragma unroll
      for (int j = 0; j < 4; ++j)
        acc[i][j] = __builtin_amdgcn_mfma_f32_16x16x32_bf16(af[i], bfrag[j], acc[i][j], 0, 0, 0);
    __syncthreads();
    buf ^= 1;
  }
  unsigned short* Pz = P + (size_t)kz * M * N;
#pragma unroll
  for (int i = 0; i < 4; ++i)
#pragma unroll
    for (int j = 0; j < 4; ++j)
#pragma unroll
      for (int e = 0; e < 4; ++e) {
        int grow = bm + wr * 64 + i * 16 + (lane >> 4) * 4 + e;
        int gcol = bn + wc * 64 + j * 16 + (lane & 15);
        Pz[(size_t)grow * N + gcol] = f2bf(acc[i][j][e]);
      }
}

// ---------------- merged rkv split-K + lora-down GEMMs --------------------
// blocks 0..767: rkv (bz=bid>>7: batch=bz%3, kz=bz/3; rem: bx=rem&15, by=rem>>4)
// blocks 768..959: lora w/a/v downs (N=64). blocks 960..1087: lora g (N=128).
__global__ __launch_bounds__(256) void bigemm_kernel(
    const unsigned short* xr, const unsigned short* xk, const unsigned short* xv,
    const unsigned short* Rt, const unsigned short* Kt, const unsigned short* Vt,
    unsigned short* __restrict__ qRKV,
    const unsigned short* xw, const unsigned short* xa, const unsigned short* xg,
    const unsigned short* w1t, const unsigned short* a1t, const unsigned short* v1t,
    const unsigned short* g1t,
    float* pw, float* pa, float* pv, float* pg) {
  __shared__ __align__(16) unsigned short smem[16384];  // 32 KB
  const int bid = blockIdx.x;
  const int tid = threadIdx.x, lane = tid & 63, wid = tid >> 6;
  const int wr = wid >> 1, wc = wid & 1;
  const int mrow = lane & 15, krow = lane >> 4;
  unsigned short* As0 = smem;          // [2][4096]
  if (bid < 768) {
    int bz = bid >> 7, rem = bid & 127;
    int bx = rem & 15, by = rem >> 4;
    int batch = bz % 3, kz = bz / 3;
    const unsigned short* A = batch == 0 ? xr : (batch == 1 ? xk : xv);
    const unsigned short* Bt = batch == 0 ? Rt : (batch == 1 ? Kt : Vt);
    unsigned short* Bs0 = smem + 8192; // [2][4096]
    const size_t kbase = (size_t)kz * 1024;
    const int bm = by * 128, bn = bx * 128;
    auto stage = [&](int buf, int kt) {
#pragma unroll
      for (int q = 0; q < 2; ++q) {
        int s = q * 2048 + tid * 8;
        int m = s >> 5, k = s & 31;
        GLD16(A + (size_t)(bm + m) * C_ + kbase + kt + k, &As0[buf * 4096 + s]);
        GLD16(Bt + (size_t)(bn + m) * C_ + kbase + kt + k, &Bs0[buf * 4096 + s]);
      }
    };
    f32x4 acc[4][4] = {};
    stage(0, 0);
    __syncthreads();
    int buf = 0;
    for (int kt = 0; kt < 1024; kt += 32) {
      if (kt + 32 < 1024) stage(buf ^ 1, kt + 32);
      short8v af[4], bfrag[4];
#pragma unroll
      for (int i = 0; i < 4; ++i)
        af[i] = *(const short8v*)&As0[buf * 4096 + (wr * 64 + i * 16 + mrow) * 32 + krow * 8];
#pragma unroll
      for (int j = 0; j < 4; ++j)
        bfrag[j] = *(const short8v*)&Bs0[buf * 4096 + (wc * 64 + j * 16 + mrow) * 32 + krow * 8];
#pragma unroll
      for (int i = 0; i < 4; ++i)
#pragma unroll
        for (int j = 0; j < 4; ++j)
          acc[i][j] = __builtin_amdgcn_mfma_f32_16x16x32_bf16(af[i], bfrag[j], acc[i][j], 0, 0, 0);
      __syncthreads();
      buf ^= 1;
    }
    unsigned short* Pz = qRKV + (size_t)bz * T_ * C_;
#pragma unroll
    for (int i = 0; i < 4; ++i)
#pragma unroll
      for (int j = 0; j < 4; ++j)
#pragma unroll
        for (int e = 0; e < 4; ++e) {
          int grow = bm + wr * 64 + i * 16 + (lane >> 4) * 4 + e;
          int gcol = bn + wc * 64 + j * 16 + (lane & 15);
          Pz[(size_t)grow * C_ + gcol] = f2bf(acc[i][j][e]);
        }
    return;
  }
  // lora downs: BN=64, K=2048, 256-per-kz slices
  const unsigned short* A;
  const unsigned short* Bt;
  float* partial;
  int N, bn, bm, kz;
  if (bid < 960) {
    int idx = bid - 768;
    int by = idx & 7, kzz = idx >> 3;       // kzz 0..23
    int mz = kzz >> 3; kz = kzz & 7;
    A = mz == 0 ? xw : (mz == 1 ? xa : xv);
    Bt = mz == 0 ? w1t : (mz == 1 ? a1t : v1t);
    partial = mz == 0 ? pw : (mz == 1 ? pa : pv);
    N = 64; bn = 0; bm = by * 128;
  } else {
    int idx = bid - 960;
    kz = idx >> 4;
    int rem = idx & 15;
    A = xg; Bt = g1t; partial = pg;
    N = 128; bn = (rem & 1) * 64; bm = (rem >> 1) * 128;
  }
  unsigned short* Bs0 = smem + 8192;       // [2][2048]
  auto stage = [&](int buf, int kt) {
#pragma unroll
    for (int q = 0; q < 2; ++q) {
      int s = q * 2048 + tid * 8;
      int m = s >> 5, k = s & 31;
      GLD16(A + (size_t)(bm + m) * C_ + kt + k, &As0[buf * 4096 + s]);
    }
    {
      int s = tid * 8;
      int n = s >> 5, k = s & 31;
      GLD16(Bt + (size_t)(bn + n) * C_ + kt + k, &Bs0[buf * 2048 + s]);
    }
  };
  f32x4 acc[4][2] = {};
  int k0 = kz * 256;
  stage(0, k0);
  __syncthreads();
  int buf = 0;
  for (int kt = k0; kt < k0 + 256; kt += 32) {
    if (kt + 32 < k0 + 256) stage(buf ^ 1, kt + 32);
    short8v af[4], bfrag[2];
#pragma unroll
    for (int i = 0; i < 4; ++i)
      af[i] = *(const short8v*)&As0[buf * 4096 + (wr * 64 + i * 16 + mrow) * 32 + krow * 8];
#pragma unroll
    for (int j = 0; j < 2; ++j)
      bfrag[j] = *(const short8v*)&Bs0[buf * 2048 + (wc * 32 + j * 16 + mrow) * 32 + krow * 8];
#pragma unroll
    for (int i = 0; i < 4; ++i)
#pragma unroll
      for (int j = 0; j < 2; ++j)
        acc[i][j] = __builtin_amdgcn_mfma_f32_16x16x32_bf16(af[i], bfrag[j], acc[i][j], 0, 0, 0);
    __syncthreads();
    buf ^= 1;
  }
#pragma unroll
  for (int i = 0; i < 4; ++i)
#pragma unroll
    for (int j = 0; j < 2; ++j)
#pragma unroll
      for (int e = 0; e < 4; ++e) {
        int row = bm + wr * 64 + i * 16 + (lane >> 4) * 4 + e;
        int col = bn + wc * 32 + j * 16 + (lane & 15);
        partial[((size_t)kz * 1024 + row) * N + col] = acc[i][j][e];
      }
}

// ---------------- o = a + p0+p1+p2+p3 (bf16 partials at stride T*C) -------
__global__ __launch_bounds__(256) void add5_kernel(
    const float* __restrict__ a, const unsigned short* __restrict__ p,
    float* __restrict__ o) {
  size_t i = ((size_t)blockIdx.x * 256 + threadIdx.x) * 8;
  const size_t TC = (size_t)T_ * C_;
  float va[8], v0[8], v1[8], v2[8], v3[8], r[8];
  load8f(a + i, va);
  load8bf(p + i, v0);
  load8bf(p + i + TC, v1);
  load8bf(p + i + 2 * TC, v2);
  load8bf(p + i + 3 * TC, v3);
#pragma unroll
  for (int k = 0; k < 8; ++k) r[k] = va[k] + v0[k] + v1[k] + v2[k] + v3[k];
  *(float4*)(o + i) = make_float4(r[0], r[1], r[2], r[3]);
  *(float4*)(o + i + 4) = make_float4(r[4], r[5], r[6], r[7]);
}

// ---------------- add5 + fK transpose fused (blocks >= 1024) --------------
__global__ __launch_bounds__(256) void add5tr_kernel(
    const float* __restrict__ a, const unsigned short* __restrict__ p,
    float* __restrict__ o, const float* __restrict__ fK,
    unsigned short* __restrict__ fKt) {
  int bid = blockIdx.x;
  if (bid < 1024) {
    size_t i = ((size_t)bid * 256 + threadIdx.x) * 8;
    const size_t TC = (size_t)T_ * C_;
    float va[8], v0[8], v1[8], v2[8], v3[8], r[8];
    load8f(a + i, va);
    load8bf(p + i, v0);
    load8bf(p + i + TC, v1);
    load8bf(p + i + 2 * TC, v2);
    load8bf(p + i + 3 * TC, v3);
#pragma unroll
    for (int k = 0; k < 8; ++k) r[k] = va[k] + v0[k] + v1[k] + v2[k] + v3[k];
    *(float4*)(o + i) = make_float4(r[0], r[1], r[2], r[3]);
    *(float4*)(o + i + 4) = make_float4(r[4], r[5], r[6], r[7]);
    return;
  }
  __shared__ __align__(16) unsigned short tile[64][80];
  int idx = bid - 1024;                 // 0..4095
  transpose_tile(fK, fKt, C_, 4 * C_, idx & 127, idx >> 7, tile);
}

__global__ __launch_bounds__(128) void lora_combine_kernel(
    const float* __restrict__ pw, const float* __restrict__ pa,
    const float* __restrict__ pv, const float* __restrict__ pg,
    unsigned short* __restrict__ hw, unsigned short* __restrict__ ha,
    unsigned short* __restrict__ hv, unsigned short* __restrict__ hg) {
  int t = blockIdx.x, which = blockIdx.y, tid = threadIdx.x;
  int Nl = (which == 3) ? 128 : 64;
  if (tid >= Nl) return;
  const float* p = which == 0 ? pw : which == 1 ? pa : which == 2 ? pv : pg;
  float s = 0.f;
#pragma unroll
  for (int kz = 0; kz < 8; ++kz) s += p[((size_t)kz * 1024 + t) * Nl + tid];
  float r = which == 0 ? tanhf(s) : (which == 3 ? sigm(s) : s);
  unsigned short* o = which == 0 ? hw : which == 1 ? ha : which == 2 ? hv : hg;
  o[t * Nl + tid] = f2bf(r);
}

// ---------------- post: rkv bf16-partial combine + pack scan inputs -------
__global__ __launch_bounds__(256) void post_kernel(
    const unsigned short* __restrict__ qRKV, const float* __restrict__ wpre,
    const float* __restrict__ apre, const float* __restrict__ vpre,
    const float* __restrict__ vfirst, const float* __restrict__ w0,
    const float* __restrict__ a0, const float* __restrict__ v0_,
    const float* __restrict__ k_k, const float* __restrict__ k_a,
    float* __restrict__ scanin) {
  int t = blockIdx.x, tid = threadIdx.x;
  int c = tid * 8, h = tid >> 3, j = c & 63;
  size_t o = (size_t)t * C_ + c;
  const size_t TC = (size_t)T_ * C_;
  float rv[8], kv[8], vv[8], t0[8], wv[8], av[8], vp[8], vf[8];
  load8bf(qRKV + o, rv);          load8bf(qRKV + 3 * TC + o, t0);
#pragma unroll
  for (int i = 0; i < 8; ++i) rv[i] += t0[i];
  load8bf(qRKV + TC + o, kv);     load8bf(qRKV + 4 * TC + o, t0);
#pragma unroll
  for (int i = 0; i < 8; ++i) kv[i] += t0[i];
  load8bf(qRKV + 2 * TC + o, vv); load8bf(qRKV + 5 * TC + o, t0);
#pragma unroll
  for (int i = 0; i < 8; ++i) vv[i] += t0[i];
  load8f(wpre + o, wv); load8f(apre + o, av); load8f(vpre + o, vp);
  load8f(vfirst + o, vf);
  float ckk[8], cka[8], cw0[8], ca0[8], cv0[8];
  load8f(k_k + c, ckk); load8f(k_a + c, cka); load8f(w0 + c, cw0);
  load8f(a0 + c, ca0); load8f(v0_ + c, cv0);
  float kk[8]; float ss = 0.f;
#pragma unroll
  for (int i = 0; i < 8; ++i) { kk[i] = kv[i] * ckk[i]; ss += kk[i] * kk[i]; }
  ss += __shfl_xor(ss, 1); ss += __shfl_xor(ss, 2); ss += __shfl_xor(ss, 4);
  float rdn = 1.f / fmaxf(sqrtf(ss), 1e-12f);
  float sw[8], skn[8], scc[8], sk2[8], sv[8];
#pragma unroll
  for (int i = 0; i < 8; ++i) {
    float kkn = kk[i] * rdn;
    float a = sigm(ca0[i] + av[i]);
    skn[i] = kkn;
    scc[i] = -kkn * a;
    sk2[i] = kv[i] * (1.f + (a - 1.f) * cka[i]);
    float sg = sigm(cv0[i] + vp[i]);
    sv[i] = vv[i] + (vf[i] - vv[i]) * sg;
    sw[i] = __expf(-0.606531f * sigm(cw0[i] + wv[i]));
  }
  float* bp = scanin + ((size_t)h * T_ + t) * 384 + j;
  ((float4*)(bp + 0))[0]   = make_float4(sw[0], sw[1], sw[2], sw[3]);
  ((float4*)(bp + 4))[0]   = make_float4(sw[4], sw[5], sw[6], sw[7]);
  ((float4*)(bp + 64))[0]  = make_float4(skn[0], skn[1], skn[2], skn[3]);
  ((float4*)(bp + 68))[0]  = make_float4(skn[4], skn[5], skn[6], skn[7]);
  ((float4*)(bp + 128))[0] = make_float4(scc[0], scc[1], scc[2], scc[3]);
  ((float4*)(bp + 132))[0] = make_float4(scc[4], scc[5], scc[6], scc[7]);
  ((float4*)(bp + 192))[0] = make_float4(sk2[0], sk2[1], sk2[2], sk2[3]);
  ((float4*)(bp + 196))[0] = make_float4(sk2[4], sk2[5], sk2[6], sk2[7]);
  ((float4*)(bp + 256))[0] = make_float4(sv[0], sv[1], sv[2], sv[3]);
  ((float4*)(bp + 260))[0] = make_float4(sv[4], sv[5], sv[6], sv[7]);
  ((float4*)(bp + 320))[0] = make_float4(rv[0], rv[1], rv[2], rv[3]);
  ((float4*)(bp + 324))[0] = make_float4(rv[4], rv[5], rv[6], rv[7]);
}

// ---------------- scan + O/fV transposes fused ----------------------------
struct SR { float wv[4], nv[4], cv[4], kv[4], rv[4], vvv; };

template <int CTRL>
__device__ __forceinline__ float dppadd(float x) {
  int y = __builtin_amdgcn_update_dpp(0, __float_as_int(x), CTRL, 0xF, 0xF, true);
  return x + __int_as_float(y);
}
__device__ __forceinline__ float red16(float x) {
  x = dppadd<0xB1>(x);
  x = dppadd<0x4E>(x);
  x = dppadd<0x140>(x);
  x = dppadd<0x141>(x);
  return x;
}

__device__ __forceinline__ void loadstep(const float* S, SR& R, int p4, int row) {
  load4f(S + p4, R.wv);
  load4f(S + 64 + p4, R.nv);
  load4f(S + 128 + p4, R.cv);
  load4f(S + 192 + p4, R.kv);
  load4f(S + 320 + p4, R.rv);
  R.vvv = S[256 + row];
}

__device__ __forceinline__ void stepcomp(const SR& R, float* st, int part,
                                         float* __restrict__ ob, size_t oidx) {
  float p0 = fmaf(st[0], R.nv[0], 0.f);
  float p1 = fmaf(st[1], R.nv[1], 0.f);
  p0 = fmaf(st[2], R.nv[2], p0);
  p1 = fmaf(st[3], R.nv[3], p1);
  float sa = red16(p0 + p1);
  float s0 = 0.f, s1 = 0.f;
#pragma unroll
  for (int i = 0; i < 4; ++i) {
    float t = fmaf(st[i], R.wv[i], fmaf(sa, R.cv[i], R.vvv * R.kv[i]));
    st[i] = t;
    if (i & 1) s1 = fmaf(t, R.rv[i], s1);
    else s0 = fmaf(t, R.rv[i], s0);
  }
  float so = red16(s0 + s1);
  if (part == 0) ob[oidx] = so;
}

__global__ __launch_bounds__(256) void scanfuse_kernel(
    const float* __restrict__ scanin, const float* __restrict__ vk0,
    float* __restrict__ outs,
    const float* __restrict__ Osrc, unsigned short* __restrict__ Ot,
    const float* __restrict__ fVsrc, unsigned short* __restrict__ fVt) {
  int bid = blockIdx.x;
  if (bid >= 512) {
    __shared__ __align__(16) unsigned short tile[64][80];
    int idx = bid - 512;
    if (idx < 1024) transpose_tile(Osrc, Ot, C_, C_, idx & 31, idx >> 5, tile);
    else { idx -= 1024; transpose_tile(fVsrc, fVt, 4 * C_, C_, idx & 31, idx >> 5, tile); }
    return;
  }
  if (threadIdx.x >= 64) return;
  int h = (bid & 7) + 8 * ((bid >> 3) & 3);
  int rg = bid >> 5;
  int tid = threadIdx.x;
  int part = tid & 15, row = rg * 4 + (tid >> 4);
  int p4 = part * 4;
  float st[4];
  load4f(vk0 + ((size_t)h * NH + row) * NH + p4, st);
  const float* src = scanin + (size_t)h * T_ * 384;
  float* ob = outs + h * NH + row;
  SR A, B, C, D;
  loadstep(src + 0 * 384, A, p4, row);
  loadstep(src + 1 * 384, B, p4, row);
  loadstep(src + 2 * 384, C, p4, row);
  int s = 0;
  for (; s < T_ - 4; s += 4) {
    const float* sp = src + (size_t)s * 384;
    loadstep(sp + 3 * 384, D, p4, row);
    stepcomp(A, st, part, ob, (size_t)(s + 0) * C_);
    loadstep(sp + 4 * 384, A, p4, row);
    stepcomp(B, st, part, ob, (size_t)(s + 1) * C_);
    loadstep(sp + 5 * 384, B, p4, row);
    stepcomp(C, st, part, ob, (size_t)(s + 2) * C_);
    loadstep(sp + 6 * 384, C, p4, row);
    stepcomp(D, st, part, ob, (size_t)(s + 3) * C_);
  }
  loadstep(src + (size_t)(T_ - 1) * 384, D, p4, row);
  stepcomp(A, st, part, ob, (size_t)(s + 0) * C_);
  stepcomp(B, st, part, ob, (size_t)(s + 1) * C_);
  stepcomp(C, st, part, ob, (size_t)(s + 2) * C_);
  stepcomp(D, st, part, ob, (size_t)(s + 3) * C_);
}

// ---------------- groupnorm + bonus + gate --------------------------------
__global__ __launch_bounds__(256) void gnb_kernel(
    const float* __restrict__ outs, const float* __restrict__ scanin,
    const float* __restrict__ g, const float* __restrict__ rk,
    const float* __restrict__ gw, const float* __restrict__ gb,
    unsigned short* __restrict__ attin) {
  int t = blockIdx.x, tid = threadIdx.x;
  int c = tid * 8, h = tid >> 3, j = c & 63;
  float o[8], gv[8], rkv[8];
  load8f(outs + (size_t)t * C_ + c, o);
  load8f(g + (size_t)t * C_ + c, gv);
  load8f(rk + c, rkv);
  size_t sbase = ((size_t)h * T_ + t) * 384 + j;
  float rv[8], k2[8], vv[8];
  load8f(scanin + sbase + 320, rv);
  load8f(scanin + sbase + 192, k2);
  load8f(scanin + sbase + 256, vv);
  float s = 0.f, q = 0.f, bs = 0.f;
#pragma unroll
  for (int i = 0; i < 8; ++i) {
    s += o[i]; q += o[i] * o[i];
    bs += rv[i] * k2[i] * rkv[i];
  }
  s += __shfl_xor(s, 1); s += __shfl_xor(s, 2); s += __shfl_xor(s, 4);
  q += __shfl_xor(q, 1); q += __shfl_xor(q, 2); q += __shfl_xor(q, 4);
  bs += __shfl_xor(bs, 1); bs += __shfl_xor(bs, 2); bs += __shfl_xor(bs, 4);
  float mean = s * (1.f / NH);
  float var = q * (1.f / NH) - mean * mean;
  float rstd = rsqrtf(var + 0.00064f);
  float res[8];
#pragma unroll
  for (int i = 0; i < 8; ++i) {
    float gn = (o[i] - mean) * rstd * gw[c + i] + gb[c + i];
    res[i] = (gn + bs * vv[i]) * gv[i];
  }
  store8bf(attin + (size_t)t * C_ + c, res);
}

extern "C" void kernel_launch(void* const* d_in, const int* in_sizes, int n_in,
                              void* d_out, int out_size, void* d_ws, size_t ws_size,
                              hipStream_t stream) {
  const float* x       = (const float*)d_in[0];
  const float* xprev_a = (const float*)d_in[1];
  const float* vk0     = (const float*)d_in[2];
  const float* xprev_f = (const float*)d_in[3];
  const float* vfirst  = (const float*)d_in[4];
  const float* ln1w = (const float*)d_in[5];
  const float* ln1b = (const float*)d_in[6];
  const float* m_r = (const float*)d_in[7];
  const float* m_w = (const float*)d_in[8];
  const float* m_k = (const float*)d_in[9];
  const float* m_v = (const float*)d_in[10];
  const float* m_a = (const float*)d_in[11];
  const float* m_g = (const float*)d_in[12];
  const float* w0 = (const float*)d_in[13];
  const float* w1 = (const float*)d_in[14];
  const float* w2 = (const float*)d_in[15];
  const float* a0 = (const float*)d_in[16];
  const float* a1 = (const float*)d_in[17];
  const float* a2 = (const float*)d_in[18];
  const float* v0 = (const float*)d_in[19];
  const float* v1 = (const float*)d_in[20];
  const float* v2 = (const float*)d_in[21];
  const float* g1 = (const float*)d_in[22];
  const float* g2 = (const float*)d_in[23];
  const float* k_k = (const float*)d_in[24];
  const float* k_a = (const float*)d_in[25];
  const float* r_k = (const float*)d_in[26];
  const float* R_ = (const float*)d_in[27];
  const float* K_ = (const float*)d_in[28];
  const float* V_ = (const float*)d_in[29];
  const float* O_ = (const float*)d_in[30];
  const float* lnxw = (const float*)d_in[31];
  const float* lnxb = (const float*)d_in[32];
  const float* ln2w = (const float*)d_in[33];
  const float* ln2b = (const float*)d_in[34];
  const float* fxk = (const float*)d_in[35];
  const float* fK = (const float*)d_in[36];
  const float* fV = (const float*)d_in[37];
  float* out = (float*)d_out;

  char* ws = (char*)d_ws;
  const size_t MB = 1ull << 20;
  // ---- workspace layout (fixed w2t placement; peak 132 MB) ---------------
  // 0-4: attin (ph7+); 0-1.25: w1t..g1t (ph1-3); 1.31-2: hwb..hgb (ph4)
  // 4-8: xr; 8-12: xw; 12-16: xk; 16-20: xv; 20-24: xa; 24-28: xg (ph1-3)
  // 4-12: wpre; 12-20: apre; 20-28: vpre (ph4c-5, over dead xr..xg)
  // 4-36: fVt (written in scanfuse ph6, read ph11)
  // 28-52: qRKV bf16 (ph3-5, dead after post)
  // 52-60: outsb (ph6-7); 60-68: Ot (ph6-8) then x_att (ph9+)
  // 68-72: xkf (ph9b-10)
  // 72-73.25: w2t..g2t (ph1-4c; FREE hole -- no overlap with qRKV now)
  // 76-84: g_buf (ph4c-7)
  // 84-132: scanin fp32 (ph5-7); 84-108: Rt/Kt/Vt (ph1-3)
  // 84-100: qO bf16 (ph8-9) then hffn (ph10-11)
  // 100-132: fKt (ph9-10); 100-116: pF bf16 (ph11, over dead fKt)
  // 108-118: pw/pa/pv/pg fp32 (ph3-4b, dead before scanin ph5 write)
  unsigned short* attin = (unsigned short*)(ws + 0 * MB);
  unsigned short* xr    = (unsigned short*)(ws + 4 * MB);
  unsigned short* xw    = (unsigned short*)(ws + 8 * MB);
  unsigned short* xk    = (unsigned short*)(ws + 12 * MB);
  unsigned short* xv    = (unsigned short*)(ws + 16 * MB);
  unsigned short* xa    = (unsigned short*)(ws + 20 * MB);
  unsigned short* xg    = (unsigned short*)(ws + 24 * MB);
  float* wpre  = (float*)(ws + 4 * MB);
  float* apre  = (float*)(ws + 12 * MB);
  float* vpre  = (float*)(ws + 20 * MB);
  unsigned short* fVt = (unsigned short*)(ws + 4 * MB);
  unsigned short* qRKV = (unsigned short*)(ws + 28 * MB);
  float* outsb = (float*)(ws + 52 * MB);
  unsigned short* Ot = (unsigned short*)(ws + 60 * MB);
  float* x_att = (float*)(ws + 60 * MB);
  unsigned short* xkf = (unsigned short*)(ws + 68 * MB);
  unsigned short* w2t = (unsigned short*)(ws + 72 * MB);
  unsigned short* a2t = (unsigned short*)(ws + 72 * MB + 262144);
  unsigned short* v2t = (unsigned short*)(ws + 72 * MB + 524288);
  unsigned short* g2t = (unsigned short*)(ws + 72 * MB + 786432);
  float* g_buf = (float*)(ws + 76 * MB);
  float* scanin = (float*)(ws + 84 * MB);
  unsigned short* Rt  = (unsigned short*)(ws + 84 * MB);
  unsigned short* Kt  = (unsigned short*)(ws + 92 * MB);
  unsigned short* Vt  = (unsigned short*)(ws + 100 * MB);
  unsigned short* qO  = (unsigned short*)(ws + 84 * MB);
  unsigned short* hffn = (unsigned short*)(ws + 84 * MB);
  unsigned short* fKt  = (unsigned short*)(ws + 100 * MB);
  unsigned short* pF   = (unsigned short*)(ws + 100 * MB);
  float* pw = (float*)(ws + 108 * MB);
  float* pa = (float*)(ws + 110 * MB);
  float* pv = (float*)(ws + 112 * MB);
  float* pg = (float*)(ws + 114 * MB);
  unsigned short* w1t = (unsigned short*)(ws + 0);
  unsigned short* a1t = (unsigned short*)(ws + 262144);
  unsigned short* v1t = (unsigned short*)(ws + 524288);
  unsigned short* g1t = (unsigned short*)(ws + 786432);
  unsigned short* hwb = (unsigned short*)(ws + 1376256);
  unsigned short* hab = (unsigned short*)(ws + 1507328);
  unsigned short* hvb = (unsigned short*)(ws + 1638400);
  unsigned short* hgb = (unsigned short*)(ws + 1769472);

  // ph1: fused LN+mix6 + all weight transposes
  lnmix6tr_kernel<<<4416, 256, 0, stream>>>(
      x, xprev_a, ln1w, ln1b, m_r, m_w, m_k, m_v, m_a, m_g,
      xr, xw, xk, xv, xa, xg,
      R_, K_, V_, Rt, Kt, Vt,
      w1, a1, v1, w1t, a1t, v1t, g1, g1t,
      w2, a2, v2, w2t, a2t, v2t, g2, g2t);
  // ph3: merged rkv split-K + lora downs
  bigemm_kernel<<<1088, 256, 0, stream>>>(xr, xk, xv, Rt, Kt, Vt, qRKV,
                                          xw, xa, xg, w1t, a1t, v1t, g1t,
                                          pw, pa, pv, pg);
  // ph4b: lora combine; ph4c: merged up-projections
  lora_combine_kernel<<<dim3(T_, 4), 128, 0, stream>>>(pw, pa, pv, pg, hwb, hab, hvb, hgb);
  gemm2up_kernel<<<dim3(16, 8, 4), 256, 0, stream>>>(hwb, hab, hvb, hgb,
                                                     w2t, a2t, v2t, g2t,
                                                     wpre, apre, vpre, g_buf);
  // ph5-7: scan pipeline (transposes of O/fV ride the scan)
  post_kernel<<<T_, 256, 0, stream>>>(qRKV, wpre, apre, vpre, vfirst,
                                      w0, a0, v0, k_k, k_a, scanin);
  scanfuse_kernel<<<5632, 256, 0, stream>>>(scanin, vk0, outsb, O_, Ot, fV, fVt);
  gnb_kernel<<<T_, 256, 0, stream>>>(outsb, scanin, g_buf, r_k, lnxw, lnxb, attin);
  // ph8-9: output proj (split-K, bf16 partials); fK transpose rides add5
  gemm2ks_kernel<<<dim3(16, 8, 4), 256, 0, stream>>>(attin, Ot, qO, T_, 512, C_, C_);
  add5tr_kernel<<<5120, 256, 0, stream>>>(x, qO, x_att, fK, fKt);
  // ph9b-11: CMix
  lnmix1_kernel<<<T_, 256, 0, stream>>>(x_att, xprev_f, ln2w, ln2b, fxk, xkf);
  gemm2_kernel<2><<<dim3(64, 8, 1), 256, 0, stream>>>(xkf, xkf, xkf, fKt, fKt, fKt,
                                                      hffn, hffn, hffn, nullptr, T_, C_, 4 * C_);
  gemm2ks_kernel<<<dim3(16, 8, 4), 256, 0, stream>>>(hffn, fVt, pF, T_, 2048, 4 * C_, C_);
  add5_kernel<<<1024, 256, 0, stream>>>(x_att, pF, out);
}